// Round 5
// baseline (10548.402 us; speedup 1.0000x reference)
//
#include <hip/hip_runtime.h>

#define DIMM 1024
#define NHEADS 8
#define DH 128
#define NSLOTS 128
#define CHUNK 256
#define NCHUNK 16
#define NB 2
#define SEQ 4096
#define NROWS (NB * SEQ)
#define NVOCAB 32000
#define GAMMA64 0.9
#define SCALE64 0.08838834764831845

typedef unsigned short u16;
typedef __attribute__((ext_vector_type(4))) float f32x4;
typedef __attribute__((ext_vector_type(8))) short s16x8;

struct alignas(8) u16x4 { u16 x, y, z, w; };

__device__ __forceinline__ u16 f2bf(float f) {
  union { float f; unsigned u; } v; v.f = f;
  return (u16)((v.u + 0x7FFFu + ((v.u >> 16) & 1u)) >> 16);
}

__device__ __forceinline__ void gld16(void* lds, const void* g) {
  __builtin_amdgcn_global_load_lds(
      (const __attribute__((address_space(1))) unsigned*)g,
      (__attribute__((address_space(3))) unsigned*)lds, 16, 0, 0);
}
__device__ __forceinline__ f32x4 mfma16(s16x8 a, s16x8 b, f32x4 c) {
  return __builtin_amdgcn_mfma_f32_16x16x32_bf16(a, b, c, 0, 0, 0);
}

// ---------------- embedding gather -> f64 ----------------
__global__ __launch_bounds__(256) void embed64_kernel(
    const int* __restrict__ tok, const float* __restrict__ emb,
    double* __restrict__ hid) {
  const int row = blockIdx.x;
  const int t = tok[row];
  const float4 v = ((const float4*)(emb + (size_t)t * DIMM))[threadIdx.x];
  double* o = hid + (size_t)row * DIMM + threadIdx.x * 4;
  o[0] = (double)v.x; o[1] = (double)v.y; o[2] = (double)v.z; o[3] = (double)v.w;
}

// ---------------- f64 two-pass layernorm ----------------
template <int BF16OUT>
__global__ __launch_bounds__(256) void ln64_kernel(
    const double* __restrict__ x, const float* __restrict__ g,
    const float* __restrict__ bb, double* __restrict__ o64,
    u16* __restrict__ obf) {
  const int row = blockIdx.x, tid = threadIdx.x;
  const double* xr = x + (size_t)row * DIMM + tid * 4;
  const double v0 = xr[0], v1 = xr[1], v2 = xr[2], v3 = xr[3];
  __shared__ double red[4];
  double s1 = v0 + v1 + v2 + v3;
#pragma unroll
  for (int off = 32; off >= 1; off >>= 1) s1 += __shfl_xor(s1, off);
  if ((tid & 63) == 0) red[tid >> 6] = s1;
  __syncthreads();
  const double mu = (red[0] + red[1] + red[2] + red[3]) * (1.0 / DIMM);
  __syncthreads();
  const double d0 = v0 - mu, d1 = v1 - mu, d2 = v2 - mu, d3 = v3 - mu;
  double s2 = d0 * d0 + d1 * d1 + d2 * d2 + d3 * d3;
#pragma unroll
  for (int off = 32; off >= 1; off >>= 1) s2 += __shfl_xor(s2, off);
  if ((tid & 63) == 0) red[tid >> 6] = s2;
  __syncthreads();
  const double var = (red[0] + red[1] + red[2] + red[3]) * (1.0 / DIMM);
  const double rs = 1.0 / sqrt(var + 1e-5);
  const float4 g4 = ((const float4*)g)[tid];
  const float4 b4 = ((const float4*)bb)[tid];
  const double y0 = d0 * rs * (double)g4.x + (double)b4.x;
  const double y1 = d1 * rs * (double)g4.y + (double)b4.y;
  const double y2 = d2 * rs * (double)g4.z + (double)b4.z;
  const double y3 = d3 * rs * (double)g4.w + (double)b4.w;
  if (BF16OUT) {
    u16x4 r;
    r.x = f2bf((float)y0); r.y = f2bf((float)y1);
    r.z = f2bf((float)y2); r.w = f2bf((float)y3);
    ((u16x4*)(obf + (size_t)row * DIMM))[tid] = r;
  } else {
    double* o = o64 + (size_t)row * DIMM + tid * 4;
    o[0] = y0; o[1] = y1; o[2] = y2; o[3] = y3;
  }
}

// ---------------- f64 GEMM: C[M][N] = A[M][K](f64) @ W[K][N](f32) ----------
// 128x64 block tile, BK=32, 256 threads, 8x4 per thread.  LDS 49.6KB.
template <bool RES>
__global__ __launch_bounds__(256) void gemm64_kernel(
    const double* __restrict__ A, const float* __restrict__ W,
    double* __restrict__ C, const double* __restrict__ Cres, int M, int N,
    int K) {
  __shared__ double AsT[32][129];
  __shared__ double Ws[32][65];
  const int tid = threadIdx.x, bn = blockIdx.x, bm = blockIdx.y;
  const int tx = tid & 15, ty = tid >> 4;
  double acc[8][4] = {};
  const int ar = tid >> 1, kh = (tid & 1) * 16;
  const int wk = tid >> 3, wn = (tid & 7) * 8;
  const double* Ap = A + (size_t)(bm * 128 + ar) * K + kh;
  const float* Wp = W + (size_t)wk * N + bn * 64 + wn;

  for (int k0 = 0; k0 < K; k0 += 32) {
    double av[16];
    const double2* ap2 = (const double2*)(Ap + k0);
#pragma unroll
    for (int j = 0; j < 8; j++) {
      const double2 t = ap2[j];
      av[2 * j] = t.x; av[2 * j + 1] = t.y;
    }
    const float4 w0 = *(const float4*)(Wp + (size_t)k0 * N);
    const float4 w1 = *(const float4*)(Wp + (size_t)k0 * N + 4);
    __syncthreads();
#pragma unroll
    for (int j = 0; j < 16; j++) AsT[kh + j][ar] = av[j];
    Ws[wk][wn + 0] = (double)w0.x; Ws[wk][wn + 1] = (double)w0.y;
    Ws[wk][wn + 2] = (double)w0.z; Ws[wk][wn + 3] = (double)w0.w;
    Ws[wk][wn + 4] = (double)w1.x; Ws[wk][wn + 5] = (double)w1.y;
    Ws[wk][wn + 6] = (double)w1.z; Ws[wk][wn + 7] = (double)w1.w;
    __syncthreads();
#pragma unroll 4
    for (int kk = 0; kk < 32; kk++) {
      double a[8], b[4];
#pragma unroll
      for (int i = 0; i < 8; i++) a[i] = AsT[kk][ty * 8 + i];
#pragma unroll
      for (int j = 0; j < 4; j++) b[j] = Ws[kk][tx * 4 + j];
#pragma unroll
      for (int i = 0; i < 8; i++)
#pragma unroll
        for (int j = 0; j < 4; j++) acc[i][j] += a[i] * b[j];
    }
  }
#pragma unroll
  for (int i = 0; i < 8; i++) {
    const size_t r = (size_t)(bm * 128 + ty * 8 + i) * N + bn * 64 + tx * 4;
#pragma unroll
    for (int j = 0; j < 4; j++) {
      double v = acc[i][j];
      if (RES) v += Cres[r + j];
      C[r + j] = v;
    }
  }
}

// ---------------- top-16 of 128 slot scores, full f64 ----------------
__global__ __launch_bounds__(256) void topk64_kernel(
    const double* __restrict__ X, const float* __restrict__ sk,
    int* __restrict__ oidx, double* __restrict__ ow) {
  __shared__ double vsh[4][130];
  const int wid = threadIdx.x >> 6, lane = threadIdx.x & 63;
  const int rid = blockIdx.x * 4 + wid;  // (b*8+h)*4096 + t
  const int t = rid & 4095, h = (rid >> 12) & 7, b = rid >> 15;
  const double* xrow = X + ((size_t)b * SEQ + t) * DIMM + h * DH;
  vsh[wid][lane * 2] = xrow[lane * 2];
  vsh[wid][lane * 2 + 1] = xrow[lane * 2 + 1];
  const float* skh = sk + (size_t)h * NSLOTS * DH;
  double s0 = 0.0, s1 = 0.0;
#pragma unroll 8
  for (int d = 0; d < DH; d++) {
    const double v = vsh[wid][d];
    s0 += v * (double)skh[(size_t)lane * DH + d];
    s1 += v * (double)skh[(size_t)(lane + 64) * DH + d];
  }
  s0 *= SCALE64; s1 *= SCALE64;
  double selv = -1e300; int seli = 0;
  double v0 = s0, v1 = s1;
  for (int it = 0; it < 16; it++) {
    double m; int mi;
    if (v1 > v0) { m = v1; mi = lane + 64; } else { m = v0; mi = lane; }
#pragma unroll
    for (int off = 1; off < 64; off <<= 1) {
      const double om = __shfl_xor(m, off);
      const int oi = __shfl_xor(mi, off);
      if (om > m || (om == m && oi < mi)) { m = om; mi = oi; }
    }
    if (lane == it) { selv = m; seli = mi; }
    if (mi == lane) v0 = -1e300;
    if (mi == lane + 64) v1 = -1e300;
  }
  const double mx = __shfl(selv, 0);
  const float e = (lane < 16) ? expf((float)(selv - mx)) : 0.0f;
  double ss = (double)e;
  ss += __shfl_xor(ss, 1); ss += __shfl_xor(ss, 2);
  ss += __shfl_xor(ss, 4); ss += __shfl_xor(ss, 8);
  if (lane < 16) {
    ow[(size_t)rid * 16 + lane] = (double)e / ss;
    oidx[(size_t)rid * 16 + lane] = seli;
  }
}

// ---------------- dense per-chunk write delta, f64, stable order -----------
__global__ __launch_bounds__(512) void delta64_kernel(
    const int* __restrict__ wi, const double* __restrict__ ww,
    const double* __restrict__ V, double* __restrict__ delta) {
  __shared__ short slot_sh[4096];
  __shared__ double w_sh[4096];
  __shared__ u16 list[4096];
  __shared__ int cnt[NSLOTS], off_[NSLOTS];
  const int bid = blockIdx.x;
  const int c = bid & 15, h = (bid >> 4) & 7, b = bid >> 7;
  const int tid = threadIdx.x;
  if (tid < NSLOTS) cnt[tid] = 0;
  __syncthreads();
  const size_t ebase = ((size_t)(b * 8 + h) * SEQ + (size_t)c * CHUNK) * 16;
#pragma unroll
  for (int i = 0; i < 8; i++) {
    const int e = tid + i * 512;
    const int s = wi[ebase + e];
    slot_sh[e] = (short)s;
    w_sh[e] = ww[ebase + e];
    atomicAdd(&cnt[s], 1);
  }
  __syncthreads();
  if (tid == 0) {
    int a = 0;
    for (int s = 0; s < NSLOTS; s++) { off_[s] = a; a += cnt[s]; }
  }
  __syncthreads();
  if (tid < NSLOTS) {
    int p = off_[tid];
    const short me = (short)tid;
    for (int e = 0; e < 4096; e++)
      if (slot_sh[e] == me) list[p++] = (u16)e;
  }
  __syncthreads();
  const int slot = tid >> 2, dbase = (tid & 3) * 32;
  double acc[32] = {};
  const int start = off_[slot], len = cnt[slot];
  const double* vbase =
      V + ((size_t)b * SEQ + (size_t)c * CHUNK) * DIMM + h * DH + dbase;
  for (int i = 0; i < len; i++) {
    const int e = list[start + i];
    const double w = w_sh[e];
    const double* vp = vbase + (size_t)(e >> 4) * DIMM;
#pragma unroll
    for (int d = 0; d < 32; d++) acc[d] += w * vp[d];
  }
  double* dst = delta + ((size_t)bid * NSLOTS + slot) * DH + dbase;
#pragma unroll
  for (int d = 0; d < 32; d++) dst[d] = acc[d];
}

// ---------------- local attention scores, f64 dots -> f32 S ----------------
// block = (b,c,h,rq of 8): 32 q-rows, key tiles of 16.  LDS 49.9KB (<64KB).
__global__ __launch_bounds__(256) void attn_qk64(
    const double* __restrict__ Q, const double* __restrict__ Kb,
    float* __restrict__ S) {
  __shared__ double Qs[32][130];
  __shared__ double Ks[16][130];
  const int idx = blockIdx.x;
  const int rq = idx & 7, h = (idx >> 3) & 7, c = (idx >> 6) & 15, b = idx >> 10;
  const int tid = threadIdx.x;
  const size_t rowbase = (size_t)b * SEQ + (size_t)c * CHUNK;
  {  // stage Q: 32 rows x 128 dims, 16 elems/thread
    const int r = tid >> 3, d0 = (tid & 7) * 16;
    const double* qp = Q + (rowbase + rq * 32 + r) * DIMM + h * DH + d0;
#pragma unroll
    for (int j = 0; j < 16; j++) Qs[r][d0 + j] = qp[j];
  }
  const int row = tid >> 3;   // 0..31
  const int kq = tid & 7;     // 8 threads/row, 2 keys each
  const int row_abs = rq * 32 + row;
  float* srow =
      S + ((((size_t)(b * 16 + c) * 8 + h) * 256) + row_abs) * 256;
  const int ntile = (rq * 32 + 31) / 16 + 1;
  for (int kt = 0; kt < ntile; kt++) {
    __syncthreads();
    {  // stage K tile: 16 rows x 128 dims, 8 elems/thread
      const int r = tid >> 4, d0 = (tid & 15) * 8;
      const double* kp = Kb + (rowbase + kt * 16 + r) * DIMM + h * DH + d0;
#pragma unroll
      for (int j = 0; j < 8; j++) Ks[r][d0 + j] = kp[j];
    }
    __syncthreads();
#pragma unroll
    for (int kk = 0; kk < 2; kk++) {
      const int key = kq * 2 + kk;
      double s = 0.0;
#pragma unroll 8
      for (int d = 0; d < DH; d++) s += Qs[row][d] * Ks[key][d];
      const int kabs = kt * 16 + key;
      srow[kabs] = (kabs <= row_abs) ? (float)(s * SCALE64) : -1e30f;
    }
  }
}

// ---------------- row softmax over S (in place), causal-masked -------------
// grid = NB*NCHUNK*NHEADS*16 = 4096 blocks; decode uses bits [0:4)=g,
// [4:7)=h, [7:11)=c, [11)=b.  (Bug fix: previous decode skipped bit 7,
// leaving batch b=1 un-softmaxed.)
__global__ __launch_bounds__(256) void soft_kernel(float* __restrict__ S) {
  const int idx = blockIdx.x;
  const int g = idx & 15, h = (idx >> 4) & 7, c = (idx >> 7) & 15, b = idx >> 11;
  const int tid = threadIdx.x;
  const int r = tid >> 4, c2 = tid & 15;
  const int row = g * 16 + r;
  float* srow = S + ((((size_t)(b * 16 + c) * 8 + h) * 256) + row) * 256;
  float sv[16];
#pragma unroll
  for (int j = 0; j < 4; j++) {
    const float4 t = *(const float4*)(srow + c2 * 16 + j * 4);
    sv[4 * j] = t.x; sv[4 * j + 1] = t.y;
    sv[4 * j + 2] = t.z; sv[4 * j + 3] = t.w;
  }
#pragma unroll
  for (int j = 0; j < 16; j++)
    if (c2 * 16 + j > row) sv[j] = -1e30f;
  float m = -1e30f;
#pragma unroll
  for (int j = 0; j < 16; j++) m = fmaxf(m, sv[j]);
  m = fmaxf(m, __shfl_xor(m, 1)); m = fmaxf(m, __shfl_xor(m, 2));
  m = fmaxf(m, __shfl_xor(m, 4)); m = fmaxf(m, __shfl_xor(m, 8));
  float pv[16];
  double ss = 0.0;
#pragma unroll
  for (int j = 0; j < 16; j++) {
    pv[j] = __expf(sv[j] - m);
    ss += (double)pv[j];
  }
  ss += __shfl_xor(ss, 1); ss += __shfl_xor(ss, 2);
  ss += __shfl_xor(ss, 4); ss += __shfl_xor(ss, 8);
  const double inv = 1.0 / ss;
#pragma unroll
  for (int j = 0; j < 4; j++) {
    float4 t;
    t.x = (float)((double)pv[4 * j] * inv);
    t.y = (float)((double)pv[4 * j + 1] * inv);
    t.z = (float)((double)pv[4 * j + 2] * inv);
    t.w = (float)((double)pv[4 * j + 3] * inv);
    *(float4*)(srow + c2 * 16 + j * 4) = t;
  }
}

// ---------------- PV, f64 accumulate, writes local -------------------------
// block = (b,c,h,rq of 8): 32 q-rows, key tiles of 16.  LDS 18.8KB.
__global__ __launch_bounds__(256) void attn_pv64(
    const float* __restrict__ P, const double* __restrict__ V,
    double* __restrict__ outb) {
  __shared__ double Vs[16][130];
  __shared__ float Ps[32][17];
  const int idx = blockIdx.x;
  const int rq = idx & 7, h = (idx >> 3) & 7, c = (idx >> 6) & 15, b = idx >> 10;
  const int tid = threadIdx.x;
  const size_t rowbase = (size_t)b * SEQ + (size_t)c * CHUNK;
  const int row = tid >> 3, dq = (tid & 7) * 16;
  const int row_abs = rq * 32 + row;
  const size_t sbase = ((size_t)(b * 16 + c) * 8 + h) * 256;
  double acc[16] = {};
  const int ntile = (rq * 32 + 31) / 16 + 1;
  for (int kt = 0; kt < ntile; kt++) {
    __syncthreads();
    {  // stage V tile
      const int r = tid >> 4, d0 = (tid & 15) * 8;
      const double* vp = V + (rowbase + kt * 16 + r) * DIMM + h * DH + d0;
#pragma unroll
      for (int j = 0; j < 8; j++) Vs[r][d0 + j] = vp[j];
      // stage P tile: 32 rows x 16 keys, 2 floats/thread
      const int pr = tid >> 3, pk = (tid & 7) * 2;
      const float* pp = P + (sbase + rq * 32 + pr) * 256 + kt * 16 + pk;
      Ps[pr][pk] = pp[0];
      Ps[pr][pk + 1] = pp[1];
    }
    __syncthreads();
#pragma unroll
    for (int key = 0; key < 16; key++) {
      const double p = (double)Ps[row][key];
      const double* vrow = &Vs[key][dq];
#pragma unroll
      for (int d = 0; d < 16; d++) acc[d] += p * vrow[d];
    }
  }
  double* op = outb + (rowbase + row_abs) * DIMM + h * DH + dq;
#pragma unroll
  for (int d = 0; d < 16; d++) op[d] = acc[d];
}

// ---------------- sequential M recurrence, f64 ----------------
__global__ __launch_bounds__(256) void recur64_kernel(
    const int* __restrict__ ri, const double* __restrict__ rw,
    const double* __restrict__ delta, double* __restrict__ outb) {
  __shared__ double Msh[NSLOTS][17];
  const int bid = blockIdx.x;
  const int ds = bid & 7, h = (bid >> 3) & 7, b = bid >> 6;
  const int tid = threadIdx.x;
  for (int i = tid; i < NSLOTS * 17; i += 256) ((double*)Msh)[i] = 0.0;
  __syncthreads();
  for (int c = 0; c < NCHUNK; c++) {
    const size_t rbase =
        ((size_t)(b * 8 + h) * SEQ + (size_t)c * CHUNK + tid) * 16;
    double a[16] = {};
#pragma unroll
    for (int j = 0; j < 16; j++) {
      const int slot = ri[rbase + j];
      const double w = rw[rbase + j];
      const double* mp = &Msh[slot][0];
#pragma unroll
      for (int d = 0; d < 16; d++) a[d] += w * mp[d];
    }
    double* op = outb + ((size_t)b * SEQ + (size_t)c * CHUNK + tid) * DIMM +
                 h * DH + ds * 16;
#pragma unroll
    for (int d = 0; d < 16; d++) op[d] += a[d];
    __syncthreads();
    const int slot = tid >> 1, d8 = (tid & 1) * 8;
    const double* dp = delta +
        (((size_t)(b * 8 + h) * NCHUNK + c) * NSLOTS + slot) * DH + ds * 16 + d8;
#pragma unroll
    for (int d = 0; d < 8; d++)
      Msh[slot][d8 + d] = GAMMA64 * Msh[slot][d8 + d] + dp[d];
    __syncthreads();
  }
}

// ---------------- W[K][N] f32 -> WT[N][K] bf16 (final logits weights) ------
__global__ void transconv_kernel(const float* __restrict__ W,
                                 u16* __restrict__ WT, int K, int N) {
  __shared__ float tile[32][33];
  const int n0 = blockIdx.x * 32, k0 = blockIdx.y * 32;
  const int tx = threadIdx.x, ty = threadIdx.y;
#pragma unroll
  for (int i = 0; i < 4; i++)
    tile[ty + 8 * i][tx] = W[(size_t)(k0 + ty + 8 * i) * N + n0 + tx];
  __syncthreads();
#pragma unroll
  for (int i = 0; i < 4; i++)
    WT[(size_t)(n0 + ty + 8 * i) * K + k0 + tx] = f2bf(tile[tx][ty + 8 * i]);
}

// ---------------- bf16 MFMA GEMM for logits: C = A @ BT^T + bias -----------
template <bool BIAS>
__global__ __launch_bounds__(256) void gemm_kernel(
    const u16* __restrict__ A, const u16* __restrict__ B, float* __restrict__ C,
    const float* __restrict__ bias, int M, int N, int K) {
  __shared__ u16 As[128 * 32];
  __shared__ u16 Bs[128 * 32];
  const int tid = threadIdx.x;
  const int bn = blockIdx.x, bm = blockIdx.y;
  const int wid = tid >> 6, lane = tid & 63;
  const int wr = (wid >> 1) * 64, wc = (wid & 1) * 64;
  f32x4 acc[4][4] = {};
  const int row0 = tid >> 2;
  const int colb = (tid & 3) << 4;
  const char* A0 = (const char*)A + ((size_t)(bm * 128 + row0) * K) * 2 + colb;
  const char* A1 = (const char*)A + ((size_t)(bm * 128 + row0 + 64) * K) * 2 + colb;
  const char* B0 = (const char*)B + ((size_t)(bn * 128 + row0) * K) * 2 + colb;
  const char* B1 = (const char*)B + ((size_t)(bn * 128 + row0 + 64) * K) * 2 + colb;
  char* lA0 = (char*)As + (tid & 192) * 16;
  char* lB0 = (char*)Bs + (tid & 192) * 16;
  const char* pa = (const char*)As + wr * 64 + (lane & 15) * 64 + (lane >> 4) * 16;
  const char* pb = (const char*)Bs + wc * 64 + (lane & 15) * 64 + (lane >> 4) * 16;
  for (int k0 = 0; k0 < K; k0 += 32) {
    const size_t kb = (size_t)k0 * 2;
    gld16(lA0, A0 + kb);
    gld16(lA0 + 4096, A1 + kb);
    gld16(lB0, B0 + kb);
    gld16(lB0 + 4096, B1 + kb);
    __syncthreads();
    s16x8 af[4], bf[4];
#pragma unroll
    for (int m = 0; m < 4; m++) af[m] = *(const s16x8*)(pa + m * 1024);
#pragma unroll
    for (int n = 0; n < 4; n++) bf[n] = *(const s16x8*)(pb + n * 1024);
#pragma unroll
    for (int m = 0; m < 4; m++)
#pragma unroll
      for (int n = 0; n < 4; n++) acc[m][n] = mfma16(af[m], bf[n], acc[m][n]);
    __syncthreads();
  }
#pragma unroll
  for (int m = 0; m < 4; m++)
#pragma unroll
    for (int n = 0; n < 4; n++)
#pragma unroll
      for (int j = 0; j < 4; j++) {
        const int r = bm * 128 + wr + m * 16 + (lane >> 4) * 4 + j;
        const int c = bn * 128 + wc + n * 16 + (lane & 15);
        float v = acc[m][n][j];
        if (BIAS) v += bias[c];
        C[(size_t)r * N + c] = v;
      }
}

extern "C" void kernel_launch(void* const* d_in, const int* in_sizes, int n_in,
                              void* d_out, int out_size, void* d_ws,
                              size_t ws_size, hipStream_t stream) {
  (void)in_sizes; (void)n_in; (void)out_size; (void)ws_size;
  const int* tokens = (const int*)d_in[0];
  const float* embed = (const float*)d_in[1];
  const float* Wq = (const float*)d_in[2];
  const float* Wk = (const float*)d_in[3];
  const float* Wv = (const float*)d_in[4];
  const float* Wo = (const float*)d_in[5];
  const float* slot_keys = (const float*)d_in[6];
  const float* ln_g = (const float*)d_in[7];
  const float* ln_b = (const float*)d_in[8];
  const float* fg = (const float*)d_in[9];
  const float* fb = (const float*)d_in[10];
  const float* Wout = (const float*)d_in[11];
  const float* bout = (const float*)d_in[12];
  float* out = (float*)d_out;

  char* p = (char*)d_ws;
  auto alloc = [&](size_t bytes) -> char* {
    char* r = p;
    p += (bytes + 255) & ~(size_t)255;
    return r;
  };
  const size_t RD = (size_t)NROWS * DIMM;
  double* hidden64 = (double*)alloc(RD * 8);
  double* xn64 = (double*)alloc(RD * 8);      // aliased as local64 later
  double* q64 = (double*)alloc(RD * 8);       // aliased as xnb (bf16) at end
  double* k64 = (double*)alloc(RD * 8);       // aliased as WoutT (bf16) at end
  double* v64 = (double*)alloc(RD * 8);
  float* S = (float*)alloc((size_t)NB * NCHUNK * NHEADS * 256 * 256 * 4);
  double* delta64 =
      (double*)alloc((size_t)NB * NHEADS * NCHUNK * NSLOTS * DH * 8);
  int* ri = (int*)alloc((size_t)65536 * 16 * 4);
  int* wi = (int*)alloc((size_t)65536 * 16 * 4);
  double* rw64 = (double*)alloc((size_t)65536 * 16 * 8);
  double* ww64 = (double*)alloc((size_t)65536 * 16 * 8);

  double* local64 = xn64;  // xn64 dead once q/k/v are computed
  u16* xnb = (u16*)q64;    // used only after layer-2 attn
  u16* WoutT = (u16*)k64;  // used only after layer-2 attn

  embed64_kernel<<<NROWS, 256, 0, stream>>>(tokens, embed, hidden64);

  const dim3 g64(DIMM / 64, NROWS / 128);
  for (int l = 0; l < 2; l++) {
    const size_t wo = (size_t)l * DIMM * DIMM;
    ln64_kernel<0><<<NROWS, 256, 0, stream>>>(hidden64, ln_g + l * DIMM,
                                              ln_b + l * DIMM, xn64, nullptr);
    gemm64_kernel<false><<<g64, 256, 0, stream>>>(xn64, Wq + wo, q64, nullptr,
                                                  NROWS, DIMM, DIMM);
    gemm64_kernel<false><<<g64, 256, 0, stream>>>(xn64, Wk + wo, k64, nullptr,
                                                  NROWS, DIMM, DIMM);
    gemm64_kernel<false><<<g64, 256, 0, stream>>>(xn64, Wv + wo, v64, nullptr,
                                                  NROWS, DIMM, DIMM);
    const float* skl = slot_keys + (size_t)l * NHEADS * NSLOTS * DH;
    topk64_kernel<<<16384, 256, 0, stream>>>(q64, skl, ri, rw64);
    topk64_kernel<<<16384, 256, 0, stream>>>(k64, skl, wi, ww64);
    delta64_kernel<<<NB * NHEADS * NCHUNK, 512, 0, stream>>>(wi, ww64, v64,
                                                             delta64);
    attn_qk64<<<NB * NCHUNK * NHEADS * 8, 256, 0, stream>>>(q64, k64, S);
    soft_kernel<<<NB * NCHUNK * NHEADS * 16, 256, 0, stream>>>(S);
    attn_pv64<<<NB * NCHUNK * NHEADS * 8, 256, 0, stream>>>(S, v64, local64);
    recur64_kernel<<<NB * NHEADS * 8, 256, 0, stream>>>(ri, rw64, delta64,
                                                        local64);
    gemm64_kernel<true><<<g64, 256, 0, stream>>>(local64, Wo + wo, hidden64,
                                                 hidden64, NROWS, DIMM, DIMM);
  }
  transconv_kernel<<<dim3(NVOCAB / 32, DIMM / 32), dim3(32, 8), 0, stream>>>(
      Wout, WoutT, DIMM, NVOCAB);
  ln64_kernel<1><<<NROWS, 256, 0, stream>>>(hidden64, fg, fb, nullptr, xnb);
  gemm_kernel<true><<<dim3(NVOCAB / 128, NROWS / 128), 256, 0, stream>>>(
      xnb, WoutT, out, bout, NROWS, NVOCAB, DIMM);
}

// Round 6
// 8753.991 us; speedup vs baseline: 1.2050x; 1.2050x over previous
//
#include <hip/hip_runtime.h>

#define DIMM 1024
#define NHEADS 8
#define DH 128
#define NSLOTS 128
#define CHUNK 256
#define NCHUNK 16
#define NB 2
#define SEQ 4096
#define NROWS (NB * SEQ)
#define NVOCAB 32000
#define GAMMA64 0.9
#define SCALE64 0.08838834764831845

typedef unsigned short u16;
typedef __attribute__((ext_vector_type(4))) float f32x4;
typedef __attribute__((ext_vector_type(8))) short s16x8;

struct alignas(8) u16x4 { u16 x, y, z, w; };

__device__ __forceinline__ u16 f2bf(float f) {
  union { float f; unsigned u; } v; v.f = f;
  return (u16)((v.u + 0x7FFFu + ((v.u >> 16) & 1u)) >> 16);
}
__device__ __forceinline__ float bf2f(u16 u) {
  union { unsigned u; float f; } v; v.u = ((unsigned)u) << 16; return v.f;
}
// exact 3-way bf16 split of an f32 (hi+mid+lo reproduces all 24 mantissa bits)
__device__ __forceinline__ void split3s(float x, u16& h, u16& m, u16& l) {
  h = f2bf(x); float r = x - bf2f(h);
  m = f2bf(r); float r2 = r - bf2f(m);
  l = f2bf(r2);
}

__device__ __forceinline__ void gld16(void* lds, const void* g) {
  __builtin_amdgcn_global_load_lds(
      (const __attribute__((address_space(1))) unsigned*)g,
      (__attribute__((address_space(3))) unsigned*)lds, 16, 0, 0);
}
__device__ __forceinline__ f32x4 mfma16(s16x8 a, s16x8 b, f32x4 c) {
  return __builtin_amdgcn_mfma_f32_16x16x32_bf16(a, b, c, 0, 0, 0);
}

// ---------------- embedding gather -> f64 ----------------
__global__ __launch_bounds__(256) void embed64_kernel(
    const int* __restrict__ tok, const float* __restrict__ emb,
    double* __restrict__ hid) {
  const int row = blockIdx.x;
  const int t = tok[row];
  const float4 v = ((const float4*)(emb + (size_t)t * DIMM))[threadIdx.x];
  double* o = hid + (size_t)row * DIMM + threadIdx.x * 4;
  o[0] = (double)v.x; o[1] = (double)v.y; o[2] = (double)v.z; o[3] = (double)v.w;
}

// ---------------- f64 two-pass layernorm ----------------
template <int BF16OUT>
__global__ __launch_bounds__(256) void ln64_kernel(
    const double* __restrict__ x, const float* __restrict__ g,
    const float* __restrict__ bb, double* __restrict__ o64,
    u16* __restrict__ obf) {
  const int row = blockIdx.x, tid = threadIdx.x;
  const double* xr = x + (size_t)row * DIMM + tid * 4;
  const double v0 = xr[0], v1 = xr[1], v2 = xr[2], v3 = xr[3];
  __shared__ double red[4];
  double s1 = v0 + v1 + v2 + v3;
#pragma unroll
  for (int off = 32; off >= 1; off >>= 1) s1 += __shfl_xor(s1, off);
  if ((tid & 63) == 0) red[tid >> 6] = s1;
  __syncthreads();
  const double mu = (red[0] + red[1] + red[2] + red[3]) * (1.0 / DIMM);
  __syncthreads();
  const double d0 = v0 - mu, d1 = v1 - mu, d2 = v2 - mu, d3 = v3 - mu;
  double s2 = d0 * d0 + d1 * d1 + d2 * d2 + d3 * d3;
#pragma unroll
  for (int off = 32; off >= 1; off >>= 1) s2 += __shfl_xor(s2, off);
  if ((tid & 63) == 0) red[tid >> 6] = s2;
  __syncthreads();
  const double var = (red[0] + red[1] + red[2] + red[3]) * (1.0 / DIMM);
  const double rs = 1.0 / sqrt(var + 1e-5);
  const float4 g4 = ((const float4*)g)[tid];
  const float4 b4 = ((const float4*)bb)[tid];
  const double y0 = d0 * rs * (double)g4.x + (double)b4.x;
  const double y1 = d1 * rs * (double)g4.y + (double)b4.y;
  const double y2 = d2 * rs * (double)g4.z + (double)b4.z;
  const double y3 = d3 * rs * (double)g4.w + (double)b4.w;
  if (BF16OUT) {
    u16x4 r;
    r.x = f2bf((float)y0); r.y = f2bf((float)y1);
    r.z = f2bf((float)y2); r.w = f2bf((float)y3);
    ((u16x4*)(obf + (size_t)row * DIMM))[tid] = r;
  } else {
    double* o = o64 + (size_t)row * DIMM + tid * 4;
    o[0] = y0; o[1] = y1; o[2] = y2; o[3] = y3;
  }
}

// ---------------- f64 GEMM: C[M][N] = A[M][K](f64) @ W[K][N](f32) ----------
// 128x64 block tile, BK=32, 256 threads, 8x4 per thread.  LDS 49.6KB.
template <bool RES>
__global__ __launch_bounds__(256) void gemm64_kernel(
    const double* __restrict__ A, const float* __restrict__ W,
    double* __restrict__ C, const double* __restrict__ Cres, int M, int N,
    int K) {
  __shared__ double AsT[32][129];
  __shared__ double Ws[32][65];
  const int tid = threadIdx.x, bn = blockIdx.x, bm = blockIdx.y;
  const int tx = tid & 15, ty = tid >> 4;
  double acc[8][4] = {};
  const int ar = tid >> 1, kh = (tid & 1) * 16;
  const int wk = tid >> 3, wn = (tid & 7) * 8;
  const double* Ap = A + (size_t)(bm * 128 + ar) * K + kh;
  const float* Wp = W + (size_t)wk * N + bn * 64 + wn;

  for (int k0 = 0; k0 < K; k0 += 32) {
    double av[16];
    const double2* ap2 = (const double2*)(Ap + k0);
#pragma unroll
    for (int j = 0; j < 8; j++) {
      const double2 t = ap2[j];
      av[2 * j] = t.x; av[2 * j + 1] = t.y;
    }
    const float4 w0 = *(const float4*)(Wp + (size_t)k0 * N);
    const float4 w1 = *(const float4*)(Wp + (size_t)k0 * N + 4);
    __syncthreads();
#pragma unroll
    for (int j = 0; j < 16; j++) AsT[kh + j][ar] = av[j];
    Ws[wk][wn + 0] = (double)w0.x; Ws[wk][wn + 1] = (double)w0.y;
    Ws[wk][wn + 2] = (double)w0.z; Ws[wk][wn + 3] = (double)w0.w;
    Ws[wk][wn + 4] = (double)w1.x; Ws[wk][wn + 5] = (double)w1.y;
    Ws[wk][wn + 6] = (double)w1.z; Ws[wk][wn + 7] = (double)w1.w;
    __syncthreads();
#pragma unroll 4
    for (int kk = 0; kk < 32; kk++) {
      double a[8], b[4];
#pragma unroll
      for (int i = 0; i < 8; i++) a[i] = AsT[kk][ty * 8 + i];
#pragma unroll
      for (int j = 0; j < 4; j++) b[j] = Ws[kk][tx * 4 + j];
#pragma unroll
      for (int i = 0; i < 8; i++)
#pragma unroll
        for (int j = 0; j < 4; j++) acc[i][j] += a[i] * b[j];
    }
  }
#pragma unroll
  for (int i = 0; i < 8; i++) {
    const size_t r = (size_t)(bm * 128 + ty * 8 + i) * N + bn * 64 + tx * 4;
#pragma unroll
    for (int j = 0; j < 4; j++) {
      double v = acc[i][j];
      if (RES) v += Cres[r + j];
      C[r + j] = v;
    }
  }
}

// ---------------- W[K][N] f32 -> WT[N][K] split3 bf16 ----------------
__global__ void transconv3_kernel(const float* __restrict__ W,
                                  u16* __restrict__ WTh, u16* __restrict__ WTm,
                                  u16* __restrict__ WTl, int K, int N) {
  __shared__ float tile[32][33];
  const int n0 = blockIdx.x * 32, k0 = blockIdx.y * 32;
  const int tx = threadIdx.x, ty = threadIdx.y;
#pragma unroll
  for (int i = 0; i < 4; i++)
    tile[ty + 8 * i][tx] = W[(size_t)(k0 + ty + 8 * i) * N + n0 + tx];
  __syncthreads();
#pragma unroll
  for (int i = 0; i < 4; i++) {
    u16 h, m, l;
    split3s(tile[tx][ty + 8 * i], h, m, l);
    const size_t o = (size_t)(n0 + ty + 8 * i) * K + k0 + tx;
    WTh[o] = h; WTm[o] = m; WTl[o] = l;
  }
}

// ---------------- f64 -> split3 bf16 elementwise ----------------
__global__ __launch_bounds__(256) void cvt3_64_kernel(
    const double* __restrict__ in, u16* __restrict__ oh, u16* __restrict__ om,
    u16* __restrict__ ol) {
  const size_t i = (size_t)blockIdx.x * 256 + threadIdx.x;
  const double* p = in + i * 4;
  u16x4 rh, rm, rl;
  split3s((float)p[0], rh.x, rm.x, rl.x);
  split3s((float)p[1], rh.y, rm.y, rl.y);
  split3s((float)p[2], rh.z, rm.z, rl.z);
  split3s((float)p[3], rh.w, rm.w, rl.w);
  ((u16x4*)oh)[i] = rh; ((u16x4*)om)[i] = rm; ((u16x4*)ol)[i] = rl;
}

// ---------------- split3 f32-faithful GEMM -> f64 out: C = A @ BT^T (+res) -
// A,B as exact (hi,mid,lo) bf16 triples; 6 MFMA cross-products.  LDS 48KB.
template <bool RES>
__global__ __launch_bounds__(256) void gemm3d_kernel(
    const u16* __restrict__ Ah, const u16* __restrict__ Am,
    const u16* __restrict__ Al, const u16* __restrict__ Bh,
    const u16* __restrict__ Bm, const u16* __restrict__ Bl,
    double* __restrict__ C, const double* __restrict__ Cres, int M, int N,
    int K) {
  __shared__ u16 lds[6 * 128 * 32];
  const int tid = threadIdx.x;
  const int bn = blockIdx.x, bm = blockIdx.y;
  const int wid = tid >> 6, lane = tid & 63;
  const int wr = (wid >> 1) * 64, wc = (wid & 1) * 64;
  f32x4 acc[4][4] = {};
  const int row0 = tid >> 2;
  const int colb = (tid & 3) << 4;
  const u16* Gs[6] = {Ah, Am, Al, Bh, Bm, Bl};
  const char* g0[6];
  const char* g1[6];
  char* lb[6];
#pragma unroll
  for (int i = 0; i < 6; i++) {
    const int rbase = (i < 3 ? bm : bn) * 128;
    g0[i] = (const char*)Gs[i] + ((size_t)(rbase + row0) * K) * 2 + colb;
    g1[i] = (const char*)Gs[i] + ((size_t)(rbase + row0 + 64) * K) * 2 + colb;
    lb[i] = (char*)lds + i * 8192 + (tid & 192) * 16;
  }
  const int fo = (lane & 15) * 64 + (lane >> 4) * 16;
  const char* paH = (const char*)lds + 0 + wr * 64 + fo;
  const char* paM = paH + 8192;
  const char* paL = paH + 16384;
  const char* pbH = (const char*)lds + 24576 + wc * 64 + fo;
  const char* pbM = pbH + 8192;
  const char* pbL = pbH + 16384;

  for (int k0 = 0; k0 < K; k0 += 32) {
    const size_t kb = (size_t)k0 * 2;
#pragma unroll
    for (int i = 0; i < 6; i++) {
      gld16(lb[i], g0[i] + kb);
      gld16(lb[i] + 4096, g1[i] + kb);
    }
    __syncthreads();
    s16x8 bh[4], bm_[4], bl[4];
#pragma unroll
    for (int n = 0; n < 4; n++) {
      bh[n] = *(const s16x8*)(pbH + n * 1024);
      bm_[n] = *(const s16x8*)(pbM + n * 1024);
      bl[n] = *(const s16x8*)(pbL + n * 1024);
    }
#pragma unroll
    for (int m = 0; m < 4; m++) {
      const s16x8 ah = *(const s16x8*)(paH + m * 1024);
      const s16x8 am = *(const s16x8*)(paM + m * 1024);
      const s16x8 al = *(const s16x8*)(paL + m * 1024);
#pragma unroll
      for (int n = 0; n < 4; n++) {
        f32x4 t = acc[m][n];
        t = mfma16(al, bh[n], t);
        t = mfma16(ah, bl[n], t);
        t = mfma16(am, bm_[n], t);
        t = mfma16(am, bh[n], t);
        t = mfma16(ah, bm_[n], t);
        t = mfma16(ah, bh[n], t);
        acc[m][n] = t;
      }
    }
    __syncthreads();
  }
#pragma unroll
  for (int m = 0; m < 4; m++)
#pragma unroll
    for (int n = 0; n < 4; n++)
#pragma unroll
      for (int j = 0; j < 4; j++) {
        const int r = bm * 128 + wr + m * 16 + (lane >> 4) * 4 + j;
        const int c = bn * 128 + wc + n * 16 + (lane & 15);
        double v = (double)acc[m][n][j];
        if (RES) v += Cres[(size_t)r * N + c];
        C[(size_t)r * N + c] = v;
      }
}

// ---------------- top-16 of 128 slot scores, full f64 ----------------
__global__ __launch_bounds__(256) void topk64_kernel(
    const double* __restrict__ X, const float* __restrict__ sk,
    int* __restrict__ oidx, double* __restrict__ ow) {
  __shared__ double vsh[4][130];
  const int wid = threadIdx.x >> 6, lane = threadIdx.x & 63;
  const int rid = blockIdx.x * 4 + wid;  // (b*8+h)*4096 + t
  const int t = rid & 4095, h = (rid >> 12) & 7, b = rid >> 15;
  const double* xrow = X + ((size_t)b * SEQ + t) * DIMM + h * DH;
  vsh[wid][lane * 2] = xrow[lane * 2];
  vsh[wid][lane * 2 + 1] = xrow[lane * 2 + 1];
  const float* skh = sk + (size_t)h * NSLOTS * DH;
  double s0 = 0.0, s1 = 0.0;
#pragma unroll 8
  for (int d = 0; d < DH; d++) {
    const double v = vsh[wid][d];
    s0 += v * (double)skh[(size_t)lane * DH + d];
    s1 += v * (double)skh[(size_t)(lane + 64) * DH + d];
  }
  s0 *= SCALE64; s1 *= SCALE64;
  double selv = -1e300; int seli = 0;
  double v0 = s0, v1 = s1;
  for (int it = 0; it < 16; it++) {
    double m; int mi;
    if (v1 > v0) { m = v1; mi = lane + 64; } else { m = v0; mi = lane; }
#pragma unroll
    for (int off = 1; off < 64; off <<= 1) {
      const double om = __shfl_xor(m, off);
      const int oi = __shfl_xor(mi, off);
      if (om > m || (om == m && oi < mi)) { m = om; mi = oi; }
    }
    if (lane == it) { selv = m; seli = mi; }
    if (mi == lane) v0 = -1e300;
    if (mi == lane + 64) v1 = -1e300;
  }
  const double mx = __shfl(selv, 0);
  const float e = (lane < 16) ? expf((float)(selv - mx)) : 0.0f;
  double ss = (double)e;
  ss += __shfl_xor(ss, 1); ss += __shfl_xor(ss, 2);
  ss += __shfl_xor(ss, 4); ss += __shfl_xor(ss, 8);
  if (lane < 16) {
    ow[(size_t)rid * 16 + lane] = (double)e / ss;
    oidx[(size_t)rid * 16 + lane] = seli;
  }
}

// ---------------- dense per-chunk write delta, f64, stable order -----------
__global__ __launch_bounds__(512) void delta64_kernel(
    const int* __restrict__ wi, const double* __restrict__ ww,
    const double* __restrict__ V, double* __restrict__ delta) {
  __shared__ short slot_sh[4096];
  __shared__ double w_sh[4096];
  __shared__ u16 list[4096];
  __shared__ int cnt[NSLOTS], off_[NSLOTS];
  const int bid = blockIdx.x;
  const int c = bid & 15, h = (bid >> 4) & 7, b = bid >> 7;
  const int tid = threadIdx.x;
  if (tid < NSLOTS) cnt[tid] = 0;
  __syncthreads();
  const size_t ebase = ((size_t)(b * 8 + h) * SEQ + (size_t)c * CHUNK) * 16;
#pragma unroll
  for (int i = 0; i < 8; i++) {
    const int e = tid + i * 512;
    const int s = wi[ebase + e];
    slot_sh[e] = (short)s;
    w_sh[e] = ww[ebase + e];
    atomicAdd(&cnt[s], 1);
  }
  __syncthreads();
  if (tid == 0) {
    int a = 0;
    for (int s = 0; s < NSLOTS; s++) { off_[s] = a; a += cnt[s]; }
  }
  __syncthreads();
  if (tid < NSLOTS) {
    int p = off_[tid];
    const short me = (short)tid;
    for (int e = 0; e < 4096; e++)
      if (slot_sh[e] == me) list[p++] = (u16)e;
  }
  __syncthreads();
  const int slot = tid >> 2, dbase = (tid & 3) * 32;
  double acc[32] = {};
  const int start = off_[slot], len = cnt[slot];
  const double* vbase =
      V + ((size_t)b * SEQ + (size_t)c * CHUNK) * DIMM + h * DH + dbase;
  for (int i = 0; i < len; i++) {
    const int e = list[start + i];
    const double w = w_sh[e];
    const double* vp = vbase + (size_t)(e >> 4) * DIMM;
#pragma unroll
    for (int d = 0; d < 32; d++) acc[d] += w * vp[d];
  }
  double* dst = delta + ((size_t)bid * NSLOTS + slot) * DH + dbase;
#pragma unroll
  for (int d = 0; d < 32; d++) dst[d] = acc[d];
}

// ---------------- local attention scores, f64 dots -> f32 S ----------------
// block = (b,c,h,rq of 8): 32 q-rows, key tiles of 16.  LDS 49.9KB (<64KB).
__global__ __launch_bounds__(256) void attn_qk64(
    const double* __restrict__ Q, const double* __restrict__ Kb,
    float* __restrict__ S) {
  __shared__ double Qs[32][130];
  __shared__ double Ks[16][130];
  const int idx = blockIdx.x;
  const int rq = idx & 7, h = (idx >> 3) & 7, c = (idx >> 6) & 15, b = idx >> 10;
  const int tid = threadIdx.x;
  const size_t rowbase = (size_t)b * SEQ + (size_t)c * CHUNK;
  {  // stage Q: 32 rows x 128 dims, 16 elems/thread
    const int r = tid >> 3, d0 = (tid & 7) * 16;
    const double* qp = Q + (rowbase + rq * 32 + r) * DIMM + h * DH + d0;
#pragma unroll
    for (int j = 0; j < 16; j++) Qs[r][d0 + j] = qp[j];
  }
  const int row = tid >> 3;   // 0..31
  const int kq = tid & 7;     // 8 threads/row, 2 keys each
  const int row_abs = rq * 32 + row;
  float* srow =
      S + ((((size_t)(b * 16 + c) * 8 + h) * 256) + row_abs) * 256;
  const int ntile = (rq * 32 + 31) / 16 + 1;
  for (int kt = 0; kt < ntile; kt++) {
    __syncthreads();
    {  // stage K tile: 16 rows x 128 dims, 8 elems/thread
      const int r = tid >> 4, d0 = (tid & 15) * 8;
      const double* kp = Kb + (rowbase + kt * 16 + r) * DIMM + h * DH + d0;
#pragma unroll
      for (int j = 0; j < 8; j++) Ks[r][d0 + j] = kp[j];
    }
    __syncthreads();
#pragma unroll
    for (int kk = 0; kk < 2; kk++) {
      const int key = kq * 2 + kk;
      double s = 0.0;
#pragma unroll 8
      for (int d = 0; d < DH; d++) s += Qs[row][d] * Ks[key][d];
      const int kabs = kt * 16 + key;
      srow[kabs] = (kabs <= row_abs) ? (float)(s * SCALE64) : -1e30f;
    }
  }
}

// ---------------- row softmax over S (in place), causal-masked -------------
__global__ __launch_bounds__(256) void soft_kernel(float* __restrict__ S) {
  const int idx = blockIdx.x;
  const int g = idx & 15, h = (idx >> 4) & 7, c = (idx >> 7) & 15, b = idx >> 11;
  const int tid = threadIdx.x;
  const int r = tid >> 4, c2 = tid & 15;
  const int row = g * 16 + r;
  float* srow = S + ((((size_t)(b * 16 + c) * 8 + h) * 256) + row) * 256;
  float sv[16];
#pragma unroll
  for (int j = 0; j < 4; j++) {
    const float4 t = *(const float4*)(srow + c2 * 16 + j * 4);
    sv[4 * j] = t.x; sv[4 * j + 1] = t.y;
    sv[4 * j + 2] = t.z; sv[4 * j + 3] = t.w;
  }
#pragma unroll
  for (int j = 0; j < 16; j++)
    if (c2 * 16 + j > row) sv[j] = -1e30f;
  float m = -1e30f;
#pragma unroll
  for (int j = 0; j < 16; j++) m = fmaxf(m, sv[j]);
  m = fmaxf(m, __shfl_xor(m, 1)); m = fmaxf(m, __shfl_xor(m, 2));
  m = fmaxf(m, __shfl_xor(m, 4)); m = fmaxf(m, __shfl_xor(m, 8));
  float pv[16];
  double ss = 0.0;
#pragma unroll
  for (int j = 0; j < 16; j++) {
    pv[j] = __expf(sv[j] - m);
    ss += (double)pv[j];
  }
  ss += __shfl_xor(ss, 1); ss += __shfl_xor(ss, 2);
  ss += __shfl_xor(ss, 4); ss += __shfl_xor(ss, 8);
  const double inv = 1.0 / ss;
#pragma unroll
  for (int j = 0; j < 4; j++) {
    float4 t;
    t.x = (float)((double)pv[4 * j] * inv);
    t.y = (float)((double)pv[4 * j + 1] * inv);
    t.z = (float)((double)pv[4 * j + 2] * inv);
    t.w = (float)((double)pv[4 * j + 3] * inv);
    *(float4*)(srow + c2 * 16 + j * 4) = t;
  }
}

// ---------------- PV, f64 accumulate, writes local -------------------------
__global__ __launch_bounds__(256) void attn_pv64(
    const float* __restrict__ P, const double* __restrict__ V,
    double* __restrict__ outb) {
  __shared__ double Vs[16][130];
  __shared__ float Ps[32][17];
  const int idx = blockIdx.x;
  const int rq = idx & 7, h = (idx >> 3) & 7, c = (idx >> 6) & 15, b = idx >> 10;
  const int tid = threadIdx.x;
  const size_t rowbase = (size_t)b * SEQ + (size_t)c * CHUNK;
  const int row = tid >> 3, dq = (tid & 7) * 16;
  const int row_abs = rq * 32 + row;
  const size_t sbase = ((size_t)(b * 16 + c) * 8 + h) * 256;
  double acc[16] = {};
  const int ntile = (rq * 32 + 31) / 16 + 1;
  for (int kt = 0; kt < ntile; kt++) {
    __syncthreads();
    {  // stage V tile
      const int r = tid >> 4, d0 = (tid & 15) * 8;
      const double* vp = V + (rowbase + kt * 16 + r) * DIMM + h * DH + d0;
#pragma unroll
      for (int j = 0; j < 8; j++) Vs[r][d0 + j] = vp[j];
      // stage P tile: 32 rows x 16 keys, 2 floats/thread
      const int pr = tid >> 3, pk = (tid & 7) * 2;
      const float* pp = P + (sbase + rq * 32 + pr) * 256 + kt * 16 + pk;
      Ps[pr][pk] = pp[0];
      Ps[pr][pk + 1] = pp[1];
    }
    __syncthreads();
#pragma unroll
    for (int key = 0; key < 16; key++) {
      const double p = (double)Ps[row][key];
      const double* vrow = &Vs[key][dq];
#pragma unroll
      for (int d = 0; d < 16; d++) acc[d] += p * vrow[d];
    }
  }
  double* op = outb + (rowbase + row_abs) * DIMM + h * DH + dq;
#pragma unroll
  for (int d = 0; d < 16; d++) op[d] = acc[d];
}

// ---------------- sequential M recurrence, f64 ----------------
__global__ __launch_bounds__(256) void recur64_kernel(
    const int* __restrict__ ri, const double* __restrict__ rw,
    const double* __restrict__ delta, double* __restrict__ outb) {
  __shared__ double Msh[NSLOTS][17];
  const int bid = blockIdx.x;
  const int ds = bid & 7, h = (bid >> 3) & 7, b = bid >> 6;
  const int tid = threadIdx.x;
  for (int i = tid; i < NSLOTS * 17; i += 256) ((double*)Msh)[i] = 0.0;
  __syncthreads();
  for (int c = 0; c < NCHUNK; c++) {
    const size_t rbase =
        ((size_t)(b * 8 + h) * SEQ + (size_t)c * CHUNK + tid) * 16;
    double a[16] = {};
#pragma unroll
    for (int j = 0; j < 16; j++) {
      const int slot = ri[rbase + j];
      const double w = rw[rbase + j];
      const double* mp = &Msh[slot][0];
#pragma unroll
      for (int d = 0; d < 16; d++) a[d] += w * mp[d];
    }
    double* op = outb + ((size_t)b * SEQ + (size_t)c * CHUNK + tid) * DIMM +
                 h * DH + ds * 16;
#pragma unroll
    for (int d = 0; d < 16; d++) op[d] += a[d];
    __syncthreads();
    const int slot = tid >> 1, d8 = (tid & 1) * 8;
    const double* dp = delta +
        (((size_t)(b * 8 + h) * NCHUNK + c) * NSLOTS + slot) * DH + ds * 16 + d8;
#pragma unroll
    for (int d = 0; d < 8; d++)
      Msh[slot][d8 + d] = GAMMA64 * Msh[slot][d8 + d] + dp[d];
    __syncthreads();
  }
}

// ---------------- W[K][N] f32 -> WT[N][K] bf16 (final logits weights) ------
__global__ void transconv_kernel(const float* __restrict__ W,
                                 u16* __restrict__ WT, int K, int N) {
  __shared__ float tile[32][33];
  const int n0 = blockIdx.x * 32, k0 = blockIdx.y * 32;
  const int tx = threadIdx.x, ty = threadIdx.y;
#pragma unroll
  for (int i = 0; i < 4; i++)
    tile[ty + 8 * i][tx] = W[(size_t)(k0 + ty + 8 * i) * N + n0 + tx];
  __syncthreads();
#pragma unroll
  for (int i = 0; i < 4; i++)
    WT[(size_t)(n0 + ty + 8 * i) * K + k0 + tx] = f2bf(tile[tx][ty + 8 * i]);
}

// ---------------- bf16 MFMA GEMM for logits: C = A @ BT^T + bias -----------
// GROUP_N=16 supertile remap: within each group of 16 bn-panels, bm runs
// fastest -> working set = 16 B-panels (4.2MB) + A (16.8MB); B fetched once.
template <bool BIAS>
__global__ __launch_bounds__(256) void gemm_kernel(
    const u16* __restrict__ A, const u16* __restrict__ B, float* __restrict__ C,
    const float* __restrict__ bias, int M, int N, int K) {
  __shared__ u16 As[128 * 32];
  __shared__ u16 Bs[128 * 32];
  const int tid = threadIdx.x;
  const int lid = blockIdx.y * gridDim.x + blockIdx.x;
  const int npm = M / 128;            // 64
  const int ngrid = N / 128;          // 250
  const int GN = 16;
  const int ppg = GN * npm;           // 1024
  const int gid = lid / ppg;
  const int first_n = gid * GN;
  const int gsz = min(GN, ngrid - first_n);
  const int local = lid - gid * ppg;
  const int bn = first_n + local % gsz;
  const int bm = local / gsz;
  const int wid = tid >> 6, lane = tid & 63;
  const int wr = (wid >> 1) * 64, wc = (wid & 1) * 64;
  f32x4 acc[4][4] = {};
  const int row0 = tid >> 2;
  const int colb = (tid & 3) << 4;
  const char* A0 = (const char*)A + ((size_t)(bm * 128 + row0) * K) * 2 + colb;
  const char* A1 = (const char*)A + ((size_t)(bm * 128 + row0 + 64) * K) * 2 + colb;
  const char* B0 = (const char*)B + ((size_t)(bn * 128 + row0) * K) * 2 + colb;
  const char* B1 = (const char*)B + ((size_t)(bn * 128 + row0 + 64) * K) * 2 + colb;
  char* lA0 = (char*)As + (tid & 192) * 16;
  char* lB0 = (char*)Bs + (tid & 192) * 16;
  const char* pa = (const char*)As + wr * 64 + (lane & 15) * 64 + (lane >> 4) * 16;
  const char* pb = (const char*)Bs + wc * 64 + (lane & 15) * 64 + (lane >> 4) * 16;
  for (int k0 = 0; k0 < K; k0 += 32) {
    const size_t kb = (size_t)k0 * 2;
    gld16(lA0, A0 + kb);
    gld16(lA0 + 4096, A1 + kb);
    gld16(lB0, B0 + kb);
    gld16(lB0 + 4096, B1 + kb);
    __syncthreads();
    s16x8 af[4], bf[4];
#pragma unroll
    for (int m = 0; m < 4; m++) af[m] = *(const s16x8*)(pa + m * 1024);
#pragma unroll
    for (int n = 0; n < 4; n++) bf[n] = *(const s16x8*)(pb + n * 1024);
#pragma unroll
    for (int m = 0; m < 4; m++)
#pragma unroll
      for (int n = 0; n < 4; n++) acc[m][n] = mfma16(af[m], bf[n], acc[m][n]);
    __syncthreads();
  }
#pragma unroll
  for (int m = 0; m < 4; m++)
#pragma unroll
    for (int n = 0; n < 4; n++)
#pragma unroll
      for (int j = 0; j < 4; j++) {
        const int r = bm * 128 + wr + m * 16 + (lane >> 4) * 4 + j;
        const int c = bn * 128 + wc + n * 16 + (lane & 15);
        float v = acc[m][n][j];
        if (BIAS) v += bias[c];
        C[(size_t)r * N + c] = v;
      }
}

extern "C" void kernel_launch(void* const* d_in, const int* in_sizes, int n_in,
                              void* d_out, int out_size, void* d_ws,
                              size_t ws_size, hipStream_t stream) {
  (void)in_sizes; (void)n_in; (void)out_size; (void)ws_size;
  const int* tokens = (const int*)d_in[0];
  const float* embed = (const float*)d_in[1];
  const float* Wq = (const float*)d_in[2];
  const float* Wk = (const float*)d_in[3];
  const float* Wv = (const float*)d_in[4];
  const float* Wo = (const float*)d_in[5];
  const float* slot_keys = (const float*)d_in[6];
  const float* ln_g = (const float*)d_in[7];
  const float* ln_b = (const float*)d_in[8];
  const float* fg = (const float*)d_in[9];
  const float* fb = (const float*)d_in[10];
  const float* Wout = (const float*)d_in[11];
  const float* bout = (const float*)d_in[12];
  float* out = (float*)d_out;

  char* p = (char*)d_ws;
  auto alloc = [&](size_t bytes) -> char* {
    char* r = p;
    p += (bytes + 255) & ~(size_t)255;
    return r;
  };
  const size_t RD = (size_t)NROWS * DIMM;
  double* hidden64 = (double*)alloc(RD * 8);
  double* xn64 = (double*)alloc(RD * 8);      // aliased as local64 later
  double* q64 = (double*)alloc(RD * 8);       // aliased as xnb (bf16) at end
  double* k64 = (double*)alloc(RD * 8);       // aliased as WoutT (bf16) at end
  double* v64 = (double*)alloc(RD * 8);
  float* S = (float*)alloc((size_t)NB * NCHUNK * NHEADS * 256 * 256 * 4);
  double* delta64 =
      (double*)alloc((size_t)NB * NHEADS * NCHUNK * NSLOTS * DH * 8);
  int* ri = (int*)alloc((size_t)65536 * 16 * 4);
  int* wi = (int*)alloc((size_t)65536 * 16 * 4);
  double* rw64 = (double*)alloc((size_t)65536 * 16 * 8);
  double* ww64 = (double*)alloc((size_t)65536 * 16 * 8);
  // split3 staging: input triple (reused for xn and local) + weight triples
  u16* sAh = (u16*)alloc(RD * 2);
  u16* sAm = (u16*)alloc(RD * 2);
  u16* sAl = (u16*)alloc(RD * 2);
  u16* WTh = (u16*)alloc((size_t)4 * DIMM * DIMM * 2);  // l*2+{0=v,1=o}
  u16* WTm = (u16*)alloc((size_t)4 * DIMM * DIMM * 2);
  u16* WTl = (u16*)alloc((size_t)4 * DIMM * DIMM * 2);

  double* local64 = xn64;  // xn64 dead once q/k/v inputs are consumed
  u16* xnb = (u16*)q64;    // used only after layer-2 attn
  u16* WoutT = (u16*)k64;  // used only after layer-2 attn

  // pre-split V/O weights (transposed) once
  for (int l = 0; l < 2; l++) {
    const size_t ov = ((size_t)l * 2 + 0) * DIMM * DIMM;
    const size_t oo = ((size_t)l * 2 + 1) * DIMM * DIMM;
    transconv3_kernel<<<dim3(DIMM / 32, DIMM / 32), dim3(32, 8), 0, stream>>>(
        Wv + (size_t)l * DIMM * DIMM, WTh + ov, WTm + ov, WTl + ov, DIMM, DIMM);
    transconv3_kernel<<<dim3(DIMM / 32, DIMM / 32), dim3(32, 8), 0, stream>>>(
        Wo + (size_t)l * DIMM * DIMM, WTh + oo, WTm + oo, WTl + oo, DIMM, DIMM);
  }

  embed64_kernel<<<NROWS, 256, 0, stream>>>(tokens, embed, hidden64);

  const dim3 g64(DIMM / 64, NROWS / 128);
  const dim3 g3(DIMM / 128, NROWS / 128);
  for (int l = 0; l < 2; l++) {
    const size_t wo = (size_t)l * DIMM * DIMM;
    const size_t ov = ((size_t)l * 2 + 0) * DIMM * DIMM;
    const size_t oo = ((size_t)l * 2 + 1) * DIMM * DIMM;
    ln64_kernel<0><<<NROWS, 256, 0, stream>>>(hidden64, ln_g + l * DIMM,
                                              ln_b + l * DIMM, xn64, nullptr);
    gemm64_kernel<false><<<g64, 256, 0, stream>>>(xn64, Wq + wo, q64, nullptr,
                                                  NROWS, DIMM, DIMM);
    gemm64_kernel<false><<<g64, 256, 0, stream>>>(xn64, Wk + wo, k64, nullptr,
                                                  NROWS, DIMM, DIMM);
    cvt3_64_kernel<<<RD / 1024, 256, 0, stream>>>(xn64, sAh, sAm, sAl);
    gemm3d_kernel<false><<<g3, 256, 0, stream>>>(
        sAh, sAm, sAl, WTh + ov, WTm + ov, WTl + ov, v64, nullptr, NROWS, DIMM,
        DIMM);
    const float* skl = slot_keys + (size_t)l * NHEADS * NSLOTS * DH;
    topk64_kernel<<<16384, 256, 0, stream>>>(q64, skl, ri, rw64);
    topk64_kernel<<<16384, 256, 0, stream>>>(k64, skl, wi, ww64);
    delta64_kernel<<<NB * NHEADS * NCHUNK, 512, 0, stream>>>(wi, ww64, v64,
                                                             delta64);
    attn_qk64<<<NB * NCHUNK * NHEADS * 8, 256, 0, stream>>>(q64, k64, S);
    soft_kernel<<<NB * NCHUNK * NHEADS * 16, 256, 0, stream>>>(S);
    attn_pv64<<<NB * NCHUNK * NHEADS * 8, 256, 0, stream>>>(S, v64, local64);
    recur64_kernel<<<NB * NHEADS * 8, 256, 0, stream>>>(ri, rw64, delta64,
                                                        local64);
    cvt3_64_kernel<<<RD / 1024, 256, 0, stream>>>(local64, sAh, sAm, sAl);
    gemm3d_kernel<true><<<g3, 256, 0, stream>>>(
        sAh, sAm, sAl, WTh + oo, WTm + oo, WTl + oo, hidden64, hidden64, NROWS,
        DIMM, DIMM);
  }
  transconv_kernel<<<dim3(NVOCAB / 32, DIMM / 32), dim3(32, 8), 0, stream>>>(
      Wout, WoutT, DIMM, NVOCAB);
  ln64_kernel<1><<<NROWS, 256, 0, stream>>>(hidden64, fg, fb, nullptr, xnb);
  gemm_kernel<true><<<dim3(NVOCAB / 128, NROWS / 128), 256, 0, stream>>>(
      xnb, WoutT, out, bout, NROWS, NVOCAB, DIMM);
}

// Round 7
// 7416.066 us; speedup vs baseline: 1.4224x; 1.1804x over previous
//
#include <hip/hip_runtime.h>

#define DIMM 1024
#define NHEADS 8
#define DH 128
#define NSLOTS 128
#define CHUNK 256
#define NCHUNK 16
#define NB 2
#define SEQ 4096
#define NROWS (NB * SEQ)
#define NVOCAB 32000
#define GAMMA64 0.9
#define SCALE64 0.08838834764831845
#define TAU 1e-6
#define MAXFLAG 65536

typedef unsigned short u16;
typedef __attribute__((ext_vector_type(4))) float f32x4;
typedef __attribute__((ext_vector_type(8))) short s16x8;

struct alignas(8) u16x4 { u16 x, y, z, w; };

__device__ __forceinline__ u16 f2bf(float f) {
  union { float f; unsigned u; } v; v.f = f;
  return (u16)((v.u + 0x7FFFu + ((v.u >> 16) & 1u)) >> 16);
}
__device__ __forceinline__ float bf2f(u16 u) {
  union { unsigned u; float f; } v; v.u = ((unsigned)u) << 16; return v.f;
}
// exact 3-way bf16 split of an f32 (h+m+l == x exactly: 8+8+8 >= 24 bits)
__device__ __forceinline__ void split3s(float x, u16& h, u16& m, u16& l) {
  h = f2bf(x); float r = x - bf2f(h);
  m = f2bf(r); float r2 = r - bf2f(m);
  l = f2bf(r2);
}

__device__ __forceinline__ void gld16(void* lds, const void* g) {
  __builtin_amdgcn_global_load_lds(
      (const __attribute__((address_space(1))) unsigned*)g,
      (__attribute__((address_space(3))) unsigned*)lds, 16, 0, 0);
}
__device__ __forceinline__ f32x4 mfma16(s16x8 a, s16x8 b, f32x4 c) {
  return __builtin_amdgcn_mfma_f32_16x16x32_bf16(a, b, c, 0, 0, 0);
}

// ---------------- embedding gather -> f64 ----------------
__global__ __launch_bounds__(256) void embed64_kernel(
    const int* __restrict__ tok, const float* __restrict__ emb,
    double* __restrict__ hid) {
  const int row = blockIdx.x;
  const int t = tok[row];
  const float4 v = ((const float4*)(emb + (size_t)t * DIMM))[threadIdx.x];
  double* o = hid + (size_t)row * DIMM + threadIdx.x * 4;
  o[0] = (double)v.x; o[1] = (double)v.y; o[2] = (double)v.z; o[3] = (double)v.w;
}

// ---------------- f64 two-pass layernorm ----------------
template <int BF16OUT>
__global__ __launch_bounds__(256) void ln64_kernel(
    const double* __restrict__ x, const float* __restrict__ g,
    const float* __restrict__ bb, double* __restrict__ o64,
    u16* __restrict__ obf) {
  const int row = blockIdx.x, tid = threadIdx.x;
  const double* xr = x + (size_t)row * DIMM + tid * 4;
  const double v0 = xr[0], v1 = xr[1], v2 = xr[2], v3 = xr[3];
  __shared__ double red[4];
  double s1 = v0 + v1 + v2 + v3;
#pragma unroll
  for (int off = 32; off >= 1; off >>= 1) s1 += __shfl_xor(s1, off);
  if ((tid & 63) == 0) red[tid >> 6] = s1;
  __syncthreads();
  const double mu = (red[0] + red[1] + red[2] + red[3]) * (1.0 / DIMM);
  __syncthreads();
  const double d0 = v0 - mu, d1 = v1 - mu, d2 = v2 - mu, d3 = v3 - mu;
  double s2 = d0 * d0 + d1 * d1 + d2 * d2 + d3 * d3;
#pragma unroll
  for (int off = 32; off >= 1; off >>= 1) s2 += __shfl_xor(s2, off);
  if ((tid & 63) == 0) red[tid >> 6] = s2;
  __syncthreads();
  const double var = (red[0] + red[1] + red[2] + red[3]) * (1.0 / DIMM);
  const double rs = 1.0 / sqrt(var + 1e-5);
  const float4 g4 = ((const float4*)g)[tid];
  const float4 b4 = ((const float4*)bb)[tid];
  const double y0 = d0 * rs * (double)g4.x + (double)b4.x;
  const double y1 = d1 * rs * (double)g4.y + (double)b4.y;
  const double y2 = d2 * rs * (double)g4.z + (double)b4.z;
  const double y3 = d3 * rs * (double)g4.w + (double)b4.w;
  if (BF16OUT) {
    u16x4 r;
    r.x = f2bf((float)y0); r.y = f2bf((float)y1);
    r.z = f2bf((float)y2); r.w = f2bf((float)y3);
    ((u16x4*)(obf + (size_t)row * DIMM))[tid] = r;
  } else {
    double* o = o64 + (size_t)row * DIMM + tid * 4;
    o[0] = y0; o[1] = y1; o[2] = y2; o[3] = y3;
  }
}

// ---------------- W[K][N] f32 -> WT[N][K] split3 bf16 ----------------
__global__ void transconv3_kernel(const float* __restrict__ W,
                                  u16* __restrict__ WTh, u16* __restrict__ WTm,
                                  u16* __restrict__ WTl, int K, int N) {
  __shared__ float tile[32][33];
  const int n0 = blockIdx.x * 32, k0 = blockIdx.y * 32;
  const int tx = threadIdx.x, ty = threadIdx.y;
#pragma unroll
  for (int i = 0; i < 4; i++)
    tile[ty + 8 * i][tx] = W[(size_t)(k0 + ty + 8 * i) * N + n0 + tx];
  __syncthreads();
#pragma unroll
  for (int i = 0; i < 4; i++) {
    u16 h, m, l;
    split3s(tile[tx][ty + 8 * i], h, m, l);
    const size_t o = (size_t)(n0 + ty + 8 * i) * K + k0 + tx;
    WTh[o] = h; WTm[o] = m; WTl[o] = l;
  }
}

// ---------------- f64 -> split3 bf16 elementwise ----------------
__global__ __launch_bounds__(256) void cvt3_64_kernel(
    const double* __restrict__ in, u16* __restrict__ oh, u16* __restrict__ om,
    u16* __restrict__ ol) {
  const size_t i = (size_t)blockIdx.x * 256 + threadIdx.x;
  const double* p = in + i * 4;
  u16x4 rh, rm, rl;
  split3s((float)p[0], rh.x, rm.x, rl.x);
  split3s((float)p[1], rh.y, rm.y, rl.y);
  split3s((float)p[2], rh.z, rm.z, rl.z);
  split3s((float)p[3], rh.w, rm.w, rl.w);
  ((u16x4*)oh)[i] = rh; ((u16x4*)om)[i] = rm; ((u16x4*)ol)[i] = rl;
}

// ---------------- combined slot-score weights: W2[h*128+s][d] (f64 exact) --
// W2[r][d] = sum_j W[d, h*128+j] * sk[h, s, j]   (r = h*128+s)
__global__ __launch_bounds__(256) void w2_kernel(const float* __restrict__ W,
                                                 const float* __restrict__ sk,
                                                 double* __restrict__ W2) {
  __shared__ float sksh[128];
  const int r = blockIdx.x, h = r >> 7;
  const int tid = threadIdx.x;
  if (tid < 128) sksh[tid] = sk[(size_t)r * DH + tid];
  __syncthreads();
  for (int d = tid; d < DIMM; d += 256) {
    const float* wrow = W + (size_t)d * DIMM + h * DH;
    double acc = 0.0;
#pragma unroll 8
    for (int j = 0; j < 128; j++) acc += (double)wrow[j] * (double)sksh[j];
    W2[(size_t)r * DIMM + d] = acc;
  }
}

// ---------------- split3 f32-faithful GEMM -> f64 out: C = A @ BT^T (+res) -
template <bool RES>
__global__ __launch_bounds__(256) void gemm3d_kernel(
    const u16* __restrict__ Ah, const u16* __restrict__ Am,
    const u16* __restrict__ Al, const u16* __restrict__ Bh,
    const u16* __restrict__ Bm, const u16* __restrict__ Bl,
    double* __restrict__ C, const double* __restrict__ Cres, int M, int N,
    int K) {
  __shared__ u16 lds[6 * 128 * 32];
  const int tid = threadIdx.x;
  const int bn = blockIdx.x, bm = blockIdx.y;
  const int wid = tid >> 6, lane = tid & 63;
  const int wr = (wid >> 1) * 64, wc = (wid & 1) * 64;
  f32x4 acc[4][4] = {};
  const int row0 = tid >> 2;
  const int colb = (tid & 3) << 4;
  const u16* Gs[6] = {Ah, Am, Al, Bh, Bm, Bl};
  const char* g0[6];
  const char* g1[6];
  char* lb[6];
#pragma unroll
  for (int i = 0; i < 6; i++) {
    const int rbase = (i < 3 ? bm : bn) * 128;
    g0[i] = (const char*)Gs[i] + ((size_t)(rbase + row0) * K) * 2 + colb;
    g1[i] = (const char*)Gs[i] + ((size_t)(rbase + row0 + 64) * K) * 2 + colb;
    lb[i] = (char*)lds + i * 8192 + (tid & 192) * 16;
  }
  const int fo = (lane & 15) * 64 + (lane >> 4) * 16;
  const char* paH = (const char*)lds + 0 + wr * 64 + fo;
  const char* paM = paH + 8192;
  const char* paL = paH + 16384;
  const char* pbH = (const char*)lds + 24576 + wc * 64 + fo;
  const char* pbM = pbH + 8192;
  const char* pbL = pbH + 16384;

  for (int k0 = 0; k0 < K; k0 += 32) {
    const size_t kb = (size_t)k0 * 2;
#pragma unroll
    for (int i = 0; i < 6; i++) {
      gld16(lb[i], g0[i] + kb);
      gld16(lb[i] + 4096, g1[i] + kb);
    }
    __syncthreads();
    s16x8 bh[4], bm_[4], bl[4];
#pragma unroll
    for (int n = 0; n < 4; n++) {
      bh[n] = *(const s16x8*)(pbH + n * 1024);
      bm_[n] = *(const s16x8*)(pbM + n * 1024);
      bl[n] = *(const s16x8*)(pbL + n * 1024);
    }
#pragma unroll
    for (int m = 0; m < 4; m++) {
      const s16x8 ah = *(const s16x8*)(paH + m * 1024);
      const s16x8 am = *(const s16x8*)(paM + m * 1024);
      const s16x8 al = *(const s16x8*)(paL + m * 1024);
#pragma unroll
      for (int n = 0; n < 4; n++) {
        f32x4 t = acc[m][n];
        t = mfma16(al, bh[n], t);
        t = mfma16(ah, bl[n], t);
        t = mfma16(am, bm_[n], t);
        t = mfma16(am, bh[n], t);
        t = mfma16(ah, bm_[n], t);
        t = mfma16(ah, bh[n], t);
        acc[m][n] = t;
      }
    }
    __syncthreads();
  }
#pragma unroll
  for (int m = 0; m < 4; m++)
#pragma unroll
    for (int n = 0; n < 4; n++)
#pragma unroll
      for (int j = 0; j < 4; j++) {
        const int r = bm * 128 + wr + m * 16 + (lane >> 4) * 4 + j;
        const int c = bn * 128 + wc + n * 16 + (lane & 15);
        double v = (double)acc[m][n][j];
        if (RES) v += Cres[(size_t)r * N + c];
        C[(size_t)r * N + c] = v;
      }
}

// ---------------- top-16 of 128 slot scores + near-tie flagging ------------
// 17 selection iters; if gap(rank16,rank17) < TAU, flag row for f64 fixup.
__global__ __launch_bounds__(256) void topk_flag_kernel(
    const double* __restrict__ X, const float* __restrict__ sk,
    int* __restrict__ oidx, double* __restrict__ ow, int* __restrict__ fcnt,
    int* __restrict__ flist) {
  __shared__ double vsh[4][130];
  const int wid = threadIdx.x >> 6, lane = threadIdx.x & 63;
  const int rid = blockIdx.x * 4 + wid;  // (b*8+h)*4096 + t
  const int t = rid & 4095, h = (rid >> 12) & 7, b = rid >> 15;
  const double* xrow = X + ((size_t)b * SEQ + t) * DIMM + h * DH;
  vsh[wid][lane * 2] = xrow[lane * 2];
  vsh[wid][lane * 2 + 1] = xrow[lane * 2 + 1];
  const float* skh = sk + (size_t)h * NSLOTS * DH;
  double s0 = 0.0, s1 = 0.0;
#pragma unroll 8
  for (int d = 0; d < DH; d++) {
    const double v = vsh[wid][d];
    s0 += v * (double)skh[(size_t)lane * DH + d];
    s1 += v * (double)skh[(size_t)(lane + 64) * DH + d];
  }
  s0 *= SCALE64; s1 *= SCALE64;
  double selv = -1e300; int seli = 0;
  double v0 = s0, v1 = s1;
  for (int it = 0; it < 17; it++) {
    double m; int mi;
    if (v1 > v0) { m = v1; mi = lane + 64; } else { m = v0; mi = lane; }
#pragma unroll
    for (int off = 1; off < 64; off <<= 1) {
      const double om = __shfl_xor(m, off);
      const int oi = __shfl_xor(mi, off);
      if (om > m || (om == m && oi < mi)) { m = om; mi = oi; }
    }
    if (lane == it) { selv = m; seli = mi; }
    if (mi == lane) v0 = -1e300;
    if (mi == lane + 64) v1 = -1e300;
  }
  const double mx = __shfl(selv, 0);
  const double v15 = __shfl(selv, 15);
  const double v16 = __shfl(selv, 16);
  if (lane == 0 && (v15 - v16) < TAU) {
    const int p = atomicAdd(fcnt, 1);
    if (p < MAXFLAG) flist[p] = rid;
  }
  const float e = (lane < 16) ? expf((float)(selv - mx)) : 0.0f;
  double ss = (double)e;
  ss += __shfl_xor(ss, 1); ss += __shfl_xor(ss, 2);
  ss += __shfl_xor(ss, 4); ss += __shfl_xor(ss, 8);
  if (lane < 16) {
    ow[(size_t)rid * 16 + lane] = (double)e / ss;
    oidx[(size_t)rid * 16 + lane] = seli;
  }
}

// ---------------- f64-exact fixup for flagged rows -------------------------
// scores[s] = (xn_row . W2[h*128+s]) * scale, all in f64; redo top-16.
__global__ __launch_bounds__(256) void fixup_kernel(
    const int* __restrict__ fcnt, const int* __restrict__ flist,
    const double* __restrict__ xn, const double* __restrict__ W2,
    int* __restrict__ oidx, double* __restrict__ ow) {
  __shared__ double xsh[1024];
  __shared__ double psh[256];
  __shared__ double ssh[128];
  const int tid = threadIdx.x;
  const int n = min(*fcnt, MAXFLAG);
  for (int i = blockIdx.x; i < n; i += gridDim.x) {
    __syncthreads();
    const int rid = flist[i];
    const int t = rid & 4095, h = (rid >> 12) & 7, b = rid >> 15;
    const double* xr = xn + ((size_t)b * SEQ + t) * DIMM;
    for (int j = tid; j < DIMM; j += 256) xsh[j] = xr[j];
    __syncthreads();
    const int slot = tid >> 1, half = tid & 1;
    const double* w2r = W2 + (size_t)(h * NSLOTS + slot) * DIMM + half * 512;
    const double* xp = xsh + half * 512;
    double acc = 0.0;
#pragma unroll 8
    for (int d = 0; d < 512; d++) acc += xp[d] * w2r[d];
    psh[tid] = acc;
    __syncthreads();
    if (tid < 128) ssh[tid] = (psh[2 * tid] + psh[2 * tid + 1]) * SCALE64;
    __syncthreads();
    if (tid < 64) {
      const int lane = tid;
      double selv = -1e300; int seli = 0;
      double v0 = ssh[lane], v1 = ssh[lane + 64];
      for (int it = 0; it < 16; it++) {
        double m; int mi;
        if (v1 > v0) { m = v1; mi = lane + 64; } else { m = v0; mi = lane; }
#pragma unroll
        for (int off = 1; off < 64; off <<= 1) {
          const double om = __shfl_xor(m, off);
          const int oi = __shfl_xor(mi, off);
          if (om > m || (om == m && oi < mi)) { m = om; mi = oi; }
        }
        if (lane == it) { selv = m; seli = mi; }
        if (mi == lane) v0 = -1e300;
        if (mi == lane + 64) v1 = -1e300;
      }
      const double mx = __shfl(selv, 0);
      const float e = (lane < 16) ? expf((float)(selv - mx)) : 0.0f;
      double ss = (double)e;
      ss += __shfl_xor(ss, 1); ss += __shfl_xor(ss, 2);
      ss += __shfl_xor(ss, 4); ss += __shfl_xor(ss, 8);
      if (lane < 16) {
        ow[(size_t)rid * 16 + lane] = (double)e / ss;
        oidx[(size_t)rid * 16 + lane] = seli;
      }
    }
  }
}

// ---------------- dense per-chunk write delta, f64, stable order -----------
__global__ __launch_bounds__(512) void delta64_kernel(
    const int* __restrict__ wi, const double* __restrict__ ww,
    const double* __restrict__ V, double* __restrict__ delta) {
  __shared__ short slot_sh[4096];
  __shared__ double w_sh[4096];
  __shared__ u16 list[4096];
  __shared__ int cnt[NSLOTS], off_[NSLOTS];
  const int bid = blockIdx.x;
  const int c = bid & 15, h = (bid >> 4) & 7, b = bid >> 7;
  const int tid = threadIdx.x;
  if (tid < NSLOTS) cnt[tid] = 0;
  __syncthreads();
  const size_t ebase = ((size_t)(b * 8 + h) * SEQ + (size_t)c * CHUNK) * 16;
#pragma unroll
  for (int i = 0; i < 8; i++) {
    const int e = tid + i * 512;
    const int s = wi[ebase + e];
    slot_sh[e] = (short)s;
    w_sh[e] = ww[ebase + e];
    atomicAdd(&cnt[s], 1);
  }
  __syncthreads();
  if (tid == 0) {
    int a = 0;
    for (int s = 0; s < NSLOTS; s++) { off_[s] = a; a += cnt[s]; }
  }
  __syncthreads();
  if (tid < NSLOTS) {
    int p = off_[tid];
    const short me = (short)tid;
    for (int e = 0; e < 4096; e++)
      if (slot_sh[e] == me) list[p++] = (u16)e;
  }
  __syncthreads();
  const int slot = tid >> 2, dbase = (tid & 3) * 32;
  double acc[32] = {};
  const int start = off_[slot], len = cnt[slot];
  const double* vbase =
      V + ((size_t)b * SEQ + (size_t)c * CHUNK) * DIMM + h * DH + dbase;
  for (int i = 0; i < len; i++) {
    const int e = list[start + i];
    const double w = w_sh[e];
    const double* vp = vbase + (size_t)(e >> 4) * DIMM;
#pragma unroll
    for (int d = 0; d < 32; d++) acc[d] += w * vp[d];
  }
  double* dst = delta + ((size_t)bid * NSLOTS + slot) * DH + dbase;
#pragma unroll
  for (int d = 0; d < 32; d++) dst[d] = acc[d];
}

// ---------------- local attention scores, f64 dots -> f32 S ----------------
__global__ __launch_bounds__(256) void attn_qk64(
    const double* __restrict__ Q, const double* __restrict__ Kb,
    float* __restrict__ S) {
  __shared__ double Qs[32][130];
  __shared__ double Ks[16][130];
  const int idx = blockIdx.x;
  const int rq = idx & 7, h = (idx >> 3) & 7, c = (idx >> 6) & 15, b = idx >> 10;
  const int tid = threadIdx.x;
  const size_t rowbase = (size_t)b * SEQ + (size_t)c * CHUNK;
  {
    const int r = tid >> 3, d0 = (tid & 7) * 16;
    const double* qp = Q + (rowbase + rq * 32 + r) * DIMM + h * DH + d0;
#pragma unroll
    for (int j = 0; j < 16; j++) Qs[r][d0 + j] = qp[j];
  }
  const int row = tid >> 3;
  const int kq = tid & 7;
  const int row_abs = rq * 32 + row;
  float* srow =
      S + ((((size_t)(b * 16 + c) * 8 + h) * 256) + row_abs) * 256;
  const int ntile = (rq * 32 + 31) / 16 + 1;
  for (int kt = 0; kt < ntile; kt++) {
    __syncthreads();
    {
      const int r = tid >> 4, d0 = (tid & 15) * 8;
      const double* kp = Kb + (rowbase + kt * 16 + r) * DIMM + h * DH + d0;
#pragma unroll
      for (int j = 0; j < 8; j++) Ks[r][d0 + j] = kp[j];
    }
    __syncthreads();
#pragma unroll
    for (int kk = 0; kk < 2; kk++) {
      const int key = kq * 2 + kk;
      double s = 0.0;
#pragma unroll 8
      for (int d = 0; d < DH; d++) s += Qs[row][d] * Ks[key][d];
      const int kabs = kt * 16 + key;
      srow[kabs] = (kabs <= row_abs) ? (float)(s * SCALE64) : -1e30f;
    }
  }
}

// ---------------- row softmax over S (in place), causal-masked -------------
__global__ __launch_bounds__(256) void soft_kernel(float* __restrict__ S) {
  const int idx = blockIdx.x;
  const int g = idx & 15, h = (idx >> 4) & 7, c = (idx >> 7) & 15, b = idx >> 11;
  const int tid = threadIdx.x;
  const int r = tid >> 4, c2 = tid & 15;
  const int row = g * 16 + r;
  float* srow = S + ((((size_t)(b * 16 + c) * 8 + h) * 256) + row) * 256;
  float sv[16];
#pragma unroll
  for (int j = 0; j < 4; j++) {
    const float4 t = *(const float4*)(srow + c2 * 16 + j * 4);
    sv[4 * j] = t.x; sv[4 * j + 1] = t.y;
    sv[4 * j + 2] = t.z; sv[4 * j + 3] = t.w;
  }
#pragma unroll
  for (int j = 0; j < 16; j++)
    if (c2 * 16 + j > row) sv[j] = -1e30f;
  float m = -1e30f;
#pragma unroll
  for (int j = 0; j < 16; j++) m = fmaxf(m, sv[j]);
  m = fmaxf(m, __shfl_xor(m, 1)); m = fmaxf(m, __shfl_xor(m, 2));
  m = fmaxf(m, __shfl_xor(m, 4)); m = fmaxf(m, __shfl_xor(m, 8));
  float pv[16];
  double ss = 0.0;
#pragma unroll
  for (int j = 0; j < 16; j++) {
    pv[j] = __expf(sv[j] - m);
    ss += (double)pv[j];
  }
  ss += __shfl_xor(ss, 1); ss += __shfl_xor(ss, 2);
  ss += __shfl_xor(ss, 4); ss += __shfl_xor(ss, 8);
  const double inv = 1.0 / ss;
#pragma unroll
  for (int j = 0; j < 4; j++) {
    float4 t;
    t.x = (float)((double)pv[4 * j] * inv);
    t.y = (float)((double)pv[4 * j + 1] * inv);
    t.z = (float)((double)pv[4 * j + 2] * inv);
    t.w = (float)((double)pv[4 * j + 3] * inv);
    *(float4*)(srow + c2 * 16 + j * 4) = t;
  }
}

// ---------------- PV, f64 accumulate, writes local -------------------------
__global__ __launch_bounds__(256) void attn_pv64(
    const float* __restrict__ P, const double* __restrict__ V,
    double* __restrict__ outb) {
  __shared__ double Vs[16][130];
  __shared__ float Ps[32][17];
  const int idx = blockIdx.x;
  const int rq = idx & 7, h = (idx >> 3) & 7, c = (idx >> 6) & 15, b = idx >> 10;
  const int tid = threadIdx.x;
  const size_t rowbase = (size_t)b * SEQ + (size_t)c * CHUNK;
  const int row = tid >> 3, dq = (tid & 7) * 16;
  const int row_abs = rq * 32 + row;
  const size_t sbase = ((size_t)(b * 16 + c) * 8 + h) * 256;
  double acc[16] = {};
  const int ntile = (rq * 32 + 31) / 16 + 1;
  for (int kt = 0; kt < ntile; kt++) {
    __syncthreads();
    {
      const int r = tid >> 4, d0 = (tid & 15) * 8;
      const double* vp = V + (rowbase + kt * 16 + r) * DIMM + h * DH + d0;
#pragma unroll
      for (int j = 0; j < 8; j++) Vs[r][d0 + j] = vp[j];
      const int pr = tid >> 3, pk = (tid & 7) * 2;
      const float* pp = P + (sbase + rq * 32 + pr) * 256 + kt * 16 + pk;
      Ps[pr][pk] = pp[0];
      Ps[pr][pk + 1] = pp[1];
    }
    __syncthreads();
#pragma unroll
    for (int key = 0; key < 16; key++) {
      const double p = (double)Ps[row][key];
      const double* vrow = &Vs[key][dq];
#pragma unroll
      for (int d = 0; d < 16; d++) acc[d] += p * vrow[d];
    }
  }
  double* op = outb + (rowbase + row_abs) * DIMM + h * DH + dq;
#pragma unroll
  for (int d = 0; d < 16; d++) op[d] = acc[d];
}

// ---------------- sequential M recurrence, f64 ----------------
__global__ __launch_bounds__(256) void recur64_kernel(
    const int* __restrict__ ri, const double* __restrict__ rw,
    const double* __restrict__ delta, double* __restrict__ outb) {
  __shared__ double Msh[NSLOTS][17];
  const int bid = blockIdx.x;
  const int ds = bid & 7, h = (bid >> 3) & 7, b = bid >> 6;
  const int tid = threadIdx.x;
  for (int i = tid; i < NSLOTS * 17; i += 256) ((double*)Msh)[i] = 0.0;
  __syncthreads();
  for (int c = 0; c < NCHUNK; c++) {
    const size_t rbase =
        ((size_t)(b * 8 + h) * SEQ + (size_t)c * CHUNK + tid) * 16;
    double a[16] = {};
#pragma unroll
    for (int j = 0; j < 16; j++) {
      const int slot = ri[rbase + j];
      const double w = rw[rbase + j];
      const double* mp = &Msh[slot][0];
#pragma unroll
      for (int d = 0; d < 16; d++) a[d] += w * mp[d];
    }
    double* op = outb + ((size_t)b * SEQ + (size_t)c * CHUNK + tid) * DIMM +
                 h * DH + ds * 16;
#pragma unroll
    for (int d = 0; d < 16; d++) op[d] += a[d];
    __syncthreads();
    const int slot = tid >> 1, d8 = (tid & 1) * 8;
    const double* dp = delta +
        (((size_t)(b * 8 + h) * NCHUNK + c) * NSLOTS + slot) * DH + ds * 16 + d8;
#pragma unroll
    for (int d = 0; d < 8; d++)
      Msh[slot][d8 + d] = GAMMA64 * Msh[slot][d8 + d] + dp[d];
    __syncthreads();
  }
}

// ---------------- W[K][N] f32 -> WT[N][K] bf16 (final logits weights) ------
__global__ void transconv_kernel(const float* __restrict__ W,
                                 u16* __restrict__ WT, int K, int N) {
  __shared__ float tile[32][33];
  const int n0 = blockIdx.x * 32, k0 = blockIdx.y * 32;
  const int tx = threadIdx.x, ty = threadIdx.y;
#pragma unroll
  for (int i = 0; i < 4; i++)
    tile[ty + 8 * i][tx] = W[(size_t)(k0 + ty + 8 * i) * N + n0 + tx];
  __syncthreads();
#pragma unroll
  for (int i = 0; i < 4; i++)
    WT[(size_t)(n0 + ty + 8 * i) * K + k0 + tx] = f2bf(tile[tx][ty + 8 * i]);
}

// ---------------- bf16 MFMA GEMM for logits (GROUP_N=16 supertile) ---------
template <bool BIAS>
__global__ __launch_bounds__(256) void gemm_kernel(
    const u16* __restrict__ A, const u16* __restrict__ B, float* __restrict__ C,
    const float* __restrict__ bias, int M, int N, int K) {
  __shared__ u16 As[128 * 32];
  __shared__ u16 Bs[128 * 32];
  const int tid = threadIdx.x;
  const int lid = blockIdx.y * gridDim.x + blockIdx.x;
  const int npm = M / 128;
  const int ngrid = N / 128;
  const int GN = 16;
  const int ppg = GN * npm;
  const int gid = lid / ppg;
  const int first_n = gid * GN;
  const int gsz = min(GN, ngrid - first_n);
  const int local = lid - gid * ppg;
  const int bn = first_n + local % gsz;
  const int bm = local / gsz;
  const int wid = tid >> 6, lane = tid & 63;
  const int wr = (wid >> 1) * 64, wc = (wid & 1) * 64;
  f32x4 acc[4][4] = {};
  const int row0 = tid >> 2;
  const int colb = (tid & 3) << 4;
  const char* A0 = (const char*)A + ((size_t)(bm * 128 + row0) * K) * 2 + colb;
  const char* A1 = (const char*)A + ((size_t)(bm * 128 + row0 + 64) * K) * 2 + colb;
  const char* B0 = (const char*)B + ((size_t)(bn * 128 + row0) * K) * 2 + colb;
  const char* B1 = (const char*)B + ((size_t)(bn * 128 + row0 + 64) * K) * 2 + colb;
  char* lA0 = (char*)As + (tid & 192) * 16;
  char* lB0 = (char*)Bs + (tid & 192) * 16;
  const char* pa = (const char*)As + wr * 64 + (lane & 15) * 64 + (lane >> 4) * 16;
  const char* pb = (const char*)Bs + wc * 64 + (lane & 15) * 64 + (lane >> 4) * 16;
  for (int k0 = 0; k0 < K; k0 += 32) {
    const size_t kb = (size_t)k0 * 2;
    gld16(lA0, A0 + kb);
    gld16(lA0 + 4096, A1 + kb);
    gld16(lB0, B0 + kb);
    gld16(lB0 + 4096, B1 + kb);
    __syncthreads();
    s16x8 af[4], bf[4];
#pragma unroll
    for (int m = 0; m < 4; m++) af[m] = *(const s16x8*)(pa + m * 1024);
#pragma unroll
    for (int n = 0; n < 4; n++) bf[n] = *(const s16x8*)(pb + n * 1024);
#pragma unroll
    for (int m = 0; m < 4; m++)
#pragma unroll
      for (int n = 0; n < 4; n++) acc[m][n] = mfma16(af[m], bf[n], acc[m][n]);
    __syncthreads();
  }
#pragma unroll
  for (int m = 0; m < 4; m++)
#pragma unroll
    for (int n = 0; n < 4; n++)
#pragma unroll
      for (int j = 0; j < 4; j++) {
        const int r = bm * 128 + wr + m * 16 + (lane >> 4) * 4 + j;
        const int c = bn * 128 + wc + n * 16 + (lane & 15);
        float v = acc[m][n][j];
        if (BIAS) v += bias[c];
        C[(size_t)r * N + c] = v;
      }
}

extern "C" void kernel_launch(void* const* d_in, const int* in_sizes, int n_in,
                              void* d_out, int out_size, void* d_ws,
                              size_t ws_size, hipStream_t stream) {
  (void)in_sizes; (void)n_in; (void)out_size; (void)ws_size;
  const int* tokens = (const int*)d_in[0];
  const float* embed = (const float*)d_in[1];
  const float* Wq = (const float*)d_in[2];
  const float* Wk = (const float*)d_in[3];
  const float* Wv = (const float*)d_in[4];
  const float* Wo = (const float*)d_in[5];
  const float* slot_keys = (const float*)d_in[6];
  const float* ln_g = (const float*)d_in[7];
  const float* ln_b = (const float*)d_in[8];
  const float* fg = (const float*)d_in[9];
  const float* fb = (const float*)d_in[10];
  const float* Wout = (const float*)d_in[11];
  const float* bout = (const float*)d_in[12];
  float* out = (float*)d_out;

  char* p = (char*)d_ws;
  auto alloc = [&](size_t bytes) -> char* {
    char* r = p;
    p += (bytes + 255) & ~(size_t)255;
    return r;
  };
  const size_t RD = (size_t)NROWS * DIMM;
  double* hidden64 = (double*)alloc(RD * 8);
  double* xn64 = (double*)alloc(RD * 8);      // aliased as local64 later
  double* q64 = (double*)alloc(RD * 8);       // aliased as xnb (bf16) at end
  double* k64 = (double*)alloc(RD * 8);       // aliased as WoutT (bf16) at end
  double* v64 = (double*)alloc(RD * 8);
  float* S = (float*)alloc((size_t)NB * NCHUNK * NHEADS * 256 * 256 * 4);
  double* delta64 =
      (double*)alloc((size_t)NB * NHEADS * NCHUNK * NSLOTS * DH * 8);
  int* ri = (int*)alloc((size_t)65536 * 16 * 4);
  int* wi = (int*)alloc((size_t)65536 * 16 * 4);
  double* rw64 = (double*)alloc((size_t)65536 * 16 * 8);
  double* ww64 = (double*)alloc((size_t)65536 * 16 * 8);
  u16* sAh = (u16*)alloc(RD * 2);
  u16* sAm = (u16*)alloc(RD * 2);
  u16* sAl = (u16*)alloc(RD * 2);
  u16* WTh = (u16*)alloc((size_t)8 * DIMM * DIMM * 2);  // l*4+{q,k,v,o}
  u16* WTm = (u16*)alloc((size_t)8 * DIMM * DIMM * 2);
  u16* WTl = (u16*)alloc((size_t)8 * DIMM * DIMM * 2);
  double* W2q = (double*)alloc((size_t)2 * DIMM * DIMM * 8);
  double* W2k = (double*)alloc((size_t)2 * DIMM * DIMM * 8);
  int* fcnts = (int*)alloc(256);
  int* flq = (int*)alloc((size_t)MAXFLAG * 4);
  int* flk = (int*)alloc((size_t)MAXFLAG * 4);

  double* local64 = xn64;
  u16* xnb = (u16*)q64;
  u16* WoutT = (u16*)k64;

  const float* Wmats[4] = {Wq, Wk, Wv, Wo};
  for (int l = 0; l < 2; l++) {
    for (int w = 0; w < 4; w++) {
      const size_t o = ((size_t)l * 4 + w) * DIMM * DIMM;
      transconv3_kernel<<<dim3(DIMM / 32, DIMM / 32), dim3(32, 8), 0, stream>>>(
          Wmats[w] + (size_t)l * DIMM * DIMM, WTh + o, WTm + o, WTl + o, DIMM,
          DIMM);
    }
    const float* skl = slot_keys + (size_t)l * NHEADS * NSLOTS * DH;
    w2_kernel<<<1024, 256, 0, stream>>>(Wq + (size_t)l * DIMM * DIMM, skl,
                                        W2q + (size_t)l * DIMM * DIMM);
    w2_kernel<<<1024, 256, 0, stream>>>(Wk + (size_t)l * DIMM * DIMM, skl,
                                        W2k + (size_t)l * DIMM * DIMM);
  }

  embed64_kernel<<<NROWS, 256, 0, stream>>>(tokens, embed, hidden64);

  const dim3 g3(DIMM / 128, NROWS / 128);
  for (int l = 0; l < 2; l++) {
    const size_t oq = ((size_t)l * 4 + 0) * DIMM * DIMM;
    const size_t ok = ((size_t)l * 4 + 1) * DIMM * DIMM;
    const size_t ov = ((size_t)l * 4 + 2) * DIMM * DIMM;
    const size_t oo = ((size_t)l * 4 + 3) * DIMM * DIMM;
    ln64_kernel<0><<<NROWS, 256, 0, stream>>>(hidden64, ln_g + l * DIMM,
                                              ln_b + l * DIMM, xn64, nullptr);
    cvt3_64_kernel<<<RD / 1024, 256, 0, stream>>>(xn64, sAh, sAm, sAl);
    gemm3d_kernel<false><<<g3, 256, 0, stream>>>(
        sAh, sAm, sAl, WTh + oq, WTm + oq, WTl + oq, q64, nullptr, NROWS, DIMM,
        DIMM);
    gemm3d_kernel<false><<<g3, 256, 0, stream>>>(
        sAh, sAm, sAl, WTh + ok, WTm + ok, WTl + ok, k64, nullptr, NROWS, DIMM,
        DIMM);
    gemm3d_kernel<false><<<g3, 256, 0, stream>>>(
        sAh, sAm, sAl, WTh + ov, WTm + ov, WTl + ov, v64, nullptr, NROWS, DIMM,
        DIMM);
    const float* skl = slot_keys + (size_t)l * NHEADS * NSLOTS * DH;
    hipMemsetAsync(fcnts, 0, 8, stream);
    topk_flag_kernel<<<16384, 256, 0, stream>>>(q64, skl, ri, rw64, fcnts,
                                                flq);
    topk_flag_kernel<<<16384, 256, 0, stream>>>(k64, skl, wi, ww64, fcnts + 1,
                                                flk);
    fixup_kernel<<<1024, 256, 0, stream>>>(
        fcnts, flq, xn64, W2q + (size_t)l * DIMM * DIMM, ri, rw64);
    fixup_kernel<<<1024, 256, 0, stream>>>(
        fcnts + 1, flk, xn64, W2k + (size_t)l * DIMM * DIMM, wi, ww64);
    delta64_kernel<<<NB * NHEADS * NCHUNK, 512, 0, stream>>>(wi, ww64, v64,
                                                             delta64);
    attn_qk64<<<NB * NCHUNK * NHEADS * 8, 256, 0, stream>>>(q64, k64, S);
    soft_kernel<<<NB * NCHUNK * NHEADS * 16, 256, 0, stream>>>(S);
    attn_pv64<<<NB * NCHUNK * NHEADS * 8, 256, 0, stream>>>(S, v64, local64);
    recur64_kernel<<<NB * NHEADS * 8, 256, 0, stream>>>(ri, rw64, delta64,
                                                        local64);
    cvt3_64_kernel<<<RD / 1024, 256, 0, stream>>>(local64, sAh, sAm, sAl);
    gemm3d_kernel<true><<<g3, 256, 0, stream>>>(
        sAh, sAm, sAl, WTh + oo, WTm + oo, WTl + oo, hidden64, hidden64, NROWS,
        DIMM, DIMM);
  }
  transconv_kernel<<<dim3(NVOCAB / 32, DIMM / 32), dim3(32, 8), 0, stream>>>(
      Wout, WoutT, DIMM, NVOCAB);
  ln64_kernel<1><<<NROWS, 256, 0, stream>>>(hidden64, fg, fb, nullptr, xnb);
  gemm_kernel<true><<<dim3(NVOCAB / 128, NROWS / 128), 256, 0, stream>>>(
      xnb, WoutT, out, bout, NROWS, NVOCAB, DIMM);
}

// Round 9
// 7260.436 us; speedup vs baseline: 1.4529x; 1.0214x over previous
//
#include <hip/hip_runtime.h>

#define DIMM 1024
#define NHEADS 8
#define DH 128
#define NSLOTS 128
#define CHUNK 256
#define NCHUNK 16
#define NB 2
#define SEQ 4096
#define NROWS (NB * SEQ)
#define NVOCAB 32000
#define GAMMA64 0.9
#define SCALE64 0.08838834764831845
#define TAU 1e-6
#define MAXFLAG 65536

typedef unsigned short u16;
typedef __attribute__((ext_vector_type(4))) float f32x4;
typedef __attribute__((ext_vector_type(8))) short s16x8;

struct alignas(8) u16x4 { u16 x, y, z, w; };

__device__ __forceinline__ u16 f2bf(float f) {
  union { float f; unsigned u; } v; v.f = f;
  return (u16)((v.u + 0x7FFFu + ((v.u >> 16) & 1u)) >> 16);
}
__device__ __forceinline__ float bf2f(u16 u) {
  union { unsigned u; float f; } v; v.u = ((unsigned)u) << 16; return v.f;
}
// exact 3-way bf16 split of an f32 (h+m+l == x exactly)
__device__ __forceinline__ void split3s(float x, u16& h, u16& m, u16& l) {
  h = f2bf(x); float r = x - bf2f(h);
  m = f2bf(r); float r2 = r - bf2f(m);
  l = f2bf(r2);
}

__device__ __forceinline__ void gld16(void* lds, const void* g) {
  __builtin_amdgcn_global_load_lds(
      (const __attribute__((address_space(1))) unsigned*)g,
      (__attribute__((address_space(3))) unsigned*)lds, 16, 0, 0);
}
__device__ __forceinline__ f32x4 mfma16(s16x8 a, s16x8 b, f32x4 c) {
  return __builtin_amdgcn_mfma_f32_16x16x32_bf16(a, b, c, 0, 0, 0);
}

// ---------------- embedding gather -> f64 ----------------
__global__ __launch_bounds__(256) void embed64_kernel(
    const int* __restrict__ tok, const float* __restrict__ emb,
    double* __restrict__ hid) {
  const int row = blockIdx.x;
  const int t = tok[row];
  const float4 v = ((const float4*)(emb + (size_t)t * DIMM))[threadIdx.x];
  double* o = hid + (size_t)row * DIMM + threadIdx.x * 4;
  o[0] = (double)v.x; o[1] = (double)v.y; o[2] = (double)v.z; o[3] = (double)v.w;
}

// ------- f64 two-pass layernorm; MODE0: f64 xn + split3; MODE1: bf16 -------
template <int MODE>
__global__ __launch_bounds__(256) void ln64_kernel(
    const double* __restrict__ x, const float* __restrict__ g,
    const float* __restrict__ bb, double* __restrict__ o64,
    u16* __restrict__ oh, u16* __restrict__ om, u16* __restrict__ ol) {
  const int row = blockIdx.x, tid = threadIdx.x;
  const double* xr = x + (size_t)row * DIMM + tid * 4;
  const double v0 = xr[0], v1 = xr[1], v2 = xr[2], v3 = xr[3];
  __shared__ double red[4];
  double s1 = v0 + v1 + v2 + v3;
#pragma unroll
  for (int off = 32; off >= 1; off >>= 1) s1 += __shfl_xor(s1, off);
  if ((tid & 63) == 0) red[tid >> 6] = s1;
  __syncthreads();
  const double mu = (red[0] + red[1] + red[2] + red[3]) * (1.0 / DIMM);
  __syncthreads();
  const double d0 = v0 - mu, d1 = v1 - mu, d2 = v2 - mu, d3 = v3 - mu;
  double s2 = d0 * d0 + d1 * d1 + d2 * d2 + d3 * d3;
#pragma unroll
  for (int off = 32; off >= 1; off >>= 1) s2 += __shfl_xor(s2, off);
  if ((tid & 63) == 0) red[tid >> 6] = s2;
  __syncthreads();
  const double var = (red[0] + red[1] + red[2] + red[3]) * (1.0 / DIMM);
  const double rs = 1.0 / sqrt(var + 1e-5);
  const float4 g4 = ((const float4*)g)[tid];
  const float4 b4 = ((const float4*)bb)[tid];
  const double y0 = d0 * rs * (double)g4.x + (double)b4.x;
  const double y1 = d1 * rs * (double)g4.y + (double)b4.y;
  const double y2 = d2 * rs * (double)g4.z + (double)b4.z;
  const double y3 = d3 * rs * (double)g4.w + (double)b4.w;
  if (MODE == 0) {
    double* o = o64 + (size_t)row * DIMM + tid * 4;
    o[0] = y0; o[1] = y1; o[2] = y2; o[3] = y3;
    u16x4 rh, rm, rl;
    split3s((float)y0, rh.x, rm.x, rl.x);
    split3s((float)y1, rh.y, rm.y, rl.y);
    split3s((float)y2, rh.z, rm.z, rl.z);
    split3s((float)y3, rh.w, rm.w, rl.w);
    ((u16x4*)(oh + (size_t)row * DIMM))[tid] = rh;
    ((u16x4*)(om + (size_t)row * DIMM))[tid] = rm;
    ((u16x4*)(ol + (size_t)row * DIMM))[tid] = rl;
  } else {
    u16x4 r;
    r.x = f2bf((float)y0); r.y = f2bf((float)y1);
    r.z = f2bf((float)y2); r.w = f2bf((float)y3);
    ((u16x4*)(oh + (size_t)row * DIMM))[tid] = r;
  }
}

// ---------------- W[K][N] f32 -> WT[N][K] split3 bf16 ----------------
__global__ void transconv3_kernel(const float* __restrict__ W,
                                  u16* __restrict__ WTh, u16* __restrict__ WTm,
                                  u16* __restrict__ WTl, int K, int N) {
  __shared__ float tile[32][33];
  const int n0 = blockIdx.x * 32, k0 = blockIdx.y * 32;
  const int tx = threadIdx.x, ty = threadIdx.y;
#pragma unroll
  for (int i = 0; i < 4; i++)
    tile[ty + 8 * i][tx] = W[(size_t)(k0 + ty + 8 * i) * N + n0 + tx];
  __syncthreads();
#pragma unroll
  for (int i = 0; i < 4; i++) {
    u16 h, m, l;
    split3s(tile[tx][ty + 8 * i], h, m, l);
    const size_t o = (size_t)(n0 + ty + 8 * i) * K + k0 + tx;
    WTh[o] = h; WTm[o] = m; WTl[o] = l;
  }
}

// ---------------- combined slot-score weights: W2 (f64 exact) --------------
__global__ __launch_bounds__(256) void w2_kernel(const float* __restrict__ W,
                                                 const float* __restrict__ sk,
                                                 double* __restrict__ W2) {
  __shared__ float sksh[128];
  const int r = blockIdx.x, h = r >> 7;
  const int tid = threadIdx.x;
  if (tid < 128) sksh[tid] = sk[(size_t)r * DH + tid];
  __syncthreads();
  for (int d = tid; d < DIMM; d += 256) {
    const float* wrow = W + (size_t)d * DIMM + h * DH;
    double acc = 0.0;
#pragma unroll 8
    for (int j = 0; j < 128; j++) acc += (double)wrow[j] * (double)sksh[j];
    W2[(size_t)r * DIMM + d] = acc;
  }
}

// ------- split3 f32-faithful GEMM -> f64 out: C = A @ BT^T (+res) ----------
template <bool RES>
__global__ __launch_bounds__(256) void gemm3d_kernel(
    const u16* __restrict__ Ah, const u16* __restrict__ Am,
    const u16* __restrict__ Al, const u16* __restrict__ Bh,
    const u16* __restrict__ Bm, const u16* __restrict__ Bl,
    double* __restrict__ C, const double* __restrict__ Cres, int M, int N,
    int K) {
  __shared__ u16 lds[6 * 128 * 32];
  const int tid = threadIdx.x;
  const int bn = blockIdx.x, bm = blockIdx.y;
  const int wid = tid >> 6, lane = tid & 63;
  const int wr = (wid >> 1) * 64, wc = (wid & 1) * 64;
  f32x4 acc[4][4] = {};
  const int row0 = tid >> 2;
  const int colb = (tid & 3) << 4;
  const u16* Gs[6] = {Ah, Am, Al, Bh, Bm, Bl};
  const char* g0[6];
  const char* g1[6];
  char* lb[6];
#pragma unroll
  for (int i = 0; i < 6; i++) {
    const int rbase = (i < 3 ? bm : bn) * 128;
    g0[i] = (const char*)Gs[i] + ((size_t)(rbase + row0) * K) * 2 + colb;
    g1[i] = (const char*)Gs[i] + ((size_t)(rbase + row0 + 64) * K) * 2 + colb;
    lb[i] = (char*)lds + i * 8192 + (tid & 192) * 16;
  }
  const int fo = (lane & 15) * 64 + (lane >> 4) * 16;
  const char* paH = (const char*)lds + 0 + wr * 64 + fo;
  const char* paM = paH + 8192;
  const char* paL = paH + 16384;
  const char* pbH = (const char*)lds + 24576 + wc * 64 + fo;
  const char* pbM = pbH + 8192;
  const char* pbL = pbH + 16384;

  for (int k0 = 0; k0 < K; k0 += 32) {
    const size_t kb = (size_t)k0 * 2;
#pragma unroll
    for (int i = 0; i < 6; i++) {
      gld16(lb[i], g0[i] + kb);
      gld16(lb[i] + 4096, g1[i] + kb);
    }
    __syncthreads();
    s16x8 bh[4], bm_[4], bl[4];
#pragma unroll
    for (int n = 0; n < 4; n++) {
      bh[n] = *(const s16x8*)(pbH + n * 1024);
      bm_[n] = *(const s16x8*)(pbM + n * 1024);
      bl[n] = *(const s16x8*)(pbL + n * 1024);
    }
#pragma unroll
    for (int m = 0; m < 4; m++) {
      const s16x8 ah = *(const s16x8*)(paH + m * 1024);
      const s16x8 am = *(const s16x8*)(paM + m * 1024);
      const s16x8 al = *(const s16x8*)(paL + m * 1024);
#pragma unroll
      for (int n = 0; n < 4; n++) {
        f32x4 t = acc[m][n];
        t = mfma16(al, bh[n], t);
        t = mfma16(ah, bl[n], t);
        t = mfma16(am, bm_[n], t);
        t = mfma16(am, bh[n], t);
        t = mfma16(ah, bm_[n], t);
        t = mfma16(ah, bh[n], t);
        acc[m][n] = t;
      }
    }
    __syncthreads();
  }
#pragma unroll
  for (int m = 0; m < 4; m++)
#pragma unroll
    for (int n = 0; n < 4; n++)
#pragma unroll
      for (int j = 0; j < 4; j++) {
        const int r = bm * 128 + wr + m * 16 + (lane >> 4) * 4 + j;
        const int c = bn * 128 + wc + n * 16 + (lane & 15);
        double v = (double)acc[m][n][j];
        if (RES) v += Cres[(size_t)r * N + c];
        C[(size_t)r * N + c] = v;
      }
}

// -------- top-16 of 128 slot scores (f64 dots) + near-tie flagging ---------
__global__ __launch_bounds__(256) void topk_flag_kernel(
    const double* __restrict__ X, const float* __restrict__ sk,
    int* __restrict__ oidx, double* __restrict__ ow, int* __restrict__ fcnt,
    int* __restrict__ flist) {
  __shared__ double vsh[4][130];
  const int wid = threadIdx.x >> 6, lane = threadIdx.x & 63;
  const int rid = blockIdx.x * 4 + wid;  // (b*8+h)*4096 + t
  const int t = rid & 4095, h = (rid >> 12) & 7, b = rid >> 15;
  const double* xrow = X + ((size_t)b * SEQ + t) * DIMM + h * DH;
  vsh[wid][lane * 2] = xrow[lane * 2];
  vsh[wid][lane * 2 + 1] = xrow[lane * 2 + 1];
  const float* skh = sk + (size_t)h * NSLOTS * DH;
  double s0 = 0.0, s1 = 0.0;
#pragma unroll 8
  for (int d = 0; d < DH; d++) {
    const double v = vsh[wid][d];
    s0 += v * (double)skh[(size_t)lane * DH + d];
    s1 += v * (double)skh[(size_t)(lane + 64) * DH + d];
  }
  s0 *= SCALE64; s1 *= SCALE64;
  double selv = -1e300; int seli = 0;
  double v0 = s0, v1 = s1;
  for (int it = 0; it < 17; it++) {
    double m; int mi;
    if (v1 > v0) { m = v1; mi = lane + 64; } else { m = v0; mi = lane; }
#pragma unroll
    for (int off = 1; off < 64; off <<= 1) {
      const double om = __shfl_xor(m, off);
      const int oi = __shfl_xor(mi, off);
      if (om > m || (om == m && oi < mi)) { m = om; mi = oi; }
    }
    if (lane == it) { selv = m; seli = mi; }
    if (mi == lane) v0 = -1e300;
    if (mi == lane + 64) v1 = -1e300;
  }
  const double mx = __shfl(selv, 0);
  const double v15 = __shfl(selv, 15);
  const double v16 = __shfl(selv, 16);
  if (lane == 0 && (v15 - v16) < TAU) {
    const int p = atomicAdd(fcnt, 1);
    if (p < MAXFLAG) flist[p] = rid;
  }
  const float e = (lane < 16) ? expf((float)(selv - mx)) : 0.0f;
  double ss = (double)e;
  ss += __shfl_xor(ss, 1); ss += __shfl_xor(ss, 2);
  ss += __shfl_xor(ss, 4); ss += __shfl_xor(ss, 8);
  if (lane < 16) {
    ow[(size_t)rid * 16 + lane] = (double)e / ss;
    oidx[(size_t)rid * 16 + lane] = seli;
  }
}

// ---------------- f64-exact fixup for flagged rows -------------------------
__global__ __launch_bounds__(256) void fixup_kernel(
    const int* __restrict__ fcnt, const int* __restrict__ flist,
    const double* __restrict__ xn, const double* __restrict__ W2,
    int* __restrict__ oidx, double* __restrict__ ow) {
  __shared__ double xsh[1024];
  __shared__ double psh[256];
  __shared__ double ssh[128];
  const int tid = threadIdx.x;
  const int n = min(*fcnt, MAXFLAG);
  for (int i = blockIdx.x; i < n; i += gridDim.x) {
    __syncthreads();
    const int rid = flist[i];
    const int t = rid & 4095, h = (rid >> 12) & 7, b = rid >> 15;
    const double* xr = xn + ((size_t)b * SEQ + t) * DIMM;
    for (int j = tid; j < DIMM; j += 256) xsh[j] = xr[j];
    __syncthreads();
    const int slot = tid >> 1, half = tid & 1;
    const double* w2r = W2 + (size_t)(h * NSLOTS + slot) * DIMM + half * 512;
    const double* xp = xsh + half * 512;
    double acc = 0.0;
#pragma unroll 8
    for (int d = 0; d < 512; d++) acc += xp[d] * w2r[d];
    psh[tid] = acc;
    __syncthreads();
    if (tid < 128) ssh[tid] = (psh[2 * tid] + psh[2 * tid + 1]) * SCALE64;
    __syncthreads();
    if (tid < 64) {
      const int lane = tid;
      double selv = -1e300; int seli = 0;
      double v0 = ssh[lane], v1 = ssh[lane + 64];
      for (int it = 0; it < 16; it++) {
        double m; int mi;
        if (v1 > v0) { m = v1; mi = lane + 64; } else { m = v0; mi = lane; }
#pragma unroll
        for (int off = 1; off < 64; off <<= 1) {
          const double om = __shfl_xor(m, off);
          const int oi = __shfl_xor(mi, off);
          if (om > m || (om == m && oi < mi)) { m = om; mi = oi; }
        }
        if (lane == it) { selv = m; seli = mi; }
        if (mi == lane) v0 = -1e300;
        if (mi == lane + 64) v1 = -1e300;
      }
      const double mx = __shfl(selv, 0);
      const float e = (lane < 16) ? expf((float)(selv - mx)) : 0.0f;
      double ss = (double)e;
      ss += __shfl_xor(ss, 1); ss += __shfl_xor(ss, 2);
      ss += __shfl_xor(ss, 4); ss += __shfl_xor(ss, 8);
      if (lane < 16) {
        ow[(size_t)rid * 16 + lane] = (double)e / ss;
        oidx[(size_t)rid * 16 + lane] = seli;
      }
    }
  }
}

// ---------------- dense per-chunk write delta, f64, stable order -----------
__global__ __launch_bounds__(512) void delta64_kernel(
    const int* __restrict__ wi, const double* __restrict__ ww,
    const double* __restrict__ V, double* __restrict__ delta) {
  __shared__ short slot_sh[4096];
  __shared__ double w_sh[4096];
  __shared__ u16 list[4096];
  __shared__ int cnt[NSLOTS], off_[NSLOTS];
  const int bid = blockIdx.x;
  const int c = bid & 15, h = (bid >> 4) & 7, b = bid >> 7;
  const int tid = threadIdx.x;
  if (tid < NSLOTS) cnt[tid] = 0;
  __syncthreads();
  const size_t ebase = ((size_t)(b * 8 + h) * SEQ + (size_t)c * CHUNK) * 16;
#pragma unroll
  for (int i = 0; i < 8; i++) {
    const int e = tid + i * 512;
    const int s = wi[ebase + e];
    slot_sh[e] = (short)s;
    w_sh[e] = ww[ebase + e];
    atomicAdd(&cnt[s], 1);
  }
  __syncthreads();
  if (tid == 0) {
    int a = 0;
    for (int s = 0; s < NSLOTS; s++) { off_[s] = a; a += cnt[s]; }
  }
  __syncthreads();
  if (tid < NSLOTS) {
    int p = off_[tid];
    const short me = (short)tid;
    for (int e = 0; e < 4096; e++)
      if (slot_sh[e] == me) list[p++] = (u16)e;
  }
  __syncthreads();
  const int slot = tid >> 2, dbase = (tid & 3) * 32;
  double acc[32] = {};
  const int start = off_[slot], len = cnt[slot];
  const double* vbase =
      V + ((size_t)b * SEQ + (size_t)c * CHUNK) * DIMM + h * DH + dbase;
  for (int i = 0; i < len; i++) {
    const int e = list[start + i];
    const double w = w_sh[e];
    const double* vp = vbase + (size_t)(e >> 4) * DIMM;
#pragma unroll
    for (int d = 0; d < 32; d++) acc[d] += w * vp[d];
  }
  double* dst = delta + ((size_t)bid * NSLOTS + slot) * DH + dbase;
#pragma unroll
  for (int d = 0; d < 32; d++) dst[d] = acc[d];
}

// ------- fused local attention: qk(f64) + softmax + pv(f64), no S buffer ---
// block = (b,c,h,rq of 8): 32 q-rows; thread (row=tid>>3, sub=tid&7).
__global__ __launch_bounds__(256) void attn_fused(
    const double* __restrict__ Q, const double* __restrict__ Kb,
    const double* __restrict__ V, double* __restrict__ outb) {
  __shared__ double Qs[32][130];
  __shared__ double KVs[16][130];
  const int idx = blockIdx.x;
  const int rq = idx & 7, h = (idx >> 3) & 7, c = (idx >> 6) & 15, b = idx >> 10;
  const int tid = threadIdx.x;
  const size_t rowbase = (size_t)b * SEQ + (size_t)c * CHUNK;
  {  // stage Q: 32 rows x 128 dims
    const int r = tid >> 3, d0 = (tid & 7) * 16;
    const double* qp = Q + (rowbase + rq * 32 + r) * DIMM + h * DH + d0;
#pragma unroll
    for (int j = 0; j < 16; j++) Qs[r][d0 + j] = qp[j];
  }
  const int row = tid >> 3;
  const int sub = tid & 7;
  const int row_abs = rq * 32 + row;
  const int ntile = 2 * rq + 2;  // key tiles of 16 covering 0..rq*32+31
  float pexp[16][2];
#pragma unroll
  for (int kt = 0; kt < 16; kt++) { pexp[kt][0] = -1e30f; pexp[kt][1] = -1e30f; }

  // ---- phase 1: scores (f64 dots), stored f32 post-scale ----
#pragma unroll
  for (int kt = 0; kt < 16; kt++) {
    if (kt < ntile) {
      __syncthreads();
      {
        const int r = tid >> 4, d0 = (tid & 15) * 8;
        const double* kp = Kb + (rowbase + kt * 16 + r) * DIMM + h * DH + d0;
#pragma unroll
        for (int j = 0; j < 8; j++) KVs[r][d0 + j] = kp[j];
      }
      __syncthreads();
#pragma unroll
      for (int kk = 0; kk < 2; kk++) {
        const int key = sub * 2 + kk;
        double s = 0.0;
#pragma unroll 8
        for (int d = 0; d < DH; d++) s += Qs[row][d] * KVs[key][d];
        const int kabs = kt * 16 + key;
        pexp[kt][kk] = (kabs <= row_abs) ? (float)(s * SCALE64) : -1e30f;
      }
    }
  }
  // ---- phase 2: softmax across the row (8 lanes per row) ----
  float m = -1e30f;
#pragma unroll
  for (int kt = 0; kt < 16; kt++) {
    m = fmaxf(m, pexp[kt][0]); m = fmaxf(m, pexp[kt][1]);
  }
  m = fmaxf(m, __shfl_xor(m, 1));
  m = fmaxf(m, __shfl_xor(m, 2));
  m = fmaxf(m, __shfl_xor(m, 4));
  double ss = 0.0;
#pragma unroll
  for (int kt = 0; kt < 16; kt++) {
#pragma unroll
    for (int j = 0; j < 2; j++) {
      const float e = __expf(pexp[kt][j] - m);
      pexp[kt][j] = e;
      ss += (double)e;
    }
  }
  ss += __shfl_xor(ss, 1); ss += __shfl_xor(ss, 2); ss += __shfl_xor(ss, 4);
  const double inv = 1.0 / ss;
#pragma unroll
  for (int kt = 0; kt < 16; kt++) {
    pexp[kt][0] = (float)((double)pexp[kt][0] * inv);
    pexp[kt][1] = (float)((double)pexp[kt][1] * inv);
  }
  // ---- phase 3: PV (f64 accumulate); thread covers dims sub*16..+15 ----
  double acc[16] = {};
#pragma unroll
  for (int kt = 0; kt < 16; kt++) {
    if (kt < ntile) {
      __syncthreads();
      {
        const int r = tid >> 4, d0 = (tid & 15) * 8;
        const double* vp = V + (rowbase + kt * 16 + r) * DIMM + h * DH + d0;
#pragma unroll
        for (int j = 0; j < 8; j++) KVs[r][d0 + j] = vp[j];
      }
      __syncthreads();
#pragma unroll
      for (int key = 0; key < 16; key++) {
        const int src = (tid & 56) | (key >> 1);  // lane within wave
        const float pf = __shfl(pexp[kt][key & 1], src, 64);
        const double pd = (double)pf;
        const double* vr = &KVs[key][sub * 16];
#pragma unroll
        for (int d = 0; d < 16; d++) acc[d] += pd * vr[d];
      }
    }
  }
  double* op = outb + (rowbase + row_abs) * DIMM + h * DH + sub * 16;
#pragma unroll
  for (int d = 0; d < 16; d++) op[d] = acc[d];
}

// ------- sequential M recurrence, f64; emits split3(local+read) ------------
__global__ __launch_bounds__(256) void recur64_kernel(
    const int* __restrict__ ri, const double* __restrict__ rw,
    const double* __restrict__ delta, const double* __restrict__ inb,
    u16* __restrict__ sh, u16* __restrict__ sm, u16* __restrict__ sl) {
  __shared__ double Msh[NSLOTS][17];
  const int bid = blockIdx.x;
  const int ds = bid & 7, h = (bid >> 3) & 7, b = bid >> 6;
  const int tid = threadIdx.x;
  for (int i = tid; i < NSLOTS * 17; i += 256) ((double*)Msh)[i] = 0.0;
  __syncthreads();
  for (int c = 0; c < NCHUNK; c++) {
    const size_t rbase =
        ((size_t)(b * 8 + h) * SEQ + (size_t)c * CHUNK + tid) * 16;
    double a[16] = {};
#pragma unroll
    for (int j = 0; j < 16; j++) {
      const int slot = ri[rbase + j];
      const double w = rw[rbase + j];
      const double* mp = &Msh[slot][0];
#pragma unroll
      for (int d = 0; d < 16; d++) a[d] += w * mp[d];
    }
    const size_t base = ((size_t)b * SEQ + (size_t)c * CHUNK + tid) * DIMM +
                        h * DH + ds * 16;
    const double* ip = inb + base;
    u16x4 rh[4], rm[4], rl[4];
#pragma unroll
    for (int q = 0; q < 4; q++) {
      float f0 = (float)(ip[q * 4 + 0] + a[q * 4 + 0]);
      float f1 = (float)(ip[q * 4 + 1] + a[q * 4 + 1]);
      float f2 = (float)(ip[q * 4 + 2] + a[q * 4 + 2]);
      float f3 = (float)(ip[q * 4 + 3] + a[q * 4 + 3]);
      split3s(f0, rh[q].x, rm[q].x, rl[q].x);
      split3s(f1, rh[q].y, rm[q].y, rl[q].y);
      split3s(f2, rh[q].z, rm[q].z, rl[q].z);
      split3s(f3, rh[q].w, rm[q].w, rl[q].w);
    }
#pragma unroll
    for (int q = 0; q < 4; q++) {
      ((u16x4*)(sh + base))[q] = rh[q];
      ((u16x4*)(sm + base))[q] = rm[q];
      ((u16x4*)(sl + base))[q] = rl[q];
    }
    __syncthreads();
    const int slot = tid >> 1, d8 = (tid & 1) * 8;
    const double* dp = delta +
        (((size_t)(b * 8 + h) * NCHUNK + c) * NSLOTS + slot) * DH + ds * 16 + d8;
#pragma unroll
    for (int d = 0; d < 8; d++)
      Msh[slot][d8 + d] = GAMMA64 * Msh[slot][d8 + d] + dp[d];
    __syncthreads();
  }
}

// ---------------- W[K][N] f32 -> WT[N][K] bf16 -----------------------------
__global__ void transconv_kernel(const float* __restrict__ W,
                                 u16* __restrict__ WT, int K, int N) {
  __shared__ float tile[32][33];
  const int n0 = blockIdx.x * 32, k0 = blockIdx.y * 32;
  const int tx = threadIdx.x, ty = threadIdx.y;
#pragma unroll
  for (int i = 0; i < 4; i++)
    tile[ty + 8 * i][tx] = W[(size_t)(k0 + ty + 8 * i) * N + n0 + tx];
  __syncthreads();
#pragma unroll
  for (int i = 0; i < 4; i++)
    WT[(size_t)(n0 + ty + 8 * i) * K + k0 + tx] = f2bf(tile[tx][ty + 8 * i]);
}

// ---------------- bf16 MFMA GEMM for logits (GROUP_N=16 supertile) ---------
template <bool BIAS>
__global__ __launch_bounds__(256) void gemm_kernel(
    const u16* __restrict__ A, const u16* __restrict__ B, float* __restrict__ C,
    const float* __restrict__ bias, int M, int N, int K) {
  __shared__ u16 As[128 * 32];
  __shared__ u16 Bs[128 * 32];
  const int tid = threadIdx.x;
  const int lid = blockIdx.y * gridDim.x + blockIdx.x;
  const int npm = M / 128;
  const int ngrid = N / 128;
  const int GN = 16;
  const int ppg = GN * npm;
  const int gid = lid / ppg;
  const int first_n = gid * GN;
  const int gsz = min(GN, ngrid - first_n);
  const int local = lid - gid * ppg;
  const int bn = first_n + local % gsz;
  const int bm = local / gsz;
  const int wid = tid >> 6, lane = tid & 63;
  const int wr = (wid >> 1) * 64, wc = (wid & 1) * 64;
  f32x4 acc[4][4] = {};
  const int row0 = tid >> 2;
  const int colb = (tid & 3) << 4;
  const char* A0 = (const char*)A + ((size_t)(bm * 128 + row0) * K) * 2 + colb;
  const char* A1 = (const char*)A + ((size_t)(bm * 128 + row0 + 64) * K) * 2 + colb;
  const char* B0 = (const char*)B + ((size_t)(bn * 128 + row0) * K) * 2 + colb;
  const char* B1 = (const char*)B + ((size_t)(bn * 128 + row0 + 64) * K) * 2 + colb;
  char* lA0 = (char*)As + (tid & 192) * 16;
  char* lB0 = (char*)Bs + (tid & 192) * 16;
  const char* pa = (const char*)As + wr * 64 + (lane & 15) * 64 + (lane >> 4) * 16;
  const char* pb = (const char*)Bs + wc * 64 + (lane & 15) * 64 + (lane >> 4) * 16;
  for (int k0 = 0; k0 < K; k0 += 32) {
    const size_t kb = (size_t)k0 * 2;
    gld16(lA0, A0 + kb);
    gld16(lA0 + 4096, A1 + kb);
    gld16(lB0, B0 + kb);
    gld16(lB0 + 4096, B1 + kb);
    __syncthreads();
    s16x8 af[4], bf[4];
#pragma unroll
    for (int m = 0; m < 4; m++) af[m] = *(const s16x8*)(pa + m * 1024);
#pragma unroll
    for (int n = 0; n < 4; n++) bf[n] = *(const s16x8*)(pb + n * 1024);
#pragma unroll
    for (int m = 0; m < 4; m++)
#pragma unroll
      for (int n = 0; n < 4; n++) acc[m][n] = mfma16(af[m], bf[n], acc[m][n]);
    __syncthreads();
  }
#pragma unroll
  for (int m = 0; m < 4; m++)
#pragma unroll
    for (int n = 0; n < 4; n++)
#pragma unroll
      for (int j = 0; j < 4; j++) {
        const int r = bm * 128 + wr + m * 16 + (lane >> 4) * 4 + j;
        const int c = bn * 128 + wc + n * 16 + (lane & 15);
        float v = acc[m][n][j];
        if (BIAS) v += bias[c];
        C[(size_t)r * N + c] = v;
      }
}

extern "C" void kernel_launch(void* const* d_in, const int* in_sizes, int n_in,
                              void* d_out, int out_size, void* d_ws,
                              size_t ws_size, hipStream_t stream) {
  (void)in_sizes; (void)n_in; (void)out_size; (void)ws_size;
  const int* tokens = (const int*)d_in[0];
  const float* embed = (const float*)d_in[1];
  const float* Wq = (const float*)d_in[2];
  const float* Wk = (const float*)d_in[3];
  const float* Wv = (const float*)d_in[4];
  const float* Wo = (const float*)d_in[5];
  const float* slot_keys = (const float*)d_in[6];
  const float* ln_g = (const float*)d_in[7];
  const float* ln_b = (const float*)d_in[8];
  const float* fg = (const float*)d_in[9];
  const float* fb = (const float*)d_in[10];
  const float* Wout = (const float*)d_in[11];
  const float* bout = (const float*)d_in[12];
  float* out = (float*)d_out;

  char* p = (char*)d_ws;
  auto alloc = [&](size_t bytes) -> char* {
    char* r = p;
    p += (bytes + 255) & ~(size_t)255;
    return r;
  };
  const size_t RD = (size_t)NROWS * DIMM;
  double* hidden64 = (double*)alloc(RD * 8);
  double* xn64 = (double*)alloc(RD * 8);      // aliased as local64 later
  double* q64 = (double*)alloc(RD * 8);       // aliased as xnb (bf16) at end
  double* k64 = (double*)alloc(RD * 8);       // aliased as WoutT (bf16) at end
  double* v64 = (double*)alloc(RD * 8);
  double* delta64 =
      (double*)alloc((size_t)NB * NHEADS * NCHUNK * NSLOTS * DH * 8);
  int* ri = (int*)alloc((size_t)65536 * 16 * 4);
  int* wi = (int*)alloc((size_t)65536 * 16 * 4);
  double* rw64 = (double*)alloc((size_t)65536 * 16 * 8);
  double* ww64 = (double*)alloc((size_t)65536 * 16 * 8);
  u16* sAh = (u16*)alloc(RD * 2);
  u16* sAm = (u16*)alloc(RD * 2);
  u16* sAl = (u16*)alloc(RD * 2);
  u16* WTh = (u16*)alloc((size_t)8 * DIMM * DIMM * 2);  // l*4+{q,k,v,o}
  u16* WTm = (u16*)alloc((size_t)8 * DIMM * DIMM * 2);
  u16* WTl = (u16*)alloc((size_t)8 * DIMM * DIMM * 2);
  double* W2q = (double*)alloc((size_t)2 * DIMM * DIMM * 8);
  double* W2k = (double*)alloc((size_t)2 * DIMM * DIMM * 8);
  int* fcnts = (int*)alloc(256);
  int* flq = (int*)alloc((size_t)MAXFLAG * 4);
  int* flk = (int*)alloc((size_t)MAXFLAG * 4);

  double* local64 = xn64;  // xn64 dead after fixup consumed it
  u16* xnb = (u16*)q64;    // used only after layer-2 attn
  u16* WoutT = (u16*)k64;  // used only after layer-2 attn

  const float* Wmats[4] = {Wq, Wk, Wv, Wo};
  for (int l = 0; l < 2; l++) {
    for (int w = 0; w < 4; w++) {
      const size_t o = ((size_t)l * 4 + w) * DIMM * DIMM;
      transconv3_kernel<<<dim3(DIMM / 32, DIMM / 32), dim3(32, 8), 0, stream>>>(
          Wmats[w] + (size_t)l * DIMM * DIMM, WTh + o, WTm + o, WTl + o, DIMM,
          DIMM);
    }
    const float* skl = slot_keys + (size_t)l * NHEADS * NSLOTS * DH;
    w2_kernel<<<1024, 256, 0, stream>>>(Wq + (size_t)l * DIMM * DIMM, skl,
                                        W2q + (size_t)l * DIMM * DIMM);
    w2_kernel<<<1024, 256, 0, stream>>>(Wk + (size_t)l * DIMM * DIMM, skl,
                                        W2k + (size_t)l * DIMM * DIMM);
  }

  embed64_kernel<<<NROWS, 256, 0, stream>>>(tokens, embed, hidden64);

  const dim3 g3(DIMM / 128, NROWS / 128);
  for (int l = 0; l < 2; l++) {
    const size_t oq = ((size_t)l * 4 + 0) * DIMM * DIMM;
    const size_t ok = ((size_t)l * 4 + 1) * DIMM * DIMM;
    const size_t ov = ((size_t)l * 4 + 2) * DIMM * DIMM;
    const size_t oo = ((size_t)l * 4 + 3) * DIMM * DIMM;
    ln64_kernel<0><<<NROWS, 256, 0, stream>>>(hidden64, ln_g + l * DIMM,
                                              ln_b + l * DIMM, xn64, sAh, sAm,
                                              sAl);
    gemm3d_kernel<false><<<g3, 256, 0, stream>>>(
        sAh, sAm, sAl, WTh + oq, WTm + oq, WTl + oq, q64, nullptr, NROWS, DIMM,
        DIMM);
    gemm3d_kernel<false><<<g3, 256, 0, stream>>>(
        sAh, sAm, sAl, WTh + ok, WTm + ok, WTl + ok, k64, nullptr, NROWS, DIMM,
        DIMM);
    gemm3d_kernel<false><<<g3, 256, 0, stream>>>(
        sAh, sAm, sAl, WTh + ov, WTm + ov, WTl + ov, v64, nullptr, NROWS, DIMM,
        DIMM);
    const float* skl = slot_keys + (size_t)l * NHEADS * NSLOTS * DH;
    hipMemsetAsync(fcnts, 0, 8, stream);
    topk_flag_kernel<<<16384, 256, 0, stream>>>(q64, skl, ri, rw64, fcnts,
                                                flq);
    topk_flag_kernel<<<16384, 256, 0, stream>>>(k64, skl, wi, ww64, fcnts + 1,
                                                flk);
    fixup_kernel<<<1024, 256, 0, stream>>>(
        fcnts, flq, xn64, W2q + (size_t)l * DIMM * DIMM, ri, rw64);
    fixup_kernel<<<1024, 256, 0, stream>>>(
        fcnts + 1, flk, xn64, W2k + (size_t)l * DIMM * DIMM, wi, ww64);
    delta64_kernel<<<NB * NHEADS * NCHUNK, 512, 0, stream>>>(wi, ww64, v64,
                                                             delta64);
    attn_fused<<<NB * NCHUNK * NHEADS * 8, 256, 0, stream>>>(q64, k64, v64,
                                                             local64);
    recur64_kernel<<<NB * NHEADS * 8, 256, 0, stream>>>(ri, rw64, delta64,
                                                        local64, sAh, sAm,
                                                        sAl);
    gemm3d_kernel<true><<<g3, 256, 0, stream>>>(
        sAh, sAm, sAl, WTh + oo, WTm + oo, WTl + oo, hidden64, hidden64, NROWS,
        DIMM, DIMM);
  }
  transconv_kernel<<<dim3(NVOCAB / 32, DIMM / 32), dim3(32, 8), 0, stream>>>(
      Wout, WoutT, DIMM, NVOCAB);
  ln64_kernel<1><<<NROWS, 256, 0, stream>>>(hidden64, fg, fb, nullptr, xnb,
                                            nullptr, nullptr);
  gemm_kernel<true><<<dim3(NVOCAB / 128, NROWS / 128), 256, 0, stream>>>(
      xnb, WoutT, out, bout, NROWS, NVOCAB, DIMM);
}

// Round 10
// 6313.768 us; speedup vs baseline: 1.6707x; 1.1499x over previous
//
#include <hip/hip_runtime.h>

#define DIMM 1024
#define NHEADS 8
#define DH 128
#define NSLOTS 128
#define CHUNK 256
#define NCHUNK 16
#define NB 2
#define SEQ 4096
#define NROWS (NB * SEQ)
#define NVOCAB 32000
#define GAMMA64 0.9
#define SCALE64 0.08838834764831845
#define TAU 1e-6
#define MAXFLAG 65536

typedef unsigned short u16;
typedef __attribute__((ext_vector_type(4))) float f32x4;
typedef __attribute__((ext_vector_type(8))) short s16x8;

struct alignas(8) u16x4 { u16 x, y, z, w; };

__device__ __forceinline__ u16 f2bf(float f) {
  union { float f; unsigned u; } v; v.f = f;
  return (u16)((v.u + 0x7FFFu + ((v.u >> 16) & 1u)) >> 16);
}
__device__ __forceinline__ float bf2f(u16 u) {
  union { unsigned u; float f; } v; v.u = ((unsigned)u) << 16; return v.f;
}
// exact 3-way bf16 split of an f32 (h+m+l == x exactly)
__device__ __forceinline__ void split3s(float x, u16& h, u16& m, u16& l) {
  h = f2bf(x); float r = x - bf2f(h);
  m = f2bf(r); float r2 = r - bf2f(m);
  l = f2bf(r2);
}

__device__ __forceinline__ void gld16(void* lds, const void* g) {
  __builtin_amdgcn_global_load_lds(
      (const __attribute__((address_space(1))) unsigned*)g,
      (__attribute__((address_space(3))) unsigned*)lds, 16, 0, 0);
}
__device__ __forceinline__ f32x4 mfma16(s16x8 a, s16x8 b, f32x4 c) {
  return __builtin_amdgcn_mfma_f32_16x16x32_bf16(a, b, c, 0, 0, 0);
}

// ---------------- embedding gather -> f64 ----------------
__global__ __launch_bounds__(256) void embed64_kernel(
    const int* __restrict__ tok, const float* __restrict__ emb,
    double* __restrict__ hid) {
  const int row = blockIdx.x;
  const int t = tok[row];
  const float4 v = ((const float4*)(emb + (size_t)t * DIMM))[threadIdx.x];
  double* o = hid + (size_t)row * DIMM + threadIdx.x * 4;
  o[0] = (double)v.x; o[1] = (double)v.y; o[2] = (double)v.z; o[3] = (double)v.w;
}

// ------- f64 two-pass layernorm; MODE0: f64 xn + split3; MODE1: bf16 -------
template <int MODE>
__global__ __launch_bounds__(256) void ln64_kernel(
    const double* __restrict__ x, const float* __restrict__ g,
    const float* __restrict__ bb, double* __restrict__ o64,
    u16* __restrict__ oh, u16* __restrict__ om, u16* __restrict__ ol) {
  const int row = blockIdx.x, tid = threadIdx.x;
  const double* xr = x + (size_t)row * DIMM + tid * 4;
  const double v0 = xr[0], v1 = xr[1], v2 = xr[2], v3 = xr[3];
  __shared__ double red[4];
  double s1 = v0 + v1 + v2 + v3;
#pragma unroll
  for (int off = 32; off >= 1; off >>= 1) s1 += __shfl_xor(s1, off);
  if ((tid & 63) == 0) red[tid >> 6] = s1;
  __syncthreads();
  const double mu = (red[0] + red[1] + red[2] + red[3]) * (1.0 / DIMM);
  __syncthreads();
  const double d0 = v0 - mu, d1 = v1 - mu, d2 = v2 - mu, d3 = v3 - mu;
  double s2 = d0 * d0 + d1 * d1 + d2 * d2 + d3 * d3;
#pragma unroll
  for (int off = 32; off >= 1; off >>= 1) s2 += __shfl_xor(s2, off);
  if ((tid & 63) == 0) red[tid >> 6] = s2;
  __syncthreads();
  const double var = (red[0] + red[1] + red[2] + red[3]) * (1.0 / DIMM);
  const double rs = 1.0 / sqrt(var + 1e-5);
  const float4 g4 = ((const float4*)g)[tid];
  const float4 b4 = ((const float4*)bb)[tid];
  const double y0 = d0 * rs * (double)g4.x + (double)b4.x;
  const double y1 = d1 * rs * (double)g4.y + (double)b4.y;
  const double y2 = d2 * rs * (double)g4.z + (double)b4.z;
  const double y3 = d3 * rs * (double)g4.w + (double)b4.w;
  if (MODE == 0) {
    double* o = o64 + (size_t)row * DIMM + tid * 4;
    o[0] = y0; o[1] = y1; o[2] = y2; o[3] = y3;
    u16x4 rh, rm, rl;
    split3s((float)y0, rh.x, rm.x, rl.x);
    split3s((float)y1, rh.y, rm.y, rl.y);
    split3s((float)y2, rh.z, rm.z, rl.z);
    split3s((float)y3, rh.w, rm.w, rl.w);
    ((u16x4*)(oh + (size_t)row * DIMM))[tid] = rh;
    ((u16x4*)(om + (size_t)row * DIMM))[tid] = rm;
    ((u16x4*)(ol + (size_t)row * DIMM))[tid] = rl;
  } else {
    u16x4 r;
    r.x = f2bf((float)y0); r.y = f2bf((float)y1);
    r.z = f2bf((float)y2); r.w = f2bf((float)y3);
    ((u16x4*)(oh + (size_t)row * DIMM))[tid] = r;
  }
}

// ---------------- W[K][N] f32 -> WT[N][K] split3 bf16 ----------------
__global__ void transconv3_kernel(const float* __restrict__ W,
                                  u16* __restrict__ WTh, u16* __restrict__ WTm,
                                  u16* __restrict__ WTl, int K, int N) {
  __shared__ float tile[32][33];
  const int n0 = blockIdx.x * 32, k0 = blockIdx.y * 32;
  const int tx = threadIdx.x, ty = threadIdx.y;
#pragma unroll
  for (int i = 0; i < 4; i++)
    tile[ty + 8 * i][tx] = W[(size_t)(k0 + ty + 8 * i) * N + n0 + tx];
  __syncthreads();
#pragma unroll
  for (int i = 0; i < 4; i++) {
    u16 h, m, l;
    split3s(tile[tx][ty + 8 * i], h, m, l);
    const size_t o = (size_t)(n0 + ty + 8 * i) * K + k0 + tx;
    WTh[o] = h; WTm[o] = m; WTl[o] = l;
  }
}

// ---------------- combined slot-score weights: W2 (f64 exact) --------------
__global__ __launch_bounds__(256) void w2_kernel(const float* __restrict__ W,
                                                 const float* __restrict__ sk,
                                                 double* __restrict__ W2) {
  __shared__ float sksh[128];
  const int r = blockIdx.x, h = r >> 7;
  const int tid = threadIdx.x;
  if (tid < 128) sksh[tid] = sk[(size_t)r * DH + tid];
  __syncthreads();
  for (int d = tid; d < DIMM; d += 256) {
    const float* wrow = W + (size_t)d * DIMM + h * DH;
    double acc = 0.0;
#pragma unroll 8
    for (int j = 0; j < 128; j++) acc += (double)wrow[j] * (double)sksh[j];
    W2[(size_t)r * DIMM + d] = acc;
  }
}

// ------- split3 f32-faithful GEMM -> TC out: C = A @ BT^T (+res) ----------
template <bool RES, typename TC>
__global__ __launch_bounds__(256) void gemm3d_kernel(
    const u16* __restrict__ Ah, const u16* __restrict__ Am,
    const u16* __restrict__ Al, const u16* __restrict__ Bh,
    const u16* __restrict__ Bm, const u16* __restrict__ Bl,
    TC* __restrict__ C, const TC* __restrict__ Cres, int M, int N, int K) {
  __shared__ u16 lds[6 * 128 * 32];
  const int tid = threadIdx.x;
  const int bn = blockIdx.x, bm = blockIdx.y;
  const int wid = tid >> 6, lane = tid & 63;
  const int wr = (wid >> 1) * 64, wc = (wid & 1) * 64;
  f32x4 acc[4][4] = {};
  const int row0 = tid >> 2;
  const int colb = (tid & 3) << 4;
  const u16* Gs[6] = {Ah, Am, Al, Bh, Bm, Bl};
  const char* g0[6];
  const char* g1[6];
  char* lb[6];
#pragma unroll
  for (int i = 0; i < 6; i++) {
    const int rbase = (i < 3 ? bm : bn) * 128;
    g0[i] = (const char*)Gs[i] + ((size_t)(rbase + row0) * K) * 2 + colb;
    g1[i] = (const char*)Gs[i] + ((size_t)(rbase + row0 + 64) * K) * 2 + colb;
    lb[i] = (char*)lds + i * 8192 + (tid & 192) * 16;
  }
  const int fo = (lane & 15) * 64 + (lane >> 4) * 16;
  const char* paH = (const char*)lds + 0 + wr * 64 + fo;
  const char* paM = paH + 8192;
  const char* paL = paH + 16384;
  const char* pbH = (const char*)lds + 24576 + wc * 64 + fo;
  const char* pbM = pbH + 8192;
  const char* pbL = pbH + 16384;

  for (int k0 = 0; k0 < K; k0 += 32) {
    const size_t kb = (size_t)k0 * 2;
#pragma unroll
    for (int i = 0; i < 6; i++) {
      gld16(lb[i], g0[i] + kb);
      gld16(lb[i] + 4096, g1[i] + kb);
    }
    __syncthreads();
    s16x8 bh[4], bm_[4], bl[4];
#pragma unroll
    for (int n = 0; n < 4; n++) {
      bh[n] = *(const s16x8*)(pbH + n * 1024);
      bm_[n] = *(const s16x8*)(pbM + n * 1024);
      bl[n] = *(const s16x8*)(pbL + n * 1024);
    }
#pragma unroll
    for (int m = 0; m < 4; m++) {
      const s16x8 ah = *(const s16x8*)(paH + m * 1024);
      const s16x8 am = *(const s16x8*)(paM + m * 1024);
      const s16x8 al = *(const s16x8*)(paL + m * 1024);
#pragma unroll
      for (int n = 0; n < 4; n++) {
        f32x4 t = acc[m][n];
        t = mfma16(al, bh[n], t);
        t = mfma16(ah, bl[n], t);
        t = mfma16(am, bm_[n], t);
        t = mfma16(am, bh[n], t);
        t = mfma16(ah, bm_[n], t);
        t = mfma16(ah, bh[n], t);
        acc[m][n] = t;
      }
    }
    __syncthreads();
  }
#pragma unroll
  for (int m = 0; m < 4; m++)
#pragma unroll
    for (int n = 0; n < 4; n++)
#pragma unroll
      for (int j = 0; j < 4; j++) {
        const int r = bm * 128 + wr + m * 16 + (lane >> 4) * 4 + j;
        const int c = bn * 128 + wc + n * 16 + (lane & 15);
        TC v = (TC)acc[m][n][j];
        if (RES) v += Cres[(size_t)r * N + c];
        C[(size_t)r * N + c] = v;
      }
}

// -------- merged q/k top-16 (f32 in, f64 dots) + near-tie flagging ---------
__global__ __launch_bounds__(256) void topk_flag_kernel(
    const float* __restrict__ Q, const float* __restrict__ K,
    const float* __restrict__ sk, int* __restrict__ riQ, int* __restrict__ riK,
    double* __restrict__ rwQ, double* __restrict__ rwK,
    int* __restrict__ fcnts, int* __restrict__ flq, int* __restrict__ flk) {
  __shared__ float vsh[4][130];
  const int which = blockIdx.y;
  const float* X = which ? K : Q;
  int* oidx = which ? riK : riQ;
  double* ow = which ? rwK : rwQ;
  int* fcnt = fcnts + which;
  int* flist = which ? flk : flq;
  const int wid = threadIdx.x >> 6, lane = threadIdx.x & 63;
  const int rid = blockIdx.x * 4 + wid;  // (b*8+h)*4096 + t
  const int t = rid & 4095, h = (rid >> 12) & 7, b = rid >> 15;
  const float* xrow = X + ((size_t)b * SEQ + t) * DIMM + h * DH;
  vsh[wid][lane * 2] = xrow[lane * 2];
  vsh[wid][lane * 2 + 1] = xrow[lane * 2 + 1];
  const float* skh = sk + (size_t)h * NSLOTS * DH;
  double s0 = 0.0, s1 = 0.0;
#pragma unroll 8
  for (int d = 0; d < DH; d++) {
    const double v = (double)vsh[wid][d];
    s0 += v * (double)skh[(size_t)lane * DH + d];
    s1 += v * (double)skh[(size_t)(lane + 64) * DH + d];
  }
  s0 *= SCALE64; s1 *= SCALE64;
  double selv = -1e300; int seli = 0;
  double v0 = s0, v1 = s1;
  for (int it = 0; it < 17; it++) {
    double m; int mi;
    if (v1 > v0) { m = v1; mi = lane + 64; } else { m = v0; mi = lane; }
#pragma unroll
    for (int off = 1; off < 64; off <<= 1) {
      const double om = __shfl_xor(m, off);
      const int oi = __shfl_xor(mi, off);
      if (om > m || (om == m && oi < mi)) { m = om; mi = oi; }
    }
    if (lane == it) { selv = m; seli = mi; }
    if (mi == lane) v0 = -1e300;
    if (mi == lane + 64) v1 = -1e300;
  }
  const double mx = __shfl(selv, 0);
  const double v15 = __shfl(selv, 15);
  const double v16 = __shfl(selv, 16);
  if (lane == 0 && (v15 - v16) < TAU) {
    const int p = atomicAdd(fcnt, 1);
    if (p < MAXFLAG) flist[p] = rid;
  }
  const float e = (lane < 16) ? expf((float)(selv - mx)) : 0.0f;
  double ss = (double)e;
  ss += __shfl_xor(ss, 1); ss += __shfl_xor(ss, 2);
  ss += __shfl_xor(ss, 4); ss += __shfl_xor(ss, 8);
  if (lane < 16) {
    ow[(size_t)rid * 16 + lane] = (double)e / ss;
    oidx[(size_t)rid * 16 + lane] = seli;
  }
}

// ---------------- merged f64-exact fixup for flagged rows ------------------
__global__ __launch_bounds__(256) void fixup_kernel(
    const int* __restrict__ fcnts, const int* __restrict__ flq,
    const int* __restrict__ flk, const double* __restrict__ xn,
    const double* __restrict__ W2q, const double* __restrict__ W2k,
    int* __restrict__ riQ, int* __restrict__ riK, double* __restrict__ rwQ,
    double* __restrict__ rwK) {
  __shared__ double xsh[1024];
  __shared__ double psh[256];
  __shared__ double ssh[128];
  const int which = blockIdx.y;
  const int* flist = which ? flk : flq;
  const double* W2 = which ? W2k : W2q;
  int* oidx = which ? riK : riQ;
  double* ow = which ? rwK : rwQ;
  const int tid = threadIdx.x;
  const int n = min(fcnts[which], MAXFLAG);
  for (int i = blockIdx.x; i < n; i += gridDim.x) {
    __syncthreads();
    const int rid = flist[i];
    const int t = rid & 4095, h = (rid >> 12) & 7, b = rid >> 15;
    const double* xr = xn + ((size_t)b * SEQ + t) * DIMM;
    for (int j = tid; j < DIMM; j += 256) xsh[j] = xr[j];
    __syncthreads();
    const int slot = tid >> 1, half = tid & 1;
    const double* w2r = W2 + (size_t)(h * NSLOTS + slot) * DIMM + half * 512;
    const double* xp = xsh + half * 512;
    double acc = 0.0;
#pragma unroll 8
    for (int d = 0; d < 512; d++) acc += xp[d] * w2r[d];
    psh[tid] = acc;
    __syncthreads();
    if (tid < 128) ssh[tid] = (psh[2 * tid] + psh[2 * tid + 1]) * SCALE64;
    __syncthreads();
    if (tid < 64) {
      const int lane = tid;
      double selv = -1e300; int seli = 0;
      double v0 = ssh[lane], v1 = ssh[lane + 64];
      for (int it = 0; it < 16; it++) {
        double m; int mi;
        if (v1 > v0) { m = v1; mi = lane + 64; } else { m = v0; mi = lane; }
#pragma unroll
        for (int off = 1; off < 64; off <<= 1) {
          const double om = __shfl_xor(m, off);
          const int oi = __shfl_xor(mi, off);
          if (om > m || (om == m && oi < mi)) { m = om; mi = oi; }
        }
        if (lane == it) { selv = m; seli = mi; }
        if (mi == lane) v0 = -1e300;
        if (mi == lane + 64) v1 = -1e300;
      }
      const double mx = __shfl(selv, 0);
      const float e = (lane < 16) ? expf((float)(selv - mx)) : 0.0f;
      double ss = (double)e;
      ss += __shfl_xor(ss, 1); ss += __shfl_xor(ss, 2);
      ss += __shfl_xor(ss, 4); ss += __shfl_xor(ss, 8);
      if (lane < 16) {
        ow[(size_t)rid * 16 + lane] = (double)e / ss;
        oidx[(size_t)rid * 16 + lane] = seli;
      }
    }
  }
}

// ------- dense per-chunk write delta (V f32, f64 accum, stable order) ------
__global__ __launch_bounds__(512) void delta64_kernel(
    const int* __restrict__ wi, const double* __restrict__ ww,
    const float* __restrict__ V, double* __restrict__ delta) {
  __shared__ short slot_sh[4096];
  __shared__ double w_sh[4096];
  __shared__ u16 list[4096];
  __shared__ int cnt[NSLOTS], off_[NSLOTS];
  const int bid = blockIdx.x;
  const int c = bid & 15, h = (bid >> 4) & 7, b = bid >> 7;
  const int tid = threadIdx.x;
  if (tid < NSLOTS) cnt[tid] = 0;
  __syncthreads();
  const size_t ebase = ((size_t)(b * 8 + h) * SEQ + (size_t)c * CHUNK) * 16;
#pragma unroll
  for (int i = 0; i < 8; i++) {
    const int e = tid + i * 512;
    const int s = wi[ebase + e];
    slot_sh[e] = (short)s;
    w_sh[e] = ww[ebase + e];
    atomicAdd(&cnt[s], 1);
  }
  __syncthreads();
  if (tid == 0) {
    int a = 0;
    for (int s = 0; s < NSLOTS; s++) { off_[s] = a; a += cnt[s]; }
  }
  __syncthreads();
  if (tid < NSLOTS) {
    int p = off_[tid];
    const short me = (short)tid;
    for (int e = 0; e < 4096; e++)
      if (slot_sh[e] == me) list[p++] = (u16)e;
  }
  __syncthreads();
  const int slot = tid >> 2, dbase = (tid & 3) * 32;
  double acc[32] = {};
  const int start = off_[slot], len = cnt[slot];
  const float* vbase =
      V + ((size_t)b * SEQ + (size_t)c * CHUNK) * DIMM + h * DH + dbase;
  for (int i = 0; i < len; i++) {
    const int e = list[start + i];
    const double w = w_sh[e];
    const float* vp = vbase + (size_t)(e >> 4) * DIMM;
#pragma unroll
    for (int d = 0; d < 32; d++) acc[d] += w * (double)vp[d];
  }
  double* dst = delta + ((size_t)bid * NSLOTS + slot) * DH + dbase;
#pragma unroll
  for (int d = 0; d < 32; d++) dst[d] = acc[d];
}

// --- fused local attention: f32 storage, f64 dots/accum, no S buffer -------
__global__ __launch_bounds__(256) void attn_fused(
    const float* __restrict__ Q, const float* __restrict__ Kb,
    const float* __restrict__ V, float* __restrict__ outb) {
  __shared__ float Qs[32][130];
  __shared__ float KVs[16][130];
  const int idx = blockIdx.x;
  const int rq = idx & 7, h = (idx >> 3) & 7, c = (idx >> 6) & 15, b = idx >> 10;
  const int tid = threadIdx.x;
  const size_t rowbase = (size_t)b * SEQ + (size_t)c * CHUNK;
  {  // stage Q: 32 rows x 128 dims
    const int r = tid >> 3, d0 = (tid & 7) * 16;
    const float* qp = Q + (rowbase + rq * 32 + r) * DIMM + h * DH + d0;
#pragma unroll
    for (int j = 0; j < 16; j++) Qs[r][d0 + j] = qp[j];
  }
  const int row = tid >> 3;
  const int sub = tid & 7;
  const int row_abs = rq * 32 + row;
  const int ntile = 2 * rq + 2;
  float pexp[16][2];
#pragma unroll
  for (int kt = 0; kt < 16; kt++) { pexp[kt][0] = -1e30f; pexp[kt][1] = -1e30f; }

  // ---- phase 1: scores (f64 dots), stored f32 post-scale ----
#pragma unroll
  for (int kt = 0; kt < 16; kt++) {
    if (kt < ntile) {
      __syncthreads();
      {
        const int r = tid >> 4, d0 = (tid & 15) * 8;
        const float* kp = Kb + (rowbase + kt * 16 + r) * DIMM + h * DH + d0;
#pragma unroll
        for (int j = 0; j < 8; j++) KVs[r][d0 + j] = kp[j];
      }
      __syncthreads();
#pragma unroll
      for (int kk = 0; kk < 2; kk++) {
        const int key = sub * 2 + kk;
        double s = 0.0;
#pragma unroll 8
        for (int d = 0; d < DH; d++)
          s += (double)Qs[row][d] * (double)KVs[key][d];
        const int kabs = kt * 16 + key;
        pexp[kt][kk] = (kabs <= row_abs) ? (float)(s * SCALE64) : -1e30f;
      }
    }
  }
  // ---- phase 2: softmax across the row (8 lanes per row) ----
  float m = -1e30f;
#pragma unroll
  for (int kt = 0; kt < 16; kt++) {
    m = fmaxf(m, pexp[kt][0]); m = fmaxf(m, pexp[kt][1]);
  }
  m = fmaxf(m, __shfl_xor(m, 1));
  m = fmaxf(m, __shfl_xor(m, 2));
  m = fmaxf(m, __shfl_xor(m, 4));
  double ss = 0.0;
#pragma unroll
  for (int kt = 0; kt < 16; kt++) {
#pragma unroll
    for (int j = 0; j < 2; j++) {
      const float e = __expf(pexp[kt][j] - m);
      pexp[kt][j] = e;
      ss += (double)e;
    }
  }
  ss += __shfl_xor(ss, 1); ss += __shfl_xor(ss, 2); ss += __shfl_xor(ss, 4);
  const double inv = 1.0 / ss;
#pragma unroll
  for (int kt = 0; kt < 16; kt++) {
    pexp[kt][0] = (float)((double)pexp[kt][0] * inv);
    pexp[kt][1] = (float)((double)pexp[kt][1] * inv);
  }
  // ---- phase 3: PV (f64 accumulate) ----
  double acc[16] = {};
#pragma unroll
  for (int kt = 0; kt < 16; kt++) {
    if (kt < ntile) {
      __syncthreads();
      {
        const int r = tid >> 4, d0 = (tid & 15) * 8;
        const float* vp = V + (rowbase + kt * 16 + r) * DIMM + h * DH + d0;
#pragma unroll
        for (int j = 0; j < 8; j++) KVs[r][d0 + j] = vp[j];
      }
      __syncthreads();
#pragma unroll
      for (int key = 0; key < 16; key++) {
        const int src = (tid & 56) | (key >> 1);
        const float pf = __shfl(pexp[kt][key & 1], src, 64);
        const double pd = (double)pf;
        const float* vr = &KVs[key][sub * 16];
#pragma unroll
        for (int d = 0; d < 16; d++) acc[d] += pd * (double)vr[d];
      }
    }
  }
  float* op = outb + (rowbase + row_abs) * DIMM + h * DH + sub * 16;
#pragma unroll
  for (int d = 0; d < 16; d++) op[d] = (float)acc[d];
}

// ------- sequential M recurrence, f64 state; emits split3(local+read) ------
__global__ __launch_bounds__(256) void recur64_kernel(
    const int* __restrict__ ri, const double* __restrict__ rw,
    const double* __restrict__ delta, const float* __restrict__ inb,
    u16* __restrict__ sh, u16* __restrict__ sm, u16* __restrict__ sl) {
  __shared__ double Msh[NSLOTS][17];
  const int bid = blockIdx.x;
  const int ds = bid & 7, h = (bid >> 3) & 7, b = bid >> 6;
  const int tid = threadIdx.x;
  for (int i = tid; i < NSLOTS * 17; i += 256) ((double*)Msh)[i] = 0.0;
  __syncthreads();
  for (int c = 0; c < NCHUNK; c++) {
    const size_t rbase =
        ((size_t)(b * 8 + h) * SEQ + (size_t)c * CHUNK + tid) * 16;
    double a[16] = {};
#pragma unroll
    for (int j = 0; j < 16; j++) {
      const int slot = ri[rbase + j];
      const double w = rw[rbase + j];
      const double* mp = &Msh[slot][0];
#pragma unroll
      for (int d = 0; d < 16; d++) a[d] += w * mp[d];
    }
    const size_t base = ((size_t)b * SEQ + (size_t)c * CHUNK + tid) * DIMM +
                        h * DH + ds * 16;
    const float* ip = inb + base;
    u16x4 rh[4], rm[4], rl[4];
#pragma unroll
    for (int q = 0; q < 4; q++) {
      float f0 = (float)((double)ip[q * 4 + 0] + a[q * 4 + 0]);
      float f1 = (float)((double)ip[q * 4 + 1] + a[q * 4 + 1]);
      float f2 = (float)((double)ip[q * 4 + 2] + a[q * 4 + 2]);
      float f3 = (float)((double)ip[q * 4 + 3] + a[q * 4 + 3]);
      split3s(f0, rh[q].x, rm[q].x, rl[q].x);
      split3s(f1, rh[q].y, rm[q].y, rl[q].y);
      split3s(f2, rh[q].z, rm[q].z, rl[q].z);
      split3s(f3, rh[q].w, rm[q].w, rl[q].w);
    }
#pragma unroll
    for (int q = 0; q < 4; q++) {
      ((u16x4*)(sh + base))[q] = rh[q];
      ((u16x4*)(sm + base))[q] = rm[q];
      ((u16x4*)(sl + base))[q] = rl[q];
    }
    __syncthreads();
    const int slot = tid >> 1, d8 = (tid & 1) * 8;
    const double* dp = delta +
        (((size_t)(b * 8 + h) * NCHUNK + c) * NSLOTS + slot) * DH + ds * 16 + d8;
#pragma unroll
    for (int d = 0; d < 8; d++)
      Msh[slot][d8 + d] = GAMMA64 * Msh[slot][d8 + d] + dp[d];
    __syncthreads();
  }
}

// ---------------- W[K][N] f32 -> WT[N][K] bf16 -----------------------------
__global__ void transconv_kernel(const float* __restrict__ W,
                                 u16* __restrict__ WT, int K, int N) {
  __shared__ float tile[32][33];
  const int n0 = blockIdx.x * 32, k0 = blockIdx.y * 32;
  const int tx = threadIdx.x, ty = threadIdx.y;
#pragma unroll
  for (int i = 0; i < 4; i++)
    tile[ty + 8 * i][tx] = W[(size_t)(k0 + ty + 8 * i) * N + n0 + tx];
  __syncthreads();
#pragma unroll
  for (int i = 0; i < 4; i++)
    WT[(size_t)(n0 + ty + 8 * i) * K + k0 + tx] = f2bf(tile[tx][ty + 8 * i]);
}

// ---------------- bf16 MFMA GEMM for logits (GROUP_N=16 supertile) ---------
template <bool BIAS>
__global__ __launch_bounds__(256) void gemm_kernel(
    const u16* __restrict__ A, const u16* __restrict__ B, float* __restrict__ C,
    const float* __restrict__ bias, int M, int N, int K) {
  __shared__ u16 As[128 * 32];
  __shared__ u16 Bs[128 * 32];
  const int tid = threadIdx.x;
  const int lid = blockIdx.y * gridDim.x + blockIdx.x;
  const int npm = M / 128;
  const int ngrid = N / 128;
  const int GN = 16;
  const int ppg = GN * npm;
  const int gid = lid / ppg;
  const int first_n = gid * GN;
  const int gsz = min(GN, ngrid - first_n);
  const int local = lid - gid * ppg;
  const int bn = first_n + local % gsz;
  const int bm = local / gsz;
  const int wid = tid >> 6, lane = tid & 63;
  const int wr = (wid >> 1) * 64, wc = (wid & 1) * 64;
  f32x4 acc[4][4] = {};
  const int row0 = tid >> 2;
  const int colb = (tid & 3) << 4;
  const char* A0 = (const char*)A + ((size_t)(bm * 128 + row0) * K) * 2 + colb;
  const char* A1 = (const char*)A + ((size_t)(bm * 128 + row0 + 64) * K) * 2 + colb;
  const char* B0 = (const char*)B + ((size_t)(bn * 128 + row0) * K) * 2 + colb;
  const char* B1 = (const char*)B + ((size_t)(bn * 128 + row0 + 64) * K) * 2 + colb;
  char* lA0 = (char*)As + (tid & 192) * 16;
  char* lB0 = (char*)Bs + (tid & 192) * 16;
  const char* pa = (const char*)As + wr * 64 + (lane & 15) * 64 + (lane >> 4) * 16;
  const char* pb = (const char*)Bs + wc * 64 + (lane & 15) * 64 + (lane >> 4) * 16;
  for (int k0 = 0; k0 < K; k0 += 32) {
    const size_t kb = (size_t)k0 * 2;
    gld16(lA0, A0 + kb);
    gld16(lA0 + 4096, A1 + kb);
    gld16(lB0, B0 + kb);
    gld16(lB0 + 4096, B1 + kb);
    __syncthreads();
    s16x8 af[4], bf[4];
#pragma unroll
    for (int m = 0; m < 4; m++) af[m] = *(const s16x8*)(pa + m * 1024);
#pragma unroll
    for (int n = 0; n < 4; n++) bf[n] = *(const s16x8*)(pb + n * 1024);
#pragma unroll
    for (int m = 0; m < 4; m++)
#pragma unroll
      for (int n = 0; n < 4; n++) acc[m][n] = mfma16(af[m], bf[n], acc[m][n]);
    __syncthreads();
  }
#pragma unroll
  for (int m = 0; m < 4; m++)
#pragma unroll
    for (int n = 0; n < 4; n++)
#pragma unroll
      for (int j = 0; j < 4; j++) {
        const int r = bm * 128 + wr + m * 16 + (lane >> 4) * 4 + j;
        const int c = bn * 128 + wc + n * 16 + (lane & 15);
        float v = acc[m][n][j];
        if (BIAS) v += bias[c];
        C[(size_t)r * N + c] = v;
      }
}

extern "C" void kernel_launch(void* const* d_in, const int* in_sizes, int n_in,
                              void* d_out, int out_size, void* d_ws,
                              size_t ws_size, hipStream_t stream) {
  (void)in_sizes; (void)n_in; (void)out_size; (void)ws_size;
  const int* tokens = (const int*)d_in[0];
  const float* embed = (const float*)d_in[1];
  const float* Wq = (const float*)d_in[2];
  const float* Wk = (const float*)d_in[3];
  const float* Wv = (const float*)d_in[4];
  const float* Wo = (const float*)d_in[5];
  const float* slot_keys = (const float*)d_in[6];
  const float* ln_g = (const float*)d_in[7];
  const float* ln_b = (const float*)d_in[8];
  const float* fg = (const float*)d_in[9];
  const float* fb = (const float*)d_in[10];
  const float* Wout = (const float*)d_in[11];
  const float* bout = (const float*)d_in[12];
  float* out = (float*)d_out;

  char* p = (char*)d_ws;
  auto alloc = [&](size_t bytes) -> char* {
    char* r = p;
    p += (bytes + 255) & ~(size_t)255;
    return r;
  };
  const size_t RD = (size_t)NROWS * DIMM;
  double* hidden64 = (double*)alloc(RD * 8);   // f64 trajectory anchor
  double* xn64 = (double*)alloc(RD * 8);       // f64 (fixup input)
  float* q32 = (float*)alloc(RD * 4);          // aliased as xnb at end
  float* k32 = (float*)alloc(RD * 4);
  float* v32 = (float*)alloc(RD * 4);
  float* local32 = (float*)alloc(RD * 4);
  double* delta64 =
      (double*)alloc((size_t)NB * NHEADS * NCHUNK * NSLOTS * DH * 8);
  int* ri = (int*)alloc((size_t)65536 * 16 * 4);
  int* wi = (int*)alloc((size_t)65536 * 16 * 4);
  double* rw64 = (double*)alloc((size_t)65536 * 16 * 8);
  double* ww64 = (double*)alloc((size_t)65536 * 16 * 8);
  u16* sAh = (u16*)alloc(RD * 2);
  u16* sAm = (u16*)alloc(RD * 2);
  u16* sAl = (u16*)alloc(RD * 2);
  u16* WTh = (u16*)alloc((size_t)8 * DIMM * DIMM * 2);  // l*4+{q,k,v,o}
  u16* WTm = (u16*)alloc((size_t)8 * DIMM * DIMM * 2);
  u16* WTl = (u16*)alloc((size_t)8 * DIMM * DIMM * 2);
  double* W2q = (double*)alloc((size_t)2 * DIMM * DIMM * 8);
  double* W2k = (double*)alloc((size_t)2 * DIMM * DIMM * 8);
  u16* WoutT = (u16*)alloc((size_t)NVOCAB * DIMM * 2);
  int* fcnts = (int*)alloc(256);
  int* flq = (int*)alloc((size_t)MAXFLAG * 4);
  int* flk = (int*)alloc((size_t)MAXFLAG * 4);

  u16* xnb = (u16*)q32;  // used only after layer-2 attn

  const float* Wmats[4] = {Wq, Wk, Wv, Wo};
  for (int l = 0; l < 2; l++) {
    for (int w = 0; w < 4; w++) {
      const size_t o = ((size_t)l * 4 + w) * DIMM * DIMM;
      transconv3_kernel<<<dim3(DIMM / 32, DIMM / 32), dim3(32, 8), 0, stream>>>(
          Wmats[w] + (size_t)l * DIMM * DIMM, WTh + o, WTm + o, WTl + o, DIMM,
          DIMM);
    }
    const float* skl = slot_keys + (size_t)l * NHEADS * NSLOTS * DH;
    w2_kernel<<<1024, 256, 0, stream>>>(Wq + (size_t)l * DIMM * DIMM, skl,
                                        W2q + (size_t)l * DIMM * DIMM);
    w2_kernel<<<1024, 256, 0, stream>>>(Wk + (size_t)l * DIMM * DIMM, skl,
                                        W2k + (size_t)l * DIMM * DIMM);
  }

  embed64_kernel<<<NROWS, 256, 0, stream>>>(tokens, embed, hidden64);

  const dim3 g3(DIMM / 128, NROWS / 128);
  for (int l = 0; l < 2; l++) {
    const size_t oq = ((size_t)l * 4 + 0) * DIMM * DIMM;
    const size_t ok = ((size_t)l * 4 + 1) * DIMM * DIMM;
    const size_t ov = ((size_t)l * 4 + 2) * DIMM * DIMM;
    const size_t oo = ((size_t)l * 4 + 3) * DIMM * DIMM;
    ln64_kernel<0><<<NROWS, 256, 0, stream>>>(hidden64, ln_g + l * DIMM,
                                              ln_b + l * DIMM, xn64, sAh, sAm,
                                              sAl);
    gemm3d_kernel<false, float><<<g3, 256, 0, stream>>>(
        sAh, sAm, sAl, WTh + oq, WTm + oq, WTl + oq, q32, nullptr, NROWS, DIMM,
        DIMM);
    gemm3d_kernel<false, float><<<g3, 256, 0, stream>>>(
        sAh, sAm, sAl, WTh + ok, WTm + ok, WTl + ok, k32, nullptr, NROWS, DIMM,
        DIMM);
    gemm3d_kernel<false, float><<<g3, 256, 0, stream>>>(
        sAh, sAm, sAl, WTh + ov, WTm + ov, WTl + ov, v32, nullptr, NROWS, DIMM,
        DIMM);
    const float* skl = slot_keys + (size_t)l * NHEADS * NSLOTS * DH;
    hipMemsetAsync(fcnts, 0, 8, stream);
    topk_flag_kernel<<<dim3(16384, 2), 256, 0, stream>>>(
        q32, k32, skl, ri, wi, rw64, ww64, fcnts, flq, flk);
    fixup_kernel<<<dim3(512, 2), 256, 0, stream>>>(
        fcnts, flq, flk, xn64, W2q + (size_t)l * DIMM * DIMM,
        W2k + (size_t)l * DIMM * DIMM, ri, wi, rw64, ww64);
    delta64_kernel<<<NB * NHEADS * NCHUNK, 512, 0, stream>>>(wi, ww64, v32,
                                                             delta64);
    attn_fused<<<NB * NCHUNK * NHEADS * 8, 256, 0, stream>>>(q32, k32, v32,
                                                             local32);
    recur64_kernel<<<NB * NHEADS * 8, 256, 0, stream>>>(ri, rw64, delta64,
                                                        local32, sAh, sAm,
                                                        sAl);
    gemm3d_kernel<true, double><<<g3, 256, 0, stream>>>(
        sAh, sAm, sAl, WTh + oo, WTm + oo, WTl + oo, hidden64, hidden64, NROWS,
        DIMM, DIMM);
  }
  transconv_kernel<<<dim3(NVOCAB / 32, DIMM / 32), dim3(32, 8), 0, stream>>>(
      Wout, WoutT, DIMM, NVOCAB);
  ln64_kernel<1><<<NROWS, 256, 0, stream>>>(hidden64, fg, fb, nullptr, xnb,
                                            nullptr, nullptr);
  gemm_kernel<true><<<dim3(NVOCAB / 128, NROWS / 128), 256, 0, stream>>>(
      xnb, WoutT, out, bout, NROWS, NVOCAB, DIMM);
}

// Round 11
// 5222.435 us; speedup vs baseline: 2.0198x; 1.2090x over previous
//
#include <hip/hip_runtime.h>

#define DIMM 1024
#define NHEADS 8
#define DH 128
#define NSLOTS 128
#define CHUNK 256
#define NCHUNK 16
#define NB 2
#define SEQ 4096
#define NROWS (NB * SEQ)
#define NVOCAB 32000
#define GAMMA64 0.9
#define SCALE64 0.08838834764831845
#define TAU 1e-6f
#define MAXFLAG 65536

typedef unsigned short u16;
typedef __attribute__((ext_vector_type(4))) float f32x4;
typedef __attribute__((ext_vector_type(8))) short s16x8;

struct alignas(8) u16x4 { u16 x, y, z, w; };

__device__ __forceinline__ u16 f2bf(float f) {
  union { float f; unsigned u; } v; v.f = f;
  return (u16)((v.u + 0x7FFFu + ((v.u >> 16) & 1u)) >> 16);
}
__device__ __forceinline__ float bf2f(u16 u) {
  union { unsigned u; float f; } v; v.u = ((unsigned)u) << 16; return v.f;
}
// exact 3-way bf16 split of an f32 (h+m+l == x exactly)
__device__ __forceinline__ void split3s(float x, u16& h, u16& m, u16& l) {
  h = f2bf(x); float r = x - bf2f(h);
  m = f2bf(r); float r2 = r - bf2f(m);
  l = f2bf(r2);
}

__device__ __forceinline__ void gld16(void* lds, const void* g) {
  __builtin_amdgcn_global_load_lds(
      (const __attribute__((address_space(1))) unsigned*)g,
      (__attribute__((address_space(3))) unsigned*)lds, 16, 0, 0);
}
__device__ __forceinline__ f32x4 mfma16(s16x8 a, s16x8 b, f32x4 c) {
  return __builtin_amdgcn_mfma_f32_16x16x32_bf16(a, b, c, 0, 0, 0);
}

// ---------------- embedding gather -> f64 ----------------
__global__ __launch_bounds__(256) void embed64_kernel(
    const int* __restrict__ tok, const float* __restrict__ emb,
    double* __restrict__ hid) {
  const int row = blockIdx.x;
  const int t = tok[row];
  const float4 v = ((const float4*)(emb + (size_t)t * DIMM))[threadIdx.x];
  double* o = hid + (size_t)row * DIMM + threadIdx.x * 4;
  o[0] = (double)v.x; o[1] = (double)v.y; o[2] = (double)v.z; o[3] = (double)v.w;
}

// ------- f64 two-pass layernorm; MODE0: f64 xn + split3; MODE1: bf16 -------
template <int MODE>
__global__ __launch_bounds__(256) void ln64_kernel(
    const double* __restrict__ x, const float* __restrict__ g,
    const float* __restrict__ bb, double* __restrict__ o64,
    u16* __restrict__ oh, u16* __restrict__ om, u16* __restrict__ ol) {
  const int row = blockIdx.x, tid = threadIdx.x;
  const double* xr = x + (size_t)row * DIMM + tid * 4;
  const double v0 = xr[0], v1 = xr[1], v2 = xr[2], v3 = xr[3];
  __shared__ double red[4];
  double s1 = v0 + v1 + v2 + v3;
#pragma unroll
  for (int off = 32; off >= 1; off >>= 1) s1 += __shfl_xor(s1, off);
  if ((tid & 63) == 0) red[tid >> 6] = s1;
  __syncthreads();
  const double mu = (red[0] + red[1] + red[2] + red[3]) * (1.0 / DIMM);
  __syncthreads();
  const double d0 = v0 - mu, d1 = v1 - mu, d2 = v2 - mu, d3 = v3 - mu;
  double s2 = d0 * d0 + d1 * d1 + d2 * d2 + d3 * d3;
#pragma unroll
  for (int off = 32; off >= 1; off >>= 1) s2 += __shfl_xor(s2, off);
  if ((tid & 63) == 0) red[tid >> 6] = s2;
  __syncthreads();
  const double var = (red[0] + red[1] + red[2] + red[3]) * (1.0 / DIMM);
  const double rs = 1.0 / sqrt(var + 1e-5);
  const float4 g4 = ((const float4*)g)[tid];
  const float4 b4 = ((const float4*)bb)[tid];
  const double y0 = d0 * rs * (double)g4.x + (double)b4.x;
  const double y1 = d1 * rs * (double)g4.y + (double)b4.y;
  const double y2 = d2 * rs * (double)g4.z + (double)b4.z;
  const double y3 = d3 * rs * (double)g4.w + (double)b4.w;
  if (MODE == 0) {
    double* o = o64 + (size_t)row * DIMM + tid * 4;
    o[0] = y0; o[1] = y1; o[2] = y2; o[3] = y3;
    u16x4 rh, rm, rl;
    split3s((float)y0, rh.x, rm.x, rl.x);
    split3s((float)y1, rh.y, rm.y, rl.y);
    split3s((float)y2, rh.z, rm.z, rl.z);
    split3s((float)y3, rh.w, rm.w, rl.w);
    ((u16x4*)(oh + (size_t)row * DIMM))[tid] = rh;
    ((u16x4*)(om + (size_t)row * DIMM))[tid] = rm;
    ((u16x4*)(ol + (size_t)row * DIMM))[tid] = rl;
  } else {
    u16x4 r;
    r.x = f2bf((float)y0); r.y = f2bf((float)y1);
    r.z = f2bf((float)y2); r.w = f2bf((float)y3);
    ((u16x4*)(oh + (size_t)row * DIMM))[tid] = r;
  }
}

// ---------------- W[K][N] f32 -> WT[N][K] split3 bf16 ----------------
__global__ void transconv3_kernel(const float* __restrict__ W,
                                  u16* __restrict__ WTh, u16* __restrict__ WTm,
                                  u16* __restrict__ WTl, int K, int N) {
  __shared__ float tile[32][33];
  const int n0 = blockIdx.x * 32, k0 = blockIdx.y * 32;
  const int tx = threadIdx.x, ty = threadIdx.y;
#pragma unroll
  for (int i = 0; i < 4; i++)
    tile[ty + 8 * i][tx] = W[(size_t)(k0 + ty + 8 * i) * N + n0 + tx];
  __syncthreads();
#pragma unroll
  for (int i = 0; i < 4; i++) {
    u16 h, m, l;
    split3s(tile[tx][ty + 8 * i], h, m, l);
    const size_t o = (size_t)(n0 + ty + 8 * i) * K + k0 + tx;
    WTh[o] = h; WTm[o] = m; WTl[o] = l;
  }
}

// ---------------- f32 -> split3 bf16 elementwise ----------------
__global__ __launch_bounds__(256) void cvt3_32_kernel(
    const float* __restrict__ in, u16* __restrict__ oh, u16* __restrict__ om,
    u16* __restrict__ ol) {
  const size_t i = (size_t)blockIdx.x * 256 + threadIdx.x;
  const float4 v = ((const float4*)in)[i];
  u16x4 rh, rm, rl;
  split3s(v.x, rh.x, rm.x, rl.x); split3s(v.y, rh.y, rm.y, rl.y);
  split3s(v.z, rh.z, rm.z, rl.z); split3s(v.w, rh.w, rm.w, rl.w);
  ((u16x4*)oh)[i] = rh; ((u16x4*)om)[i] = rm; ((u16x4*)ol)[i] = rl;
}

// ---------------- combined slot-score weights: W2 (f64 exact) --------------
__global__ __launch_bounds__(256) void w2_kernel(const float* __restrict__ W,
                                                 const float* __restrict__ sk,
                                                 double* __restrict__ W2) {
  __shared__ float sksh[128];
  const int r = blockIdx.x, h = r >> 7;
  const int tid = threadIdx.x;
  if (tid < 128) sksh[tid] = sk[(size_t)r * DH + tid];
  __syncthreads();
  for (int d = tid; d < DIMM; d += 256) {
    const float* wrow = W + (size_t)d * DIMM + h * DH;
    double acc = 0.0;
#pragma unroll 8
    for (int j = 0; j < 128; j++) acc += (double)wrow[j] * (double)sksh[j];
    W2[(size_t)r * DIMM + d] = acc;
  }
}

// ------- split3 f32-faithful GEMM -> TC out: C = A @ BT^T (+res) ----------
template <bool RES, typename TC>
__global__ __launch_bounds__(256) void gemm3d_kernel(
    const u16* __restrict__ Ah, const u16* __restrict__ Am,
    const u16* __restrict__ Al, const u16* __restrict__ Bh,
    const u16* __restrict__ Bm, const u16* __restrict__ Bl,
    TC* __restrict__ C, const TC* __restrict__ Cres, int M, int N, int K) {
  __shared__ u16 lds[6 * 128 * 32];
  const int tid = threadIdx.x;
  const int bn = blockIdx.x, bm = blockIdx.y;
  const int wid = tid >> 6, lane = tid & 63;
  const int wr = (wid >> 1) * 64, wc = (wid & 1) * 64;
  f32x4 acc[4][4] = {};
  const int row0 = tid >> 2;
  const int colb = (tid & 3) << 4;
  const u16* Gs[6] = {Ah, Am, Al, Bh, Bm, Bl};
  const char* g0[6];
  const char* g1[6];
  char* lb[6];
#pragma unroll
  for (int i = 0; i < 6; i++) {
    const int rbase = (i < 3 ? bm : bn) * 128;
    g0[i] = (const char*)Gs[i] + ((size_t)(rbase + row0) * K) * 2 + colb;
    g1[i] = (const char*)Gs[i] + ((size_t)(rbase + row0 + 64) * K) * 2 + colb;
    lb[i] = (char*)lds + i * 8192 + (tid & 192) * 16;
  }
  const int fo = (lane & 15) * 64 + (lane >> 4) * 16;
  const char* paH = (const char*)lds + 0 + wr * 64 + fo;
  const char* paM = paH + 8192;
  const char* paL = paH + 16384;
  const char* pbH = (const char*)lds + 24576 + wc * 64 + fo;
  const char* pbM = pbH + 8192;
  const char* pbL = pbH + 16384;

  for (int k0 = 0; k0 < K; k0 += 32) {
    const size_t kb = (size_t)k0 * 2;
#pragma unroll
    for (int i = 0; i < 6; i++) {
      gld16(lb[i], g0[i] + kb);
      gld16(lb[i] + 4096, g1[i] + kb);
    }
    __syncthreads();
    s16x8 bh[4], bm_[4], bl[4];
#pragma unroll
    for (int n = 0; n < 4; n++) {
      bh[n] = *(const s16x8*)(pbH + n * 1024);
      bm_[n] = *(const s16x8*)(pbM + n * 1024);
      bl[n] = *(const s16x8*)(pbL + n * 1024);
    }
#pragma unroll
    for (int m = 0; m < 4; m++) {
      const s16x8 ah = *(const s16x8*)(paH + m * 1024);
      const s16x8 am = *(const s16x8*)(paM + m * 1024);
      const s16x8 al = *(const s16x8*)(paL + m * 1024);
#pragma unroll
      for (int n = 0; n < 4; n++) {
        f32x4 t = acc[m][n];
        t = mfma16(al, bh[n], t);
        t = mfma16(ah, bl[n], t);
        t = mfma16(am, bm_[n], t);
        t = mfma16(am, bh[n], t);
        t = mfma16(ah, bm_[n], t);
        t = mfma16(ah, bh[n], t);
        acc[m][n] = t;
      }
    }
    __syncthreads();
  }
#pragma unroll
  for (int m = 0; m < 4; m++)
#pragma unroll
    for (int n = 0; n < 4; n++)
#pragma unroll
      for (int j = 0; j < 4; j++) {
        const int r = bm * 128 + wr + m * 16 + (lane >> 4) * 4 + j;
        const int c = bn * 128 + wc + n * 16 + (lane & 15);
        TC v = (TC)acc[m][n][j];
        if (RES) v += Cres[(size_t)r * N + c];
        C[(size_t)r * N + c] = v;
      }
}

// ------- slot scores via split3 MFMA: S[which][rid][slot] (f32) ------------
// block = (ttile, y={which,b,h}); C tile 128 t-rows x 128 slots, K=DH=128.
__global__ __launch_bounds__(256) void score3_kernel(
    const u16* __restrict__ Qh, const u16* __restrict__ Qm,
    const u16* __restrict__ Ql, const u16* __restrict__ Kh3,
    const u16* __restrict__ Km3, const u16* __restrict__ Kl3,
    const u16* __restrict__ skh, const u16* __restrict__ skm,
    const u16* __restrict__ skl, float* __restrict__ S) {
  __shared__ u16 lds[6 * 128 * 32];
  const int tid = threadIdx.x;
  const int bm = blockIdx.x;
  const int y = blockIdx.y;
  const int which = y >> 4, b = (y >> 3) & 1, h = y & 7;
  const u16* Ah = which ? Kh3 : Qh;
  const u16* Am = which ? Km3 : Qm;
  const u16* Al = which ? Kl3 : Ql;
  const int wid = tid >> 6, lane = tid & 63;
  const int wr = (wid >> 1) * 64, wc = (wid & 1) * 64;
  f32x4 acc[4][4] = {};
  const int row0 = tid >> 2;
  const int colb = (tid & 3) << 4;
  const size_t arow = (size_t)(b * SEQ + bm * 128);
  const u16* Gs[6] = {Ah, Am, Al, skh, skm, skl};
  const char* g0[6];
  const char* g1[6];
  char* lb[6];
#pragma unroll
  for (int i = 0; i < 6; i++) {
    if (i < 3) {
      g0[i] = (const char*)Gs[i] + (arow + row0) * 2048 + h * 256 + colb;
      g1[i] = (const char*)Gs[i] + (arow + row0 + 64) * 2048 + h * 256 + colb;
    } else {
      g0[i] = (const char*)Gs[i] + ((size_t)h * 128 + row0) * 256 + colb;
      g1[i] = (const char*)Gs[i] + ((size_t)h * 128 + row0 + 64) * 256 + colb;
    }
    lb[i] = (char*)lds + i * 8192 + (tid & 192) * 16;
  }
  const int fo = (lane & 15) * 64 + (lane >> 4) * 16;
  const char* paH = (const char*)lds + 0 + wr * 64 + fo;
  const char* paM = paH + 8192;
  const char* paL = paH + 16384;
  const char* pbH = (const char*)lds + 24576 + wc * 64 + fo;
  const char* pbM = pbH + 8192;
  const char* pbL = pbH + 16384;

  for (int k0 = 0; k0 < DH; k0 += 32) {
    const size_t kb = (size_t)k0 * 2;
#pragma unroll
    for (int i = 0; i < 6; i++) {
      gld16(lb[i], g0[i] + kb);
      gld16(lb[i] + 4096, g1[i] + kb);
    }
    __syncthreads();
    s16x8 bh[4], bm_[4], bl[4];
#pragma unroll
    for (int n = 0; n < 4; n++) {
      bh[n] = *(const s16x8*)(pbH + n * 1024);
      bm_[n] = *(const s16x8*)(pbM + n * 1024);
      bl[n] = *(const s16x8*)(pbL + n * 1024);
    }
#pragma unroll
    for (int m = 0; m < 4; m++) {
      const s16x8 ah = *(const s16x8*)(paH + m * 1024);
      const s16x8 am = *(const s16x8*)(paM + m * 1024);
      const s16x8 al = *(const s16x8*)(paL + m * 1024);
#pragma unroll
      for (int n = 0; n < 4; n++) {
        f32x4 t = acc[m][n];
        t = mfma16(al, bh[n], t);
        t = mfma16(ah, bl[n], t);
        t = mfma16(am, bm_[n], t);
        t = mfma16(am, bh[n], t);
        t = mfma16(ah, bm_[n], t);
        t = mfma16(ah, bh[n], t);
        acc[m][n] = t;
      }
    }
    __syncthreads();
  }
  const size_t sbase =
      (size_t)which * 65536 + (size_t)(b * 8 + h) * 4096 + (size_t)bm * 128;
#pragma unroll
  for (int m = 0; m < 4; m++)
#pragma unroll
    for (int n = 0; n < 4; n++)
#pragma unroll
      for (int j = 0; j < 4; j++) {
        const int r = wr + m * 16 + (lane >> 4) * 4 + j;
        const int c = wc + n * 16 + (lane & 15);
        S[(sbase + r) * NSLOTS + c] = acc[m][n][j];
      }
}

// -------- top-16 selection on precomputed f32 scores + flagging ------------
__global__ __launch_bounds__(256) void select_kernel(
    const float* __restrict__ S, int* __restrict__ riQ, int* __restrict__ riK,
    double* __restrict__ rwQ, double* __restrict__ rwK,
    int* __restrict__ fcnts, int* __restrict__ flq, int* __restrict__ flk) {
  const int which = blockIdx.y;
  int* oidx = which ? riK : riQ;
  double* ow = which ? rwK : rwQ;
  int* fcnt = fcnts + which;
  int* flist = which ? flk : flq;
  const int wid = threadIdx.x >> 6, lane = threadIdx.x & 63;
  const int rid = blockIdx.x * 4 + wid;
  const float2 sv =
      *(const float2*)(S + ((size_t)which * 65536 + rid) * NSLOTS + lane * 2);
  const float sc = (float)SCALE64;
  float v0 = sv.x * sc, v1 = sv.y * sc;
  const int i0 = lane * 2, i1 = lane * 2 + 1;
  float selv = -1e30f; int seli = 0;
  for (int it = 0; it < 17; it++) {
    float m; int mi;
    if (v1 > v0) { m = v1; mi = i1; } else { m = v0; mi = i0; }
#pragma unroll
    for (int off = 1; off < 64; off <<= 1) {
      const float om = __shfl_xor(m, off);
      const int oi = __shfl_xor(mi, off);
      if (om > m || (om == m && oi < mi)) { m = om; mi = oi; }
    }
    if (lane == it) { selv = m; seli = mi; }
    if (mi == i0) v0 = -1e30f;
    if (mi == i1) v1 = -1e30f;
  }
  const float mx = __shfl(selv, 0);
  const float v15 = __shfl(selv, 15);
  const float v16 = __shfl(selv, 16);
  if (lane == 0 && (v15 - v16) < TAU) {
    const int p = atomicAdd(fcnt, 1);
    if (p < MAXFLAG) flist[p] = rid;
  }
  const float e = (lane < 16) ? expf(selv - mx) : 0.0f;
  double ss = (double)e;
  ss += __shfl_xor(ss, 1); ss += __shfl_xor(ss, 2);
  ss += __shfl_xor(ss, 4); ss += __shfl_xor(ss, 8);
  if (lane < 16) {
    ow[(size_t)rid * 16 + lane] = (double)e / ss;
    oidx[(size_t)rid * 16 + lane] = seli;
  }
}

// ---------------- merged f64-exact fixup for flagged rows ------------------
__global__ __launch_bounds__(256) void fixup_kernel(
    const int* __restrict__ fcnts, const int* __restrict__ flq,
    const int* __restrict__ flk, const double* __restrict__ xn,
    const double* __restrict__ W2q, const double* __restrict__ W2k,
    int* __restrict__ riQ, int* __restrict__ riK, double* __restrict__ rwQ,
    double* __restrict__ rwK) {
  __shared__ double xsh[1024];
  __shared__ double psh[256];
  __shared__ double ssh[128];
  const int which = blockIdx.y;
  const int* flist = which ? flk : flq;
  const double* W2 = which ? W2k : W2q;
  int* oidx = which ? riK : riQ;
  double* ow = which ? rwK : rwQ;
  const int tid = threadIdx.x;
  const int n = min(fcnts[which], MAXFLAG);
  for (int i = blockIdx.x; i < n; i += gridDim.x) {
    __syncthreads();
    const int rid = flist[i];
    const int t = rid & 4095, h = (rid >> 12) & 7, b = rid >> 15;
    const double* xr = xn + ((size_t)b * SEQ + t) * DIMM;
    for (int j = tid; j < DIMM; j += 256) xsh[j] = xr[j];
    __syncthreads();
    const int slot = tid >> 1, half = tid & 1;
    const double* w2r = W2 + (size_t)(h * NSLOTS + slot) * DIMM + half * 512;
    const double* xp = xsh + half * 512;
    double acc = 0.0;
#pragma unroll 8
    for (int d = 0; d < 512; d++) acc += xp[d] * w2r[d];
    psh[tid] = acc;
    __syncthreads();
    if (tid < 128) ssh[tid] = (psh[2 * tid] + psh[2 * tid + 1]) * SCALE64;
    __syncthreads();
    if (tid < 64) {
      const int lane = tid;
      double selv = -1e300; int seli = 0;
      double v0 = ssh[lane], v1 = ssh[lane + 64];
      for (int it = 0; it < 16; it++) {
        double m; int mi;
        if (v1 > v0) { m = v1; mi = lane + 64; } else { m = v0; mi = lane; }
#pragma unroll
        for (int off = 1; off < 64; off <<= 1) {
          const double om = __shfl_xor(m, off);
          const int oi = __shfl_xor(mi, off);
          if (om > m || (om == m && oi < mi)) { m = om; mi = oi; }
        }
        if (lane == it) { selv = m; seli = mi; }
        if (mi == lane) v0 = -1e300;
        if (mi == lane + 64) v1 = -1e300;
      }
      const double mx = __shfl(selv, 0);
      const float e = (lane < 16) ? expf((float)(selv - mx)) : 0.0f;
      double ss = (double)e;
      ss += __shfl_xor(ss, 1); ss += __shfl_xor(ss, 2);
      ss += __shfl_xor(ss, 4); ss += __shfl_xor(ss, 8);
      if (lane < 16) {
        ow[(size_t)rid * 16 + lane] = (double)e / ss;
        oidx[(size_t)rid * 16 + lane] = seli;
      }
    }
  }
}

// ------- dense per-chunk write delta (V f32, f64 accum, stable order) ------
__global__ __launch_bounds__(512) void delta64_kernel(
    const int* __restrict__ wi, const double* __restrict__ ww,
    const float* __restrict__ V, double* __restrict__ delta) {
  __shared__ short slot_sh[4096];
  __shared__ double w_sh[4096];
  __shared__ u16 list[4096];
  __shared__ int cnt[NSLOTS], off_[NSLOTS];
  const int bid = blockIdx.x;
  const int c = bid & 15, h = (bid >> 4) & 7, b = bid >> 7;
  const int tid = threadIdx.x;
  if (tid < NSLOTS) cnt[tid] = 0;
  __syncthreads();
  const size_t ebase = ((size_t)(b * 8 + h) * SEQ + (size_t)c * CHUNK) * 16;
#pragma unroll
  for (int i = 0; i < 8; i++) {
    const int e = tid + i * 512;
    const int s = wi[ebase + e];
    slot_sh[e] = (short)s;
    w_sh[e] = ww[ebase + e];
    atomicAdd(&cnt[s], 1);
  }
  __syncthreads();
  if (tid == 0) {
    int a = 0;
    for (int s = 0; s < NSLOTS; s++) { off_[s] = a; a += cnt[s]; }
  }
  __syncthreads();
  if (tid < NSLOTS) {
    int p = off_[tid];
    const short me = (short)tid;
    for (int e = 0; e < 4096; e++)
      if (slot_sh[e] == me) list[p++] = (u16)e;
  }
  __syncthreads();
  const int slot = tid >> 2, dbase = (tid & 3) * 32;
  double acc[32] = {};
  const int start = off_[slot], len = cnt[slot];
  const float* vbase =
      V + ((size_t)b * SEQ + (size_t)c * CHUNK) * DIMM + h * DH + dbase;
  for (int i = 0; i < len; i++) {
    const int e = list[start + i];
    const double w = w_sh[e];
    const float* vp = vbase + (size_t)(e >> 4) * DIMM;
#pragma unroll
    for (int d = 0; d < 32; d++) acc[d] += w * (double)vp[d];
  }
  double* dst = delta + ((size_t)bid * NSLOTS + slot) * DH + dbase;
#pragma unroll
  for (int d = 0; d < 32; d++) dst[d] = acc[d];
}

// --- fused local attention: f32 storage, f64 dots/accum, no S buffer -------
__global__ __launch_bounds__(256) void attn_fused(
    const float* __restrict__ Q, const float* __restrict__ Kb,
    const float* __restrict__ V, float* __restrict__ outb) {
  __shared__ float Qs[32][130];
  __shared__ float KVs[16][130];
  const int idx = blockIdx.x;
  const int rq = idx & 7, h = (idx >> 3) & 7, c = (idx >> 6) & 15, b = idx >> 10;
  const int tid = threadIdx.x;
  const size_t rowbase = (size_t)b * SEQ + (size_t)c * CHUNK;
  {
    const int r = tid >> 3, d0 = (tid & 7) * 16;
    const float* qp = Q + (rowbase + rq * 32 + r) * DIMM + h * DH + d0;
#pragma unroll
    for (int j = 0; j < 16; j++) Qs[r][d0 + j] = qp[j];
  }
  const int row = tid >> 3;
  const int sub = tid & 7;
  const int row_abs = rq * 32 + row;
  const int ntile = 2 * rq + 2;
  float pexp[16][2];
#pragma unroll
  for (int kt = 0; kt < 16; kt++) { pexp[kt][0] = -1e30f; pexp[kt][1] = -1e30f; }

#pragma unroll
  for (int kt = 0; kt < 16; kt++) {
    if (kt < ntile) {
      __syncthreads();
      {
        const int r = tid >> 4, d0 = (tid & 15) * 8;
        const float* kp = Kb + (rowbase + kt * 16 + r) * DIMM + h * DH + d0;
#pragma unroll
        for (int j = 0; j < 8; j++) KVs[r][d0 + j] = kp[j];
      }
      __syncthreads();
#pragma unroll
      for (int kk = 0; kk < 2; kk++) {
        const int key = sub * 2 + kk;
        double s = 0.0;
#pragma unroll 8
        for (int d = 0; d < DH; d++)
          s += (double)Qs[row][d] * (double)KVs[key][d];
        const int kabs = kt * 16 + key;
        pexp[kt][kk] = (kabs <= row_abs) ? (float)(s * SCALE64) : -1e30f;
      }
    }
  }
  float m = -1e30f;
#pragma unroll
  for (int kt = 0; kt < 16; kt++) {
    m = fmaxf(m, pexp[kt][0]); m = fmaxf(m, pexp[kt][1]);
  }
  m = fmaxf(m, __shfl_xor(m, 1));
  m = fmaxf(m, __shfl_xor(m, 2));
  m = fmaxf(m, __shfl_xor(m, 4));
  double ss = 0.0;
#pragma unroll
  for (int kt = 0; kt < 16; kt++) {
#pragma unroll
    for (int j = 0; j < 2; j++) {
      const float e = __expf(pexp[kt][j] - m);
      pexp[kt][j] = e;
      ss += (double)e;
    }
  }
  ss += __shfl_xor(ss, 1); ss += __shfl_xor(ss, 2); ss += __shfl_xor(ss, 4);
  const double inv = 1.0 / ss;
#pragma unroll
  for (int kt = 0; kt < 16; kt++) {
    pexp[kt][0] = (float)((double)pexp[kt][0] * inv);
    pexp[kt][1] = (float)((double)pexp[kt][1] * inv);
  }
  double acc[16] = {};
#pragma unroll
  for (int kt = 0; kt < 16; kt++) {
    if (kt < ntile) {
      __syncthreads();
      {
        const int r = tid >> 4, d0 = (tid & 15) * 8;
        const float* vp = V + (rowbase + kt * 16 + r) * DIMM + h * DH + d0;
#pragma unroll
        for (int j = 0; j < 8; j++) KVs[r][d0 + j] = vp[j];
      }
      __syncthreads();
#pragma unroll
      for (int key = 0; key < 16; key++) {
        const int src = (tid & 56) | (key >> 1);
        const float pf = __shfl(pexp[kt][key & 1], src, 64);
        const double pd = (double)pf;
        const float* vr = &KVs[key][sub * 16];
#pragma unroll
        for (int d = 0; d < 16; d++) acc[d] += pd * (double)vr[d];
      }
    }
  }
  float* op = outb + (rowbase + row_abs) * DIMM + h * DH + sub * 16;
#pragma unroll
  for (int d = 0; d < 16; d++) op[d] = (float)acc[d];
}

// ------- sequential M recurrence, f64 state; emits split3(local+read) ------
__global__ __launch_bounds__(256) void recur64_kernel(
    const int* __restrict__ ri, const double* __restrict__ rw,
    const double* __restrict__ delta, const float* __restrict__ inb,
    u16* __restrict__ sh, u16* __restrict__ sm, u16* __restrict__ sl) {
  __shared__ double Msh[NSLOTS][17];
  const int bid = blockIdx.x;
  const int ds = bid & 7, h = (bid >> 3) & 7, b = bid >> 6;
  const int tid = threadIdx.x;
  for (int i = tid; i < NSLOTS * 17; i += 256) ((double*)Msh)[i] = 0.0;
  __syncthreads();
  for (int c = 0; c < NCHUNK; c++) {
    const size_t rbase =
        ((size_t)(b * 8 + h) * SEQ + (size_t)c * CHUNK + tid) * 16;
    double a[16] = {};
#pragma unroll
    for (int j = 0; j < 16; j++) {
      const int slot = ri[rbase + j];
      const double w = rw[rbase + j];
      const double* mp = &Msh[slot][0];
#pragma unroll
      for (int d = 0; d < 16; d++) a[d] += w * mp[d];
    }
    const size_t base = ((size_t)b * SEQ + (size_t)c * CHUNK + tid) * DIMM +
                        h * DH + ds * 16;
    const float* ip = inb + base;
    u16x4 rh[4], rm[4], rl[4];
#pragma unroll
    for (int q = 0; q < 4; q++) {
      float f0 = (float)((double)ip[q * 4 + 0] + a[q * 4 + 0]);
      float f1 = (float)((double)ip[q * 4 + 1] + a[q * 4 + 1]);
      float f2 = (float)((double)ip[q * 4 + 2] + a[q * 4 + 2]);
      float f3 = (float)((double)ip[q * 4 + 3] + a[q * 4 + 3]);
      split3s(f0, rh[q].x, rm[q].x, rl[q].x);
      split3s(f1, rh[q].y, rm[q].y, rl[q].y);
      split3s(f2, rh[q].z, rm[q].z, rl[q].z);
      split3s(f3, rh[q].w, rm[q].w, rl[q].w);
    }
#pragma unroll
    for (int q = 0; q < 4; q++) {
      ((u16x4*)(sh + base))[q] = rh[q];
      ((u16x4*)(sm + base))[q] = rm[q];
      ((u16x4*)(sl + base))[q] = rl[q];
    }
    __syncthreads();
    const int slot = tid >> 1, d8 = (tid & 1) * 8;
    const double* dp = delta +
        (((size_t)(b * 8 + h) * NCHUNK + c) * NSLOTS + slot) * DH + ds * 16 + d8;
#pragma unroll
    for (int d = 0; d < 8; d++)
      Msh[slot][d8 + d] = GAMMA64 * Msh[slot][d8 + d] + dp[d];
    __syncthreads();
  }
}

// ---------------- W[K][N] f32 -> WT[N][K] bf16 -----------------------------
__global__ void transconv_kernel(const float* __restrict__ W,
                                 u16* __restrict__ WT, int K, int N) {
  __shared__ float tile[32][33];
  const int n0 = blockIdx.x * 32, k0 = blockIdx.y * 32;
  const int tx = threadIdx.x, ty = threadIdx.y;
#pragma unroll
  for (int i = 0; i < 4; i++)
    tile[ty + 8 * i][tx] = W[(size_t)(k0 + ty + 8 * i) * N + n0 + tx];
  __syncthreads();
#pragma unroll
  for (int i = 0; i < 4; i++)
    WT[(size_t)(n0 + ty + 8 * i) * K + k0 + tx] = f2bf(tile[tx][ty + 8 * i]);
}

// ---------------- bf16 MFMA GEMM for logits (GROUP_N=16 supertile) ---------
template <bool BIAS>
__global__ __launch_bounds__(256) void gemm_kernel(
    const u16* __restrict__ A, const u16* __restrict__ B, float* __restrict__ C,
    const float* __restrict__ bias, int M, int N, int K) {
  __shared__ u16 As[128 * 32];
  __shared__ u16 Bs[128 * 32];
  const int tid = threadIdx.x;
  const int lid = blockIdx.y * gridDim.x + blockIdx.x;
  const int npm = M / 128;
  const int ngrid = N / 128;
  const int GN = 16;
  const int ppg = GN * npm;
  const int gid = lid / ppg;
  const int first_n = gid * GN;
  const int gsz = min(GN, ngrid - first_n);
  const int local = lid - gid * ppg;
  const int bn = first_n + local % gsz;
  const int bm = local / gsz;
  const int wid = tid >> 6, lane = tid & 63;
  const int wr = (wid >> 1) * 64, wc = (wid & 1) * 64;
  f32x4 acc[4][4] = {};
  const int row0 = tid >> 2;
  const int colb = (tid & 3) << 4;
  const char* A0 = (const char*)A + ((size_t)(bm * 128 + row0) * K) * 2 + colb;
  const char* A1 = (const char*)A + ((size_t)(bm * 128 + row0 + 64) * K) * 2 + colb;
  const char* B0 = (const char*)B + ((size_t)(bn * 128 + row0) * K) * 2 + colb;
  const char* B1 = (const char*)B + ((size_t)(bn * 128 + row0 + 64) * K) * 2 + colb;
  char* lA0 = (char*)As + (tid & 192) * 16;
  char* lB0 = (char*)Bs + (tid & 192) * 16;
  const char* pa = (const char*)As + wr * 64 + (lane & 15) * 64 + (lane >> 4) * 16;
  const char* pb = (const char*)Bs + wc * 64 + (lane & 15) * 64 + (lane >> 4) * 16;
  for (int k0 = 0; k0 < K; k0 += 32) {
    const size_t kb = (size_t)k0 * 2;
    gld16(lA0, A0 + kb);
    gld16(lA0 + 4096, A1 + kb);
    gld16(lB0, B0 + kb);
    gld16(lB0 + 4096, B1 + kb);
    __syncthreads();
    s16x8 af[4], bf[4];
#pragma unroll
    for (int m = 0; m < 4; m++) af[m] = *(const s16x8*)(pa + m * 1024);
#pragma unroll
    for (int n = 0; n < 4; n++) bf[n] = *(const s16x8*)(pb + n * 1024);
#pragma unroll
    for (int m = 0; m < 4; m++)
#pragma unroll
      for (int n = 0; n < 4; n++) acc[m][n] = mfma16(af[m], bf[n], acc[m][n]);
    __syncthreads();
  }
#pragma unroll
  for (int m = 0; m < 4; m++)
#pragma unroll
    for (int n = 0; n < 4; n++)
#pragma unroll
      for (int j = 0; j < 4; j++) {
        const int r = bm * 128 + wr + m * 16 + (lane >> 4) * 4 + j;
        const int c = bn * 128 + wc + n * 16 + (lane & 15);
        float v = acc[m][n][j];
        if (BIAS) v += bias[c];
        C[(size_t)r * N + c] = v;
      }
}

extern "C" void kernel_launch(void* const* d_in, const int* in_sizes, int n_in,
                              void* d_out, int out_size, void* d_ws,
                              size_t ws_size, hipStream_t stream) {
  (void)in_sizes; (void)n_in; (void)out_size; (void)ws_size;
  const int* tokens = (const int*)d_in[0];
  const float* embed = (const float*)d_in[1];
  const float* Wq = (const float*)d_in[2];
  const float* Wk = (const float*)d_in[3];
  const float* Wv = (const float*)d_in[4];
  const float* Wo = (const float*)d_in[5];
  const float* slot_keys = (const float*)d_in[6];
  const float* ln_g = (const float*)d_in[7];
  const float* ln_b = (const float*)d_in[8];
  const float* fg = (const float*)d_in[9];
  const float* fb = (const float*)d_in[10];
  const float* Wout = (const float*)d_in[11];
  const float* bout = (const float*)d_in[12];
  float* out = (float*)d_out;

  char* p = (char*)d_ws;
  auto alloc = [&](size_t bytes) -> char* {
    char* r = p;
    p += (bytes + 255) & ~(size_t)255;
    return r;
  };
  const size_t RD = (size_t)NROWS * DIMM;
  double* hidden64 = (double*)alloc(RD * 8);
  double* xn64 = (double*)alloc(RD * 8);
  float* q32 = (float*)alloc(RD * 4);          // aliased as xnb at end
  float* k32 = (float*)alloc(RD * 4);          // k32+v32 aliased as WoutT
  float* v32 = (float*)alloc(RD * 4);
  float* local32 = (float*)alloc(RD * 4);
  double* delta64 =
      (double*)alloc((size_t)NB * NHEADS * NCHUNK * NSLOTS * DH * 8);
  int* ri = (int*)alloc((size_t)65536 * 16 * 4);
  int* wi = (int*)alloc((size_t)65536 * 16 * 4);
  double* rw64 = (double*)alloc((size_t)65536 * 16 * 8);
  double* ww64 = (double*)alloc((size_t)65536 * 16 * 8);
  u16* sAh = (u16*)alloc(RD * 2);   // xn-split3, later q-split3, later local
  u16* sAm = (u16*)alloc(RD * 2);
  u16* sAl = (u16*)alloc(RD * 2);
  u16* kBh = (u16*)alloc(RD * 2);   // k-split3
  u16* kBm = (u16*)alloc(RD * 2);
  u16* kBl = (u16*)alloc(RD * 2);
  u16* WTh = (u16*)alloc((size_t)8 * DIMM * DIMM * 2);  // l*4+{q,k,v,o}
  u16* WTm = (u16*)alloc((size_t)8 * DIMM * DIMM * 2);
  u16* WTl = (u16*)alloc((size_t)8 * DIMM * DIMM * 2);
  double* W2q = (double*)alloc((size_t)2 * DIMM * DIMM * 8);
  double* W2k = (double*)alloc((size_t)2 * DIMM * DIMM * 8);
  const size_t SKE = (size_t)2 * NHEADS * NSLOTS * DH;  // both layers
  u16* sk3h = (u16*)alloc(SKE * 2);
  u16* sk3m = (u16*)alloc(SKE * 2);
  u16* sk3l = (u16*)alloc(SKE * 2);
  float* S = (float*)alloc((size_t)2 * 65536 * NSLOTS * 4);
  int* fcnts = (int*)alloc(256);
  int* flq = (int*)alloc((size_t)MAXFLAG * 4);
  int* flk = (int*)alloc((size_t)MAXFLAG * 4);

  u16* xnb = (u16*)q32;   // used only after layer-2 attn
  u16* WoutT = (u16*)k32; // spans k32+v32 (both dead after layer-2 recur)

  const float* Wmats[4] = {Wq, Wk, Wv, Wo};
  for (int l = 0; l < 2; l++) {
    for (int w = 0; w < 4; w++) {
      const size_t o = ((size_t)l * 4 + w) * DIMM * DIMM;
      transconv3_kernel<<<dim3(DIMM / 32, DIMM / 32), dim3(32, 8), 0, stream>>>(
          Wmats[w] + (size_t)l * DIMM * DIMM, WTh + o, WTm + o, WTl + o, DIMM,
          DIMM);
    }
    const float* skl = slot_keys + (size_t)l * NHEADS * NSLOTS * DH;
    w2_kernel<<<1024, 256, 0, stream>>>(Wq + (size_t)l * DIMM * DIMM, skl,
                                        W2q + (size_t)l * DIMM * DIMM);
    w2_kernel<<<1024, 256, 0, stream>>>(Wk + (size_t)l * DIMM * DIMM, skl,
                                        W2k + (size_t)l * DIMM * DIMM);
  }
  cvt3_32_kernel<<<SKE / 1024, 256, 0, stream>>>(slot_keys, sk3h, sk3m, sk3l);

  embed64_kernel<<<NROWS, 256, 0, stream>>>(tokens, embed, hidden64);

  const dim3 g3(DIMM / 128, NROWS / 128);
  for (int l = 0; l < 2; l++) {
    const size_t oq = ((size_t)l * 4 + 0) * DIMM * DIMM;
    const size_t ok = ((size_t)l * 4 + 1) * DIMM * DIMM;
    const size_t ov = ((size_t)l * 4 + 2) * DIMM * DIMM;
    const size_t oo = ((size_t)l * 4 + 3) * DIMM * DIMM;
    const size_t sko = (size_t)l * NHEADS * NSLOTS * DH;
    ln64_kernel<0><<<NROWS, 256, 0, stream>>>(hidden64, ln_g + l * DIMM,
                                              ln_b + l * DIMM, xn64, sAh, sAm,
                                              sAl);
    gemm3d_kernel<false, float><<<g3, 256, 0, stream>>>(
        sAh, sAm, sAl, WTh + oq, WTm + oq, WTl + oq, q32, nullptr, NROWS, DIMM,
        DIMM);
    gemm3d_kernel<false, float><<<g3, 256, 0, stream>>>(
        sAh, sAm, sAl, WTh + ok, WTm + ok, WTl + ok, k32, nullptr, NROWS, DIMM,
        DIMM);
    gemm3d_kernel<false, float><<<g3, 256, 0, stream>>>(
        sAh, sAm, sAl, WTh + ov, WTm + ov, WTl + ov, v32, nullptr, NROWS, DIMM,
        DIMM);
    // xn-split3 in sA* is dead now: reuse for q-split3
    cvt3_32_kernel<<<RD / 1024, 256, 0, stream>>>(q32, sAh, sAm, sAl);
    cvt3_32_kernel<<<RD / 1024, 256, 0, stream>>>(k32, kBh, kBm, kBl);
    hipMemsetAsync(fcnts, 0, 8, stream);
    score3_kernel<<<dim3(32, 32), 256, 0, stream>>>(
        sAh, sAm, sAl, kBh, kBm, kBl, sk3h + sko, sk3m + sko, sk3l + sko, S);
    select_kernel<<<dim3(16384, 2), 256, 0, stream>>>(S, ri, wi, rw64, ww64,
                                                      fcnts, flq, flk);
    fixup_kernel<<<dim3(512, 2), 256, 0, stream>>>(
        fcnts, flq, flk, xn64, W2q + (size_t)l * DIMM * DIMM,
        W2k + (size_t)l * DIMM * DIMM, ri, wi, rw64, ww64);
    delta64_kernel<<<NB * NHEADS * NCHUNK, 512, 0, stream>>>(wi, ww64, v32,
                                                             delta64);
    attn_fused<<<NB * NCHUNK * NHEADS * 8, 256, 0, stream>>>(q32, k32, v32,
                                                             local32);
    recur64_kernel<<<NB * NHEADS * 8, 256, 0, stream>>>(ri, rw64, delta64,
                                                        local32, sAh, sAm,
                                                        sAl);
    gemm3d_kernel<true, double><<<g3, 256, 0, stream>>>(
        sAh, sAm, sAl, WTh + oo, WTm + oo, WTl + oo, hidden64, hidden64, NROWS,
        DIMM, DIMM);
  }
  transconv_kernel<<<dim3(NVOCAB / 32, DIMM / 32), dim3(32, 8), 0, stream>>>(
      Wout, WoutT, DIMM, NVOCAB);
  ln64_kernel<1><<<NROWS, 256, 0, stream>>>(hidden64, fg, fb, nullptr, xnb,
                                            nullptr, nullptr);
  gemm_kernel<true><<<dim3(NVOCAB / 128, NROWS / 128), 256, 0, stream>>>(
      xnb, WoutT, out, bout, NROWS, NVOCAB, DIMM);
}